// Round 1
// baseline (6001.757 us; speedup 1.0000x reference)
//
#include <hip/hip_runtime.h>
#include <hip/hip_bf16.h>
#include <math.h>

#define NHEADS 16
#define SEQ 2048
#define BATCH 2
#define NTOK (BATCH * SEQ)
#define EPSF 1e-6f

// ---------------------------------------------------------------------------
// Generic tiled fp32 GEMM: C[M,N] = A[M,K] @ W[K,N]; M,N multiples of 64,
// K multiple of 16. A-tile stored transposed in LDS so compute loop is
// 2x ds_read_b128 + 16 FMA per k.
// ---------------------------------------------------------------------------
__global__ __launch_bounds__(256) void gemm64(
    const float* __restrict__ A, int lda,
    const float* __restrict__ W, int ldw,
    float* __restrict__ C, int ldc,
    int K)
{
    __shared__ float As[16][68];   // [k][m], padded: stride 68 -> conflict-free col reads
    __shared__ float Bs[16][64];   // [k][n]
    const int tid = threadIdx.x;
    const int bm = blockIdx.y * 64, bn = blockIdx.x * 64;
    const int tx = tid & 15, ty = tid >> 4;
    const int arow = tid >> 2, acol = (tid & 3) * 4;   // A tile 64x16, float4 per thread
    const int brow = tid >> 4, bcol = (tid & 15) * 4;  // B tile 16x64, float4 per thread
    float acc[4][4] = {};
    for (int k0 = 0; k0 < K; k0 += 16) {
        float4 av = *(const float4*)(A + (size_t)(bm + arow) * lda + k0 + acol);
        float4 bv = *(const float4*)(W + (size_t)(k0 + brow) * ldw + bn + bcol);
        As[acol + 0][arow] = av.x;
        As[acol + 1][arow] = av.y;
        As[acol + 2][arow] = av.z;
        As[acol + 3][arow] = av.w;
        *(float4*)&Bs[brow][bcol] = bv;
        __syncthreads();
#pragma unroll
        for (int k = 0; k < 16; ++k) {
            float4 a = *(const float4*)&As[k][ty * 4];
            float4 b = *(const float4*)&Bs[k][tx * 4];
            acc[0][0] += a.x * b.x; acc[0][1] += a.x * b.y; acc[0][2] += a.x * b.z; acc[0][3] += a.x * b.w;
            acc[1][0] += a.y * b.x; acc[1][1] += a.y * b.y; acc[1][2] += a.y * b.z; acc[1][3] += a.y * b.w;
            acc[2][0] += a.z * b.x; acc[2][1] += a.z * b.y; acc[2][2] += a.z * b.z; acc[2][3] += a.z * b.w;
            acc[3][0] += a.w * b.x; acc[3][1] += a.w * b.y; acc[3][2] += a.w * b.z; acc[3][3] += a.w * b.w;
        }
        __syncthreads();
    }
#pragma unroll
    for (int i = 0; i < 4; ++i) {
        float4 v = make_float4(acc[i][0], acc[i][1], acc[i][2], acc[i][3]);
        *(float4*)(C + (size_t)(bm + ty * 4 + i) * ldc + bn + tx * 4) = v;
    }
}

// ---------------------------------------------------------------------------
// In-place RMSNorm over the first `cols` entries of each row (row stride may
// exceed cols, e.g. kv buffer: normalize 512 of 576).
// ---------------------------------------------------------------------------
__global__ __launch_bounds__(256) void rmsnorm_rows(
    float* __restrict__ buf, const float* __restrict__ w,
    int row_stride, int cols)
{
    const int row = blockIdx.x;
    float* p = buf + (size_t)row * row_stride;
    float ss = 0.f;
    for (int c = threadIdx.x; c < cols; c += 256) { float v = p[c]; ss += v * v; }
#pragma unroll
    for (int off = 32; off > 0; off >>= 1) ss += __shfl_down(ss, off, 64);
    __shared__ float wsum[4];
    __shared__ float s_scale;
    const int wave = threadIdx.x >> 6;
    if ((threadIdx.x & 63) == 0) wsum[wave] = ss;
    __syncthreads();
    if (threadIdx.x == 0) {
        float t = wsum[0] + wsum[1] + wsum[2] + wsum[3];
        s_scale = rsqrtf(t / (float)cols + EPSF);
    }
    __syncthreads();
    const float sc = s_scale;
    for (int c = threadIdx.x; c < cols; c += 256) p[c] = p[c] * sc * w[c];
}

// ---------------------------------------------------------------------------
// RoPE: q (NTOK, 16*192) last-64-of-each-head in place; k_rope read from
// kv[:,512:576] -> krope_out (NTOK, 64). rotate-half formulation.
// ---------------------------------------------------------------------------
__global__ __launch_bounds__(256) void rope_kernel(
    float* __restrict__ q, float* __restrict__ krope_out,
    const float* __restrict__ kv)
{
    const int tok = blockIdx.x;
    const float pos = (float)(tok % SEQ);
    const int tid = threadIdx.x;
#pragma unroll
    for (int it = 0; it < 2; ++it) {
        int idx = tid + it * 256;          // 512 = 16 heads * 32 pairs
        int h = idx >> 5, j = idx & 31;
        float inv = powf(10000.0f, -(float)(2 * j) / 64.0f);
        float f = pos * inv;
        float cs = cosf(f), sn = sinf(f);
        float* base = q + (size_t)tok * (NHEADS * 192) + h * 192 + 128;
        float x1 = base[j], x2 = base[j + 32];
        base[j]      = x1 * cs - x2 * sn;
        base[j + 32] = x2 * cs + x1 * sn;
    }
    if (tid < 32) {
        int j = tid;
        float inv = powf(10000.0f, -(float)(2 * j) / 64.0f);
        float f = pos * inv;
        float cs = cosf(f), sn = sinf(f);
        const float* kb = kv + (size_t)tok * 576 + 512;
        float x1 = kb[j], x2 = kb[j + 32];
        float* ob = krope_out + (size_t)tok * 64;
        ob[j]      = x1 * cs - x2 * sn;
        ob[j + 32] = x2 * cs + x1 * sn;
    }
}

// ---------------------------------------------------------------------------
// Flash attention, fp32, causal. One block = (q-tile of 32 rows, head, batch).
// 256 threads: thread t owns q-row t/8, output cols (t%8)*16..+15.
// K dims = 192 (nope 128 | rope 64), V dims = 128.
// ---------------------------------------------------------------------------
#define BQ 32
#define BKV 16
#define QPAD 196   // 196%32==4 -> row reads hit distinct banks; rows 16B-aligned
#define VPAD 132
#define PPAD 17

__global__ __launch_bounds__(256) void flash_kernel(
    const float* __restrict__ q,      // (NTOK, 16*192)
    const float* __restrict__ kvb,    // (NTOK, 16*256)  [nope128 | v128] per head
    const float* __restrict__ krope,  // (NTOK, 64)
    float* __restrict__ ctx)          // (NTOK, 2048)
{
    __shared__ float Qs[BQ][QPAD];
    __shared__ float Ks[BKV][QPAD];
    __shared__ float Vs[BKV][VPAD];
    __shared__ float Ps[BQ][PPAD];
    const int qt = blockIdx.x, h = blockIdx.y, b = blockIdx.z;
    const int tid = threadIdx.x;
    const float scale = 0.07216878364870323f;  // 1/sqrt(192)

    // load+scale Q tile
    for (int i = tid; i < BQ * 192; i += 256) {
        int r = i / 192, d = i - r * 192;
        int tq = qt * BQ + r;
        Qs[r][d] = q[(size_t)(b * SEQ + tq) * (NHEADS * 192) + h * 192 + d] * scale;
    }

    const int r  = tid >> 3;   // q row in tile
    const int i8 = tid & 7;    // lane-in-row
    const int tq = qt * BQ + r;
    float o[16];
#pragma unroll
    for (int j = 0; j < 16; ++j) o[j] = 0.f;
    float m = -1e30f, l = 0.f;

    const int nkt = (qt * BQ + BQ + BKV - 1) / BKV;  // = 2*qt + 2
    for (int kt = 0; kt < nkt; ++kt) {
        __syncthreads();  // prev tile's Ks/Vs fully consumed
        for (int i = tid; i < BKV * 192; i += 256) {
            int kr = i / 192, d = i - kr * 192;
            int tk = kt * BKV + kr;
            float v;
            if (d < 128) v = kvb[(size_t)(b * SEQ + tk) * (NHEADS * 256) + h * 256 + d];
            else         v = krope[(size_t)(b * SEQ + tk) * 64 + (d - 128)];
            Ks[kr][d] = v;
        }
        for (int i = tid; i < BKV * 128; i += 256) {
            int kr = i >> 7, d = i & 127;
            int tk = kt * BKV + kr;
            Vs[kr][d] = kvb[(size_t)(b * SEQ + tk) * (NHEADS * 256) + h * 256 + 128 + d];
        }
        __syncthreads();

        // scores: 2 per thread
        const int k0 = i8 * 2, k1 = k0 + 1;
        float s0 = 0.f, s1 = 0.f;
#pragma unroll 12
        for (int d4 = 0; d4 < 48; ++d4) {
            float4 qv  = *(const float4*)&Qs[r][d4 * 4];
            float4 k0v = *(const float4*)&Ks[k0][d4 * 4];
            float4 k1v = *(const float4*)&Ks[k1][d4 * 4];
            s0 += qv.x * k0v.x + qv.y * k0v.y + qv.z * k0v.z + qv.w * k0v.w;
            s1 += qv.x * k1v.x + qv.y * k1v.y + qv.z * k1v.z + qv.w * k1v.w;
        }
        const int tk0 = kt * BKV + k0, tk1 = tk0 + 1;
        if (tk0 > tq) s0 = -1e30f;
        if (tk1 > tq) s1 = -1e30f;
        float smax = fmaxf(s0, s1);
        smax = fmaxf(smax, __shfl_xor(smax, 1, 64));
        smax = fmaxf(smax, __shfl_xor(smax, 2, 64));
        smax = fmaxf(smax, __shfl_xor(smax, 4, 64));
        float mnew = fmaxf(m, smax);
        float p0 = expf(s0 - mnew);   // masked -> exp(-huge) == 0
        float p1 = expf(s1 - mnew);
        float alpha = expf(m - mnew);
        m = mnew;
        float psum = p0 + p1;
        psum += __shfl_xor(psum, 1, 64);
        psum += __shfl_xor(psum, 2, 64);
        psum += __shfl_xor(psum, 4, 64);
        l = l * alpha + psum;
        // P row lives in the same 8 lanes (one wave) -> no barrier needed
        Ps[r][k0] = p0;
        Ps[r][k1] = p1;
#pragma unroll
        for (int j = 0; j < 16; ++j) o[j] *= alpha;
#pragma unroll
        for (int k = 0; k < BKV; ++k) {
            float p = Ps[r][k];
            float4 v0 = *(const float4*)&Vs[k][i8 * 16 + 0];
            float4 v1 = *(const float4*)&Vs[k][i8 * 16 + 4];
            float4 v2 = *(const float4*)&Vs[k][i8 * 16 + 8];
            float4 v3 = *(const float4*)&Vs[k][i8 * 16 + 12];
            o[0]  += p * v0.x; o[1]  += p * v0.y; o[2]  += p * v0.z; o[3]  += p * v0.w;
            o[4]  += p * v1.x; o[5]  += p * v1.y; o[6]  += p * v1.z; o[7]  += p * v1.w;
            o[8]  += p * v2.x; o[9]  += p * v2.y; o[10] += p * v2.z; o[11] += p * v2.w;
            o[12] += p * v3.x; o[13] += p * v3.y; o[14] += p * v3.z; o[15] += p * v3.w;
        }
    }
    const float inv_l = 1.0f / l;
    float* op = ctx + (size_t)(b * SEQ + tq) * 2048 + h * 128 + i8 * 16;
#pragma unroll
    for (int j = 0; j < 16; ++j) op[j] = o[j] * inv_l;
}

// ---------------------------------------------------------------------------
extern "C" void kernel_launch(void* const* d_in, const int* in_sizes, int n_in,
                              void* d_out, int out_size, void* d_ws, size_t ws_size,
                              hipStream_t stream) {
    const float* x         = (const float*)d_in[0];
    const float* q_a_w     = (const float*)d_in[1];
    const float* q_a_norm_w= (const float*)d_in[2];
    const float* q_b_w     = (const float*)d_in[3];
    const float* kv_a_w    = (const float*)d_in[4];
    const float* kv_norm_w = (const float*)d_in[5];
    const float* kv_b_w    = (const float*)d_in[6];
    const float* o_w       = (const float*)d_in[7];
    float* out = (float*)d_out;

    char* ws = (char*)d_ws;
    float* q_a   = (float*)(ws + 0);              // 4096x1536  (25.2 MB)
    float* qbuf  = (float*)(ws + 25165824);       // 4096x3072  (50.3 MB)
    float* kv    = (float*)(ws + 75497472);       // 4096x576   ( 9.4 MB)
    float* kvb   = (float*)(ws + 84934656);       // 4096x4096  (67.1 MB)
    float* krope = (float*)(ws + 152043520);      // 4096x64    ( 1.0 MB)
    float* ctx   = (float*)(ws + 153092096);      // 4096x2048  (33.6 MB) -> 186.6 MB total

    dim3 blk(256);

    // q_a = x @ q_a_w  (M=4096, N=1536, K=2048)
    gemm64<<<dim3(1536 / 64, NTOK / 64), blk, 0, stream>>>(x, 2048, q_a_w, 1536, q_a, 1536, 2048);
    // kv = x @ kv_a_w  (M=4096, N=576, K=2048)
    gemm64<<<dim3(576 / 64, NTOK / 64), blk, 0, stream>>>(x, 2048, kv_a_w, 576, kv, 576, 2048);
    // RMSNorm q_a rows (1536); kv rows (first 512 cols only)
    rmsnorm_rows<<<NTOK, blk, 0, stream>>>(q_a, q_a_norm_w, 1536, 1536);
    rmsnorm_rows<<<NTOK, blk, 0, stream>>>(kv, kv_norm_w, 576, 512);
    // q = q_a @ q_b_w  (N=3072, K=1536)
    gemm64<<<dim3(3072 / 64, NTOK / 64), blk, 0, stream>>>(q_a, 1536, q_b_w, 3072, qbuf, 3072, 1536);
    // kvb = kv_c @ kv_b_w  (N=4096, K=512, lda=576)
    gemm64<<<dim3(4096 / 64, NTOK / 64), blk, 0, stream>>>(kv, 576, kv_b_w, 4096, kvb, 4096, 512);
    // RoPE (q in place; k_rope -> krope)
    rope_kernel<<<NTOK, blk, 0, stream>>>(qbuf, krope, kv);
    // flash attention -> ctx (NTOK, 2048)
    flash_kernel<<<dim3(SEQ / BQ, NHEADS, BATCH), blk, 0, stream>>>(qbuf, kvb, krope, ctx);
    // out = ctx @ o_w  (N=2048, K=2048)
    gemm64<<<dim3(2048 / 64, NTOK / 64), blk, 0, stream>>>(ctx, 2048, o_w, 2048, out, 2048, 2048);
}

// Round 2
// 2212.841 us; speedup vs baseline: 2.7122x; 2.7122x over previous
//
#include <hip/hip_runtime.h>
#include <hip/hip_bf16.h>
#include <math.h>

#define NHEADS 16
#define SEQ 2048
#define BATCH 2
#define NTOK (BATCH * SEQ)
#define EPSF 1e-6f

typedef short bf16x8 __attribute__((ext_vector_type(8)));
typedef float f32x4 __attribute__((ext_vector_type(4)));

__device__ __forceinline__ unsigned short f2bf(float v) {
    __hip_bfloat16 h = __float2bfloat16(v);
    return *reinterpret_cast<unsigned short*>(&h);
}

// ---------------------------------------------------------------------------
// Generic tiled fp32 GEMM: C[M,N] = A[M,K] @ W[K,N] (unchanged from r1).
// ---------------------------------------------------------------------------
__global__ __launch_bounds__(256) void gemm64(
    const float* __restrict__ A, int lda,
    const float* __restrict__ W, int ldw,
    float* __restrict__ C, int ldc,
    int K)
{
    __shared__ float As[16][68];
    __shared__ float Bs[16][64];
    const int tid = threadIdx.x;
    const int bm = blockIdx.y * 64, bn = blockIdx.x * 64;
    const int tx = tid & 15, ty = tid >> 4;
    const int arow = tid >> 2, acol = (tid & 3) * 4;
    const int brow = tid >> 4, bcol = (tid & 15) * 4;
    float acc[4][4] = {};
    for (int k0 = 0; k0 < K; k0 += 16) {
        float4 av = *(const float4*)(A + (size_t)(bm + arow) * lda + k0 + acol);
        float4 bv = *(const float4*)(W + (size_t)(k0 + brow) * ldw + bn + bcol);
        As[acol + 0][arow] = av.x;
        As[acol + 1][arow] = av.y;
        As[acol + 2][arow] = av.z;
        As[acol + 3][arow] = av.w;
        *(float4*)&Bs[brow][bcol] = bv;
        __syncthreads();
#pragma unroll
        for (int k = 0; k < 16; ++k) {
            float4 a = *(const float4*)&As[k][ty * 4];
            float4 b = *(const float4*)&Bs[k][tx * 4];
            acc[0][0] += a.x * b.x; acc[0][1] += a.x * b.y; acc[0][2] += a.x * b.z; acc[0][3] += a.x * b.w;
            acc[1][0] += a.y * b.x; acc[1][1] += a.y * b.y; acc[1][2] += a.y * b.z; acc[1][3] += a.y * b.w;
            acc[2][0] += a.z * b.x; acc[2][1] += a.z * b.y; acc[2][2] += a.z * b.z; acc[2][3] += a.z * b.w;
            acc[3][0] += a.w * b.x; acc[3][1] += a.w * b.y; acc[3][2] += a.w * b.z; acc[3][3] += a.w * b.w;
        }
        __syncthreads();
    }
#pragma unroll
    for (int i = 0; i < 4; ++i) {
        float4 v = make_float4(acc[i][0], acc[i][1], acc[i][2], acc[i][3]);
        *(float4*)(C + (size_t)(bm + ty * 4 + i) * ldc + bn + tx * 4) = v;
    }
}

// ---------------------------------------------------------------------------
__global__ __launch_bounds__(256) void rmsnorm_rows(
    float* __restrict__ buf, const float* __restrict__ w,
    int row_stride, int cols)
{
    const int row = blockIdx.x;
    float* p = buf + (size_t)row * row_stride;
    float ss = 0.f;
    for (int c = threadIdx.x; c < cols; c += 256) { float v = p[c]; ss += v * v; }
#pragma unroll
    for (int off = 32; off > 0; off >>= 1) ss += __shfl_down(ss, off, 64);
    __shared__ float wsum[4];
    __shared__ float s_scale;
    const int wave = threadIdx.x >> 6;
    if ((threadIdx.x & 63) == 0) wsum[wave] = ss;
    __syncthreads();
    if (threadIdx.x == 0) {
        float t = wsum[0] + wsum[1] + wsum[2] + wsum[3];
        s_scale = rsqrtf(t / (float)cols + EPSF);
    }
    __syncthreads();
    const float sc = s_scale;
    for (int c = threadIdx.x; c < cols; c += 256) p[c] = p[c] * sc * w[c];
}

// ---------------------------------------------------------------------------
// rope_k: roped k_rope (shared across heads) -> bf16 [tok][64]
// ---------------------------------------------------------------------------
__global__ __launch_bounds__(64) void rope_k(
    const float* __restrict__ kv, unsigned short* __restrict__ krope_bf)
{
    const int tok = blockIdx.x;
    const int s = tok & (SEQ - 1);
    const int j = threadIdx.x;
    const int jj = j & 31;
    float inv = powf(10000.0f, -(float)(2 * jj) / 64.0f);
    float f = (float)s * inv;
    float sn, cs;
    sincosf(f, &sn, &cs);
    const float* kb = kv + (size_t)tok * 576 + 512;
    float v = (j < 32) ? (kb[j] * cs - kb[j + 32] * sn)
                       : (kb[j] * cs + kb[j - 32] * sn);
    krope_bf[(size_t)tok * 64 + j] = f2bf(v);
}

// ---------------------------------------------------------------------------
// pack_q: qbuf fp32 (tok,3072) -> q_bf [b][h][s][192] bf16, RoPE'd + scaled.
// ---------------------------------------------------------------------------
__global__ __launch_bounds__(256) void pack_q(
    const float* __restrict__ qbuf, unsigned short* __restrict__ q_bf)
{
    const int tok = blockIdx.x;
    const int b = tok >> 11, s = tok & (SEQ - 1);
    const float* src = qbuf + (size_t)tok * 3072;
    const float scale = 0.07216878364870323f;  // 1/sqrt(192)
#pragma unroll
    for (int t = 0; t < 12; ++t) {
        int i = threadIdx.x + t * 256;
        int h = i / 192, d = i - h * 192;
        float v = src[i];
        if (d >= 128) {
            int j = (d - 128) & 31;
            float inv = powf(10000.0f, -(float)(2 * j) / 64.0f);
            float f = (float)s * inv;
            float sn, cs;
            sincosf(f, &sn, &cs);
            if (d < 160) v = v * cs - src[i + 32] * sn;
            else         v = v * cs + src[i - 32] * sn;
        }
        q_bf[((size_t)(b * NHEADS + h) * SEQ + s) * 192 + d] = f2bf(v * scale);
    }
}

// ---------------------------------------------------------------------------
// pack_k: k_bf [b][h][s][192] = [ kvb nope(128) | krope_bf(64) broadcast ]
// ---------------------------------------------------------------------------
__global__ __launch_bounds__(256) void pack_k(
    const float* __restrict__ kvb, const unsigned short* __restrict__ krope_bf,
    unsigned short* __restrict__ k_bf)
{
    const int tok = blockIdx.x;
    const int b = tok >> 11, s = tok & (SEQ - 1);
#pragma unroll
    for (int t = 0; t < 12; ++t) {
        int i = threadIdx.x + t * 256;
        int h = i / 192, d = i - h * 192;
        unsigned short o;
        if (d < 128) o = f2bf(kvb[(size_t)tok * 4096 + h * 256 + d]);
        else         o = krope_bf[(size_t)tok * 64 + (d - 128)];
        k_bf[((size_t)(b * NHEADS + h) * SEQ + s) * 192 + d] = o;
    }
}

// ---------------------------------------------------------------------------
// pack_vt: vt_bf [b][h][d=128][s=2048] = kvb[b*S+s][h*256+128+d]  (transpose)
// ---------------------------------------------------------------------------
__global__ __launch_bounds__(256) void pack_vt(
    const float* __restrict__ kvb, unsigned short* __restrict__ vt_bf)
{
    __shared__ __align__(16) float T[64][132];
    const int st = blockIdx.x, h = blockIdx.y, b = blockIdx.z;
    const int tid = threadIdx.x;
#pragma unroll
    for (int t = 0; t < 8; ++t) {
        int i = tid + t * 256;
        int r = i >> 5, c4 = i & 31;
        float4 v = *(const float4*)(kvb + (size_t)(b * SEQ + st * 64 + r) * 4096 + h * 256 + 128 + c4 * 4);
        *(float4*)&T[r][c4 * 4] = v;
    }
    __syncthreads();
    const int d = tid >> 1, sh = (tid & 1) * 32;
    unsigned short tmp[32];
#pragma unroll
    for (int k = 0; k < 32; ++k) tmp[k] = f2bf(T[sh + k][d]);
    unsigned short* dst = vt_bf + ((size_t)(b * NHEADS + h) * 128 + d) * SEQ + st * 64 + sh;
#pragma unroll
    for (int c = 0; c < 4; ++c) *(bf16x8*)(dst + c * 8) = *(bf16x8*)&tmp[c * 8];
}

// ---------------------------------------------------------------------------
// MFMA flash attention, causal. Block = (q-tile 64, head, batch), 4 waves.
// Wave w owns q-rows w*16..w*16+15; Q frags in registers; K/Vt tiles in LDS.
// ---------------------------------------------------------------------------
#define KPD 200   // K LDS row stride (bf16): 400B -> rows r,r+8 share 16B slot (2-way, free)
#define VPD 72    // Vt LDS row stride: 144B
#define PPD 72

__global__ __launch_bounds__(256) void flash_mfma(
    const unsigned short* __restrict__ q_bf,
    const unsigned short* __restrict__ k_bf,
    const unsigned short* __restrict__ vt_bf,
    float* __restrict__ ctx)
{
    __shared__ __align__(16) unsigned short Ks[64][KPD];   // 25600 B
    __shared__ __align__(16) unsigned short Vs[128][VPD];  // 18432 B
    __shared__ __align__(16) unsigned short Ps[4][16][PPD];//  9216 B
    const int qt = (int)gridDim.x - 1 - (int)blockIdx.x;   // large tiles dispatch first
    const int h = blockIdx.y, b = blockIdx.z;
    const int tid = threadIdx.x;
    const int wid = tid >> 6, lane = tid & 63;
    const int l16 = lane & 15, lq = lane >> 4;

    const size_t headQ = (size_t)(b * NHEADS + h) * SEQ * 192;
    const size_t headV = (size_t)(b * NHEADS + h) * 128 * SEQ;

    // Q fragments: row = qt*64 + wid*16 + l16, k = kk*32 + lq*8 + j
    bf16x8 qf[6];
    {
        const unsigned short* qp = q_bf + headQ + (size_t)(qt * 64 + wid * 16 + l16) * 192 + lq * 8;
#pragma unroll
        for (int kk = 0; kk < 6; ++kk) qf[kk] = *(const bf16x8*)(qp + kk * 32);
    }

    f32x4 o[8];
#pragma unroll
    for (int f = 0; f < 8; ++f) o[f] = (f32x4){0.f, 0.f, 0.f, 0.f};
    float m[4] = {-1e30f, -1e30f, -1e30f, -1e30f};
    float lsum[4] = {0.f, 0.f, 0.f, 0.f};

    const int nkt = qt + 1;
    for (int kt = 0; kt < nkt; ++kt) {
        __syncthreads();
        // stage K tile: 64 x 192 bf16
#pragma unroll
        for (int t = 0; t < 6; ++t) {
            int i = tid + t * 256;
            int r = i / 24, c8 = i % 24;
            bf16x8 v = *(const bf16x8*)(k_bf + headQ + (size_t)(kt * 64 + r) * 192 + c8 * 8);
            *(bf16x8*)&Ks[r][c8 * 8] = v;
        }
        // stage Vt tile: 128 x 64 bf16
#pragma unroll
        for (int t = 0; t < 4; ++t) {
            int i = tid + t * 256;
            int r = i >> 3, c8 = i & 7;
            bf16x8 v = *(const bf16x8*)(vt_bf + headV + (size_t)r * SEQ + kt * 64 + c8 * 8);
            *(bf16x8*)&Vs[r][c8 * 8] = v;
        }
        __syncthreads();

        // S = Q(16x192) @ K^T(192x64): 4 n-frags x 6 k-steps
        f32x4 s[4];
#pragma unroll
        for (int f = 0; f < 4; ++f) s[f] = (f32x4){0.f, 0.f, 0.f, 0.f};
#pragma unroll
        for (int f = 0; f < 4; ++f) {
#pragma unroll
            for (int kk = 0; kk < 6; ++kk) {
                bf16x8 bfr = *(const bf16x8*)&Ks[f * 16 + l16][kk * 32 + lq * 8];
                s[f] = __builtin_amdgcn_mfma_f32_16x16x32_bf16(qf[kk], bfr, s[f], 0, 0, 0);
            }
        }

        // online softmax (per lane: q-rows lq*4+reg, keys f*16+l16)
        const int qabs = qt * 64 + wid * 16 + lq * 4;
        const bool diag = (kt == qt);
#pragma unroll
        for (int reg = 0; reg < 4; ++reg) {
            float a0 = s[0][reg], a1 = s[1][reg], a2 = s[2][reg], a3 = s[3][reg];
            if (diag) {
                int q = qabs + reg;
                int k0 = kt * 64 + l16;
                if (k0      > q) a0 = -1e30f;
                if (k0 + 16 > q) a1 = -1e30f;
                if (k0 + 32 > q) a2 = -1e30f;
                if (k0 + 48 > q) a3 = -1e30f;
            }
            float rmax = fmaxf(fmaxf(a0, a1), fmaxf(a2, a3));
            rmax = fmaxf(rmax, __shfl_xor(rmax, 1, 64));
            rmax = fmaxf(rmax, __shfl_xor(rmax, 2, 64));
            rmax = fmaxf(rmax, __shfl_xor(rmax, 4, 64));
            rmax = fmaxf(rmax, __shfl_xor(rmax, 8, 64));
            float mnew = fmaxf(m[reg], rmax);
            float sc = __expf(m[reg] - mnew);
            m[reg] = mnew;
            float p0 = __expf(a0 - mnew), p1 = __expf(a1 - mnew);
            float p2 = __expf(a2 - mnew), p3 = __expf(a3 - mnew);
            float rs = p0 + p1 + p2 + p3;
            rs += __shfl_xor(rs, 1, 64);
            rs += __shfl_xor(rs, 2, 64);
            rs += __shfl_xor(rs, 4, 64);
            rs += __shfl_xor(rs, 8, 64);
            lsum[reg] = lsum[reg] * sc + rs;
#pragma unroll
            for (int f = 0; f < 8; ++f) o[f][reg] *= sc;
            Ps[wid][lq * 4 + reg][ 0 + l16] = f2bf(p0);
            Ps[wid][lq * 4 + reg][16 + l16] = f2bf(p1);
            Ps[wid][lq * 4 + reg][32 + l16] = f2bf(p2);
            Ps[wid][lq * 4 + reg][48 + l16] = f2bf(p3);
        }

        // O(16x128) += P(16x64) @ V(64x128)
        bf16x8 pa0 = *(const bf16x8*)&Ps[wid][l16][lq * 8];
        bf16x8 pa1 = *(const bf16x8*)&Ps[wid][l16][32 + lq * 8];
#pragma unroll
        for (int f = 0; f < 8; ++f) {
            bf16x8 b0 = *(const bf16x8*)&Vs[f * 16 + l16][lq * 8];
            bf16x8 b1 = *(const bf16x8*)&Vs[f * 16 + l16][32 + lq * 8];
            o[f] = __builtin_amdgcn_mfma_f32_16x16x32_bf16(pa0, b0, o[f], 0, 0, 0);
            o[f] = __builtin_amdgcn_mfma_f32_16x16x32_bf16(pa1, b1, o[f], 0, 0, 0);
        }
    }

    // epilogue
#pragma unroll
    for (int reg = 0; reg < 4; ++reg) {
        float inv = 1.0f / lsum[reg];
        float* dst = ctx + (size_t)(b * SEQ + qt * 64 + wid * 16 + lq * 4 + reg) * 2048 + h * 128 + l16;
#pragma unroll
        for (int f = 0; f < 8; ++f) dst[f * 16] = o[f][reg] * inv;
    }
}

// ---------------------------------------------------------------------------
extern "C" void kernel_launch(void* const* d_in, const int* in_sizes, int n_in,
                              void* d_out, int out_size, void* d_ws, size_t ws_size,
                              hipStream_t stream) {
    const float* x          = (const float*)d_in[0];
    const float* q_a_w      = (const float*)d_in[1];
    const float* q_a_norm_w = (const float*)d_in[2];
    const float* q_b_w      = (const float*)d_in[3];
    const float* kv_a_w     = (const float*)d_in[4];
    const float* kv_norm_w  = (const float*)d_in[5];
    const float* kv_b_w     = (const float*)d_in[6];
    const float* o_w        = (const float*)d_in[7];
    float* out = (float*)d_out;

    char* ws = (char*)d_ws;
    float* q_a   = (float*)(ws + 0);              // 4096x1536 f32 (25.2 MB)
    float* qbuf  = (float*)(ws + 25165824);       // 4096x3072 f32 (50.3 MB)
    float* kv    = (float*)(ws + 75497472);       // 4096x576  f32 ( 9.4 MB)
    float* kvb   = (float*)(ws + 84934656);       // 4096x4096 f32 (67.1 MB)
    unsigned short* krope_bf = (unsigned short*)(ws + 152043520);  // 4096x64 bf16
    // overlays (producers dead by the time these are written):
    unsigned short* q_bf  = (unsigned short*)(ws + 0);         // 2x16x2048x192 bf16 = 25.2 MB (over q_a)
    unsigned short* k_bf  = (unsigned short*)(ws + 25165824);  // same size (over qbuf lo)
    unsigned short* vt_bf = (unsigned short*)(ws + 50331648);  // 2x16x128x2048 bf16 = 16.8 MB (over qbuf hi)
    float* ctx = (float*)(ws + 84934656);                      // 4096x2048 f32 (over kvb)

    dim3 blk(256);

    // q_a = x @ q_a_w  (M=4096, N=1536, K=2048)
    gemm64<<<dim3(1536 / 64, NTOK / 64), blk, 0, stream>>>(x, 2048, q_a_w, 1536, q_a, 1536, 2048);
    // kv = x @ kv_a_w  (M=4096, N=576, K=2048)
    gemm64<<<dim3(576 / 64, NTOK / 64), blk, 0, stream>>>(x, 2048, kv_a_w, 576, kv, 576, 2048);
    rmsnorm_rows<<<NTOK, blk, 0, stream>>>(q_a, q_a_norm_w, 1536, 1536);
    rmsnorm_rows<<<NTOK, blk, 0, stream>>>(kv, kv_norm_w, 576, 512);
    // q = q_a @ q_b_w  (N=3072, K=1536)
    gemm64<<<dim3(3072 / 64, NTOK / 64), blk, 0, stream>>>(q_a, 1536, q_b_w, 3072, qbuf, 3072, 1536);
    // kvb = kv_c @ kv_b_w  (N=4096, K=512, lda=576)
    gemm64<<<dim3(4096 / 64, NTOK / 64), blk, 0, stream>>>(kv, 576, kv_b_w, 4096, kvb, 4096, 512);
    // pack for attention
    rope_k<<<NTOK, dim3(64), 0, stream>>>(kv, krope_bf);
    pack_q<<<NTOK, blk, 0, stream>>>(qbuf, q_bf);          // reads qbuf, writes over q_a (dead)
    pack_k<<<NTOK, blk, 0, stream>>>(kvb, krope_bf, k_bf); // writes over qbuf (dead)
    pack_vt<<<dim3(SEQ / 64, NHEADS, BATCH), blk, 0, stream>>>(kvb, vt_bf);
    // flash attention -> ctx (over kvb, dead)
    flash_mfma<<<dim3(SEQ / 64, NHEADS, BATCH), blk, 0, stream>>>(q_bf, k_bf, vt_bf, ctx);
    // out = ctx @ o_w  (N=2048, K=2048)
    gemm64<<<dim3(2048 / 64, NTOK / 64), blk, 0, stream>>>(ctx, 2048, o_w, 2048, out, 2048, 2048);
}

// Round 5
// 542.035 us; speedup vs baseline: 11.0726x; 4.0825x over previous
//
#include <hip/hip_runtime.h>
#include <hip/hip_bf16.h>
#include <math.h>

#define NHEADS 16
#define SEQ 2048
#define BATCH 2
#define NTOK (BATCH * SEQ)
#define EPSF 1e-6f

typedef short bf16x8 __attribute__((ext_vector_type(8)));
typedef float f32x4 __attribute__((ext_vector_type(4)));

__device__ __forceinline__ unsigned short f2bf(float v) {
    __hip_bfloat16 h = __float2bfloat16(v);
    return *reinterpret_cast<unsigned short*>(&h);
}
__device__ __forceinline__ float bf2f(unsigned short u) {
    __hip_bfloat16 h = *reinterpret_cast<__hip_bfloat16*>(&u);
    return __bfloat162float(h);
}
__device__ __forceinline__ void g2l16(const void* g, void* l) {
    __builtin_amdgcn_global_load_lds(
        (const __attribute__((address_space(1))) void*)g,
        (__attribute__((address_space(3))) void*)l, 16, 0, 0);
}

// ---------------------------------------------------------------------------
// x fp32 -> bf16 (8 elems/thread)
// ---------------------------------------------------------------------------
__global__ __launch_bounds__(256) void cvt_bf16(
    const float* __restrict__ in, unsigned short* __restrict__ out)
{
    const int i = blockIdx.x * 256 + threadIdx.x;
    float4 a = ((const float4*)in)[i * 2];
    float4 b = ((const float4*)in)[i * 2 + 1];
    unsigned short o[8] = {f2bf(a.x), f2bf(a.y), f2bf(a.z), f2bf(a.w),
                           f2bf(b.x), f2bf(b.y), f2bf(b.z), f2bf(b.w)};
    *(bf16x8*)(out + (size_t)i * 8) = *(bf16x8*)o;
}

// ---------------------------------------------------------------------------
// weight transpose+convert: w [K][Nw] fp32 -> wt [Npad][K] bf16 (grid.x=Npad/32)
// tiles with n0 >= Nw are zero-filled.
// ---------------------------------------------------------------------------
__global__ __launch_bounds__(256) void transpose_cvt(
    const float* __restrict__ w, unsigned short* __restrict__ wt,
    int Nw, int K)
{
    __shared__ float T[32][33];
    const int n0 = blockIdx.x * 32, k0 = blockIdx.y * 32;
    const int tid = threadIdx.x;
    const int r = tid >> 3, c4 = (tid & 7) * 4;
    const bool valid = (n0 < Nw);
    if (valid) {
        float4 v = *(const float4*)(w + (size_t)(k0 + r) * Nw + n0 + c4);
        T[r][c4 + 0] = v.x; T[r][c4 + 1] = v.y; T[r][c4 + 2] = v.z; T[r][c4 + 3] = v.w;
    }
    __syncthreads();
    unsigned short o[4];
#pragma unroll
    for (int j = 0; j < 4; ++j) o[j] = valid ? f2bf(T[c4 + j][r]) : (unsigned short)0;
    *(ulong1*)(wt + (size_t)(n0 + r) * K + k0 + c4) = *(ulong1*)o;
}

// ---------------------------------------------------------------------------
// bf16 MFMA GEMM: C[M,N] = A[M,K](bf16) @ Bt[N,K](bf16)^T. 128x128 tile, BK=32.
// OUT_BF16: C is bf16, else fp32.
// ---------------------------------------------------------------------------
template <int OUT_BF16>
__global__ __launch_bounds__(256) void gemm_bt(
    const unsigned short* __restrict__ A,
    const unsigned short* __restrict__ Bt,
    void* __restrict__ Cv,
    int K, int N)
{
    __shared__ __align__(16) unsigned short As[128 * 32];
    __shared__ __align__(16) unsigned short Bs[128 * 32];
    const int tid = threadIdx.x;
    const int lane = tid & 63, wid = tid >> 6;
    const int l16 = lane & 15, lq = lane >> 4;
    const int wr = wid >> 1, wc = wid & 1;
    const int bm = blockIdx.y * 128, bn = blockIdx.x * 128;

    f32x4 acc[4][4];
#pragma unroll
    for (int m = 0; m < 4; ++m)
#pragma unroll
        for (int n = 0; n < 4; ++n) acc[m][n] = (f32x4){0.f, 0.f, 0.f, 0.f};

    for (int k0 = 0; k0 < K; k0 += 32) {
        __syncthreads();
#pragma unroll
        for (int t = 0; t < 2; ++t) {
            const int chunk = t * 256 + tid;           // 0..511, 16B each
            const int row = chunk >> 2, koff = (chunk & 3) << 3;
            g2l16(A  + (size_t)(bm + row) * K + k0 + koff, (char*)As + chunk * 16);
            g2l16(Bt + (size_t)(bn + row) * K + k0 + koff, (char*)Bs + chunk * 16);
        }
        __syncthreads();   // drains vmcnt before barrier

        bf16x8 af[4], bfr[4];
#pragma unroll
        for (int m = 0; m < 4; ++m)
            af[m] = *(const bf16x8*)(As + (wr * 64 + m * 16 + l16) * 32 + lq * 8);
#pragma unroll
        for (int n = 0; n < 4; ++n)
            bfr[n] = *(const bf16x8*)(Bs + (wc * 64 + n * 16 + l16) * 32 + lq * 8);
#pragma unroll
        for (int m = 0; m < 4; ++m)
#pragma unroll
            for (int n = 0; n < 4; ++n)
                acc[m][n] = __builtin_amdgcn_mfma_f32_16x16x32_bf16(af[m], bfr[n], acc[m][n], 0, 0, 0);
    }

#pragma unroll
    for (int m = 0; m < 4; ++m)
#pragma unroll
        for (int n = 0; n < 4; ++n)
#pragma unroll
            for (int reg = 0; reg < 4; ++reg) {
                const int row = bm + wr * 64 + m * 16 + lq * 4 + reg;
                const int col = bn + wc * 64 + n * 16 + l16;
                if (OUT_BF16) ((unsigned short*)Cv)[(size_t)row * N + col] = f2bf(acc[m][n][reg]);
                else          ((float*)Cv)[(size_t)row * N + col] = acc[m][n][reg];
            }
}

// ---------------------------------------------------------------------------
// RMSNorm: fp32 in (row stride, first `cols`) -> bf16 compact out
// ---------------------------------------------------------------------------
__global__ __launch_bounds__(256) void rmsnorm_bf(
    const float* __restrict__ in, const float* __restrict__ w,
    unsigned short* __restrict__ out, int in_stride, int cols)
{
    const int row = blockIdx.x;
    const float* p = in + (size_t)row * in_stride;
    float ss = 0.f;
    for (int c = threadIdx.x; c < cols; c += 256) { float v = p[c]; ss += v * v; }
#pragma unroll
    for (int off = 32; off > 0; off >>= 1) ss += __shfl_down(ss, off, 64);
    __shared__ float wsum[4];
    __shared__ float s_scale;
    const int wave = threadIdx.x >> 6;
    if ((threadIdx.x & 63) == 0) wsum[wave] = ss;
    __syncthreads();
    if (threadIdx.x == 0) {
        float t = wsum[0] + wsum[1] + wsum[2] + wsum[3];
        s_scale = rsqrtf(t / (float)cols + EPSF);
    }
    __syncthreads();
    const float sc = s_scale;
    for (int c = threadIdx.x; c < cols; c += 256)
        out[(size_t)row * cols + c] = f2bf(p[c] * sc * w[c]);
}

// ---------------------------------------------------------------------------
// rope_k: kv640 fp32 cols 512..575 -> roped bf16 [tok][64]
// ---------------------------------------------------------------------------
__global__ __launch_bounds__(64) void rope_k(
    const float* __restrict__ kv, unsigned short* __restrict__ krope_bf)
{
    const int tok = blockIdx.x;
    const int s = tok & (SEQ - 1);
    const int j = threadIdx.x;
    const int jj = j & 31;
    float inv = powf(10000.0f, -(float)(2 * jj) / 64.0f);
    float f = (float)s * inv;
    float sn, cs;
    sincosf(f, &sn, &cs);
    const float* kb = kv + (size_t)tok * 640 + 512;
    float v = (j < 32) ? (kb[j] * cs - kb[j + 32] * sn)
                       : (kb[j] * cs + kb[j - 32] * sn);
    krope_bf[(size_t)tok * 64 + j] = f2bf(v);
}

// ---------------------------------------------------------------------------
// pack_q: qbuf bf16 (tok,3072) -> q_bf [b][h][s][192], RoPE'd + scaled
// ---------------------------------------------------------------------------
__global__ __launch_bounds__(256) void pack_q(
    const unsigned short* __restrict__ qbuf, unsigned short* __restrict__ q_bf)
{
    const int tok = blockIdx.x;
    const int b = tok >> 11, s = tok & (SEQ - 1);
    const unsigned short* src = qbuf + (size_t)tok * 3072;
    const float scale = 0.07216878364870323f;  // 1/sqrt(192)
#pragma unroll
    for (int t = 0; t < 12; ++t) {
        int i = threadIdx.x + t * 256;
        int h = i / 192, d = i - h * 192;
        float v = bf2f(src[i]);
        if (d >= 128) {
            int j = (d - 128) & 31;
            float inv = powf(10000.0f, -(float)(2 * j) / 64.0f);
            float f = (float)s * inv;
            float sn, cs;
            sincosf(f, &sn, &cs);
            if (d < 160) v = v * cs - bf2f(src[i + 32]) * sn;
            else         v = v * cs + bf2f(src[i - 32]) * sn;
        }
        q_bf[((size_t)(b * NHEADS + h) * SEQ + s) * 192 + d] = f2bf(v * scale);
    }
}

// ---------------------------------------------------------------------------
// pack_k: k_bf [b][h][s][192] = [ kvb nope(128) | krope_bf(64) ]
// ---------------------------------------------------------------------------
__global__ __launch_bounds__(256) void pack_k(
    const unsigned short* __restrict__ kvb, const unsigned short* __restrict__ krope_bf,
    unsigned short* __restrict__ k_bf)
{
    const int tok = blockIdx.x;
    const int b = tok >> 11, s = tok & (SEQ - 1);
#pragma unroll
    for (int t = 0; t < 12; ++t) {
        int i = threadIdx.x + t * 256;
        int h = i / 192, d = i - h * 192;
        unsigned short o;
        if (d < 128) o = kvb[(size_t)tok * 4096 + h * 256 + d];
        else         o = krope_bf[(size_t)tok * 64 + (d - 128)];
        k_bf[((size_t)(b * NHEADS + h) * SEQ + s) * 192 + d] = o;
    }
}

// ---------------------------------------------------------------------------
// pack_vt: vt_bf [b][h][d=128][s] = kvb_bf[tok][h*256+128+d] (transpose)
// ---------------------------------------------------------------------------
__global__ __launch_bounds__(256) void pack_vt(
    const unsigned short* __restrict__ kvb, unsigned short* __restrict__ vt_bf)
{
    __shared__ __align__(16) unsigned short T[64][136];
    const int st = blockIdx.x, h = blockIdx.y, b = blockIdx.z;
    const int tid = threadIdx.x;
#pragma unroll
    for (int t = 0; t < 4; ++t) {
        int i = tid + t * 256;
        int r = i >> 4, c8 = i & 15;
        bf16x8 v = *(const bf16x8*)(kvb + (size_t)(b * SEQ + st * 64 + r) * 4096 + h * 256 + 128 + c8 * 8);
        *(bf16x8*)&T[r][c8 * 8] = v;
    }
    __syncthreads();
    const int d = tid >> 1, sh = (tid & 1) * 32;
    unsigned short tmp[32];
#pragma unroll
    for (int k = 0; k < 32; ++k) tmp[k] = T[sh + k][d];
    unsigned short* dst = vt_bf + ((size_t)(b * NHEADS + h) * 128 + d) * SEQ + st * 64 + sh;
#pragma unroll
    for (int c = 0; c < 4; ++c) *(bf16x8*)(dst + c * 8) = *(bf16x8*)&tmp[c * 8];
}

// ---------------------------------------------------------------------------
// MFMA flash attention, epilogue writes bf16 ctx.
// ---------------------------------------------------------------------------
#define KPD 200
#define VPD 72
#define PPD 72

__global__ __launch_bounds__(256) void flash_mfma(
    const unsigned short* __restrict__ q_bf,
    const unsigned short* __restrict__ k_bf,
    const unsigned short* __restrict__ vt_bf,
    unsigned short* __restrict__ ctx)
{
    __shared__ __align__(16) unsigned short Ks[64][KPD];
    __shared__ __align__(16) unsigned short Vs[128][VPD];
    __shared__ __align__(16) unsigned short Ps[4][16][PPD];
    const int qt = (int)gridDim.x - 1 - (int)blockIdx.x;
    const int h = blockIdx.y, b = blockIdx.z;
    const int tid = threadIdx.x;
    const int wid = tid >> 6, lane = tid & 63;
    const int l16 = lane & 15, lq = lane >> 4;

    const size_t headQ = (size_t)(b * NHEADS + h) * SEQ * 192;
    const size_t headV = (size_t)(b * NHEADS + h) * 128 * SEQ;

    bf16x8 qf[6];
    {
        const unsigned short* qp = q_bf + headQ + (size_t)(qt * 64 + wid * 16 + l16) * 192 + lq * 8;
#pragma unroll
        for (int kk = 0; kk < 6; ++kk) qf[kk] = *(const bf16x8*)(qp + kk * 32);
    }

    f32x4 o[8];
#pragma unroll
    for (int f = 0; f < 8; ++f) o[f] = (f32x4){0.f, 0.f, 0.f, 0.f};
    float m[4] = {-1e30f, -1e30f, -1e30f, -1e30f};
    float lsum[4] = {0.f, 0.f, 0.f, 0.f};

    const int nkt = qt + 1;
    for (int kt = 0; kt < nkt; ++kt) {
        __syncthreads();
#pragma unroll
        for (int t = 0; t < 6; ++t) {
            int i = tid + t * 256;
            int r = i / 24, c8 = i % 24;
            bf16x8 v = *(const bf16x8*)(k_bf + headQ + (size_t)(kt * 64 + r) * 192 + c8 * 8);
            *(bf16x8*)&Ks[r][c8 * 8] = v;
        }
#pragma unroll
        for (int t = 0; t < 4; ++t) {
            int i = tid + t * 256;
            int r = i >> 3, c8 = i & 7;
            bf16x8 v = *(const bf16x8*)(vt_bf + headV + (size_t)r * SEQ + kt * 64 + c8 * 8);
            *(bf16x8*)&Vs[r][c8 * 8] = v;
        }
        __syncthreads();

        f32x4 s[4];
#pragma unroll
        for (int f = 0; f < 4; ++f) s[f] = (f32x4){0.f, 0.f, 0.f, 0.f};
#pragma unroll
        for (int f = 0; f < 4; ++f) {
#pragma unroll
            for (int kk = 0; kk < 6; ++kk) {
                bf16x8 bfr = *(const bf16x8*)&Ks[f * 16 + l16][kk * 32 + lq * 8];
                s[f] = __builtin_amdgcn_mfma_f32_16x16x32_bf16(qf[kk], bfr, s[f], 0, 0, 0);
            }
        }

        const int qabs = qt * 64 + wid * 16 + lq * 4;
        const bool diag = (kt == qt);
#pragma unroll
        for (int reg = 0; reg < 4; ++reg) {
            float a0 = s[0][reg], a1 = s[1][reg], a2 = s[2][reg], a3 = s[3][reg];
            if (diag) {
                int q = qabs + reg;
                int k0 = kt * 64 + l16;
                if (k0      > q) a0 = -1e30f;
                if (k0 + 16 > q) a1 = -1e30f;
                if (k0 + 32 > q) a2 = -1e30f;
                if (k0 + 48 > q) a3 = -1e30f;
            }
            float rmax = fmaxf(fmaxf(a0, a1), fmaxf(a2, a3));
            rmax = fmaxf(rmax, __shfl_xor(rmax, 1, 64));
            rmax = fmaxf(rmax, __shfl_xor(rmax, 2, 64));
            rmax = fmaxf(rmax, __shfl_xor(rmax, 4, 64));
            rmax = fmaxf(rmax, __shfl_xor(rmax, 8, 64));
            float mnew = fmaxf(m[reg], rmax);
            float sc = __expf(m[reg] - mnew);
            m[reg] = mnew;
            float p0 = __expf(a0 - mnew), p1 = __expf(a1 - mnew);
            float p2 = __expf(a2 - mnew), p3 = __expf(a3 - mnew);
            float rs = p0 + p1 + p2 + p3;
            rs += __shfl_xor(rs, 1, 64);
            rs += __shfl_xor(rs, 2, 64);
            rs += __shfl_xor(rs, 4, 64);
            rs += __shfl_xor(rs, 8, 64);
            lsum[reg] = lsum[reg] * sc + rs;
#pragma unroll
            for (int f = 0; f < 8; ++f) o[f][reg] *= sc;
            Ps[wid][lq * 4 + reg][ 0 + l16] = f2bf(p0);
            Ps[wid][lq * 4 + reg][16 + l16] = f2bf(p1);
            Ps[wid][lq * 4 + reg][32 + l16] = f2bf(p2);
            Ps[wid][lq * 4 + reg][48 + l16] = f2bf(p3);
        }

        bf16x8 pa0 = *(const bf16x8*)&Ps[wid][l16][lq * 8];
        bf16x8 pa1 = *(const bf16x8*)&Ps[wid][l16][32 + lq * 8];
#pragma unroll
        for (int f = 0; f < 8; ++f) {
            bf16x8 b0 = *(const bf16x8*)&Vs[f * 16 + l16][lq * 8];
            bf16x8 b1 = *(const bf16x8*)&Vs[f * 16 + l16][32 + lq * 8];
            o[f] = __builtin_amdgcn_mfma_f32_16x16x32_bf16(pa0, b0, o[f], 0, 0, 0);
            o[f] = __builtin_amdgcn_mfma_f32_16x16x32_bf16(pa1, b1, o[f], 0, 0, 0);
        }
    }

#pragma unroll
    for (int reg = 0; reg < 4; ++reg) {
        float inv = 1.0f / lsum[reg];
        unsigned short* dst = ctx + (size_t)(b * SEQ + qt * 64 + wid * 16 + lq * 4 + reg) * 2048 + h * 128 + l16;
#pragma unroll
        for (int f = 0; f < 8; ++f) dst[f * 16] = f2bf(o[f][reg] * inv);
    }
}

// ---------------------------------------------------------------------------
extern "C" void kernel_launch(void* const* d_in, const int* in_sizes, int n_in,
                              void* d_out, int out_size, void* d_ws, size_t ws_size,
                              hipStream_t stream) {
    const float* x          = (const float*)d_in[0];
    const float* q_a_w      = (const float*)d_in[1];
    const float* q_a_norm_w = (const float*)d_in[2];
    const float* q_b_w      = (const float*)d_in[3];
    const float* kv_a_w     = (const float*)d_in[4];
    const float* kv_norm_w  = (const float*)d_in[5];
    const float* kv_b_w     = (const float*)d_in[6];
    const float* o_w        = (const float*)d_in[7];
    float* out = (float*)d_out;

    char* ws = (char*)d_ws;
    float*          q_a      = (float*)(ws + 0);                   // 4096x1536 f32
    unsigned short* q_bf     = (unsigned short*)(ws + 0);          // overlay after q_a dead
    unsigned short* qbuf_bf  = (unsigned short*)(ws + 25165824);   // 4096x3072 bf16
    unsigned short* k_bf     = (unsigned short*)(ws + 25165824);   // overlay after qbuf dead
    unsigned short* vt_bf    = (unsigned short*)(ws + 50331648);   // 2x16x128x2048 bf16
    unsigned short* kvb_bf   = (unsigned short*)(ws + 67108864);   // 4096x4096 bf16
    unsigned short* ctx_bf   = (unsigned short*)(ws + 67108864);   // overlay after kvb dead
    float*          kv640    = (float*)(ws + 100663296);           // 4096x640 f32
    unsigned short* x_bf     = (unsigned short*)(ws + 111149056);  // 4096x2048 bf16
    unsigned short* q_a_bf   = (unsigned short*)(ws + 111149056);  // overlay after x_bf dead
    unsigned short* kv_c_bf  = (unsigned short*)(ws + 127926272);  // 4096x512 bf16
    unsigned short* krope_bf = (unsigned short*)(ws + 132120576);  // 4096x64 bf16
    unsigned short* wqa_t    = (unsigned short*)(ws + 132644864);  // 1536x2048
    unsigned short* wqb_t    = (unsigned short*)(ws + 138936320);  // 3072x1536
    unsigned short* wkva_t   = (unsigned short*)(ws + 148373504);  // 640x2048 (pad)
    unsigned short* wkvb_t   = (unsigned short*)(ws + 150994944);  // 4096x512
    unsigned short* wo_t     = (unsigned short*)(ws + 155189248);  // 2048x2048

    dim3 blk(256);

    // conversions
    cvt_bf16<<<4096, blk, 0, stream>>>(x, x_bf);
    transpose_cvt<<<dim3(48, 64),  blk, 0, stream>>>(q_a_w,  wqa_t,  1536, 2048);
    transpose_cvt<<<dim3(96, 48),  blk, 0, stream>>>(q_b_w,  wqb_t,  3072, 1536);
    transpose_cvt<<<dim3(20, 64),  blk, 0, stream>>>(kv_a_w, wkva_t, 576,  2048);
    transpose_cvt<<<dim3(128, 16), blk, 0, stream>>>(kv_b_w, wkvb_t, 4096, 512);
    transpose_cvt<<<dim3(64, 64),  blk, 0, stream>>>(o_w,    wo_t,   2048, 2048);

    // projections
    gemm_bt<0><<<dim3(12, 32), blk, 0, stream>>>(x_bf, wqa_t, q_a, 2048, 1536);
    gemm_bt<0><<<dim3(5, 32),  blk, 0, stream>>>(x_bf, wkva_t, kv640, 2048, 640);
    rmsnorm_bf<<<NTOK, blk, 0, stream>>>(q_a, q_a_norm_w, q_a_bf, 1536, 1536);
    rmsnorm_bf<<<NTOK, blk, 0, stream>>>(kv640, kv_norm_w, kv_c_bf, 640, 512);
    gemm_bt<1><<<dim3(24, 32), blk, 0, stream>>>(q_a_bf, wqb_t, qbuf_bf, 1536, 3072);
    gemm_bt<1><<<dim3(32, 32), blk, 0, stream>>>(kv_c_bf, wkvb_t, kvb_bf, 512, 4096);

    // attention prep
    rope_k<<<NTOK, dim3(64), 0, stream>>>(kv640, krope_bf);
    pack_q<<<NTOK, blk, 0, stream>>>(qbuf_bf, q_bf);
    pack_k<<<NTOK, blk, 0, stream>>>(kvb_bf, krope_bf, k_bf);
    pack_vt<<<dim3(SEQ / 64, NHEADS, BATCH), blk, 0, stream>>>(kvb_bf, vt_bf);

    // attention
    flash_mfma<<<dim3(SEQ / 64, NHEADS, BATCH), blk, 0, stream>>>(q_bf, k_bf, vt_bf, ctx_bf);

    // output projection
    gemm_bt<0><<<dim3(16, 32), blk, 0, stream>>>(ctx_bf, wo_t, out, 2048, 2048);
}

// Round 6
// 449.265 us; speedup vs baseline: 13.3591x; 1.2065x over previous
//
#include <hip/hip_runtime.h>
#include <hip/hip_bf16.h>
#include <math.h>

#define NHEADS 16
#define SEQ 2048
#define BATCH 2
#define NTOK (BATCH * SEQ)
#define EPSF 1e-6f

typedef short bf16x8 __attribute__((ext_vector_type(8)));
typedef float f32x4 __attribute__((ext_vector_type(4)));

__device__ __forceinline__ unsigned short f2bf(float v) {
    __hip_bfloat16 h = __float2bfloat16(v);
    return *reinterpret_cast<unsigned short*>(&h);
}
__device__ __forceinline__ float bf2f(unsigned short u) {
    __hip_bfloat16 h = *reinterpret_cast<__hip_bfloat16*>(&u);
    return __bfloat162float(h);
}
__device__ __forceinline__ void g2l16(const void* g, void* l) {
    __builtin_amdgcn_global_load_lds(
        (const __attribute__((address_space(1))) void*)g,
        (__attribute__((address_space(3))) void*)l, 16, 0, 0);
}

// log2(10000) * 2 / 64
#define ROPE_L2 0.4152410118609203f

// ---------------------------------------------------------------------------
// x fp32 -> bf16 (8 elems/thread)
// ---------------------------------------------------------------------------
__global__ __launch_bounds__(256) void cvt_bf16(
    const float* __restrict__ in, unsigned short* __restrict__ out)
{
    const int i = blockIdx.x * 256 + threadIdx.x;
    float4 a = ((const float4*)in)[i * 2];
    float4 b = ((const float4*)in)[i * 2 + 1];
    unsigned short o[8] = {f2bf(a.x), f2bf(a.y), f2bf(a.z), f2bf(a.w),
                           f2bf(b.x), f2bf(b.y), f2bf(b.z), f2bf(b.w)};
    *(bf16x8*)(out + (size_t)i * 8) = *(bf16x8*)o;
}

// ---------------------------------------------------------------------------
// weight transpose+convert: w [K][Nw] fp32 -> wt [Npad][K] bf16
// ---------------------------------------------------------------------------
__global__ __launch_bounds__(256) void transpose_cvt(
    const float* __restrict__ w, unsigned short* __restrict__ wt,
    int Nw, int K)
{
    __shared__ float T[32][33];
    const int n0 = blockIdx.x * 32, k0 = blockIdx.y * 32;
    const int tid = threadIdx.x;
    const int r = tid >> 3, c4 = (tid & 7) * 4;
    const bool valid = (n0 < Nw);
    if (valid) {
        float4 v = *(const float4*)(w + (size_t)(k0 + r) * Nw + n0 + c4);
        T[r][c4 + 0] = v.x; T[r][c4 + 1] = v.y; T[r][c4 + 2] = v.z; T[r][c4 + 3] = v.w;
    }
    __syncthreads();
    unsigned short o[4];
#pragma unroll
    for (int j = 0; j < 4; ++j) o[j] = valid ? f2bf(T[c4 + j][r]) : (unsigned short)0;
    *(ulong1*)(wt + (size_t)(n0 + r) * K + k0 + c4) = *(ulong1*)o;
}

// ---------------------------------------------------------------------------
// bf16 MFMA GEMM: C[M,N] = A[M,K](bf16) @ Bt[N,K](bf16)^T. 128x128 tile, BK=32.
// ---------------------------------------------------------------------------
template <int OUT_BF16>
__global__ __launch_bounds__(256) void gemm_bt(
    const unsigned short* __restrict__ A,
    const unsigned short* __restrict__ Bt,
    void* __restrict__ Cv,
    int K, int N)
{
    __shared__ __align__(16) unsigned short As[128 * 32];
    __shared__ __align__(16) unsigned short Bs[128 * 32];
    const int tid = threadIdx.x;
    const int lane = tid & 63, wid = tid >> 6;
    const int l16 = lane & 15, lq = lane >> 4;
    const int wr = wid >> 1, wc = wid & 1;
    const int bm = blockIdx.y * 128, bn = blockIdx.x * 128;

    f32x4 acc[4][4];
#pragma unroll
    for (int m = 0; m < 4; ++m)
#pragma unroll
        for (int n = 0; n < 4; ++n) acc[m][n] = (f32x4){0.f, 0.f, 0.f, 0.f};

    for (int k0 = 0; k0 < K; k0 += 32) {
        __syncthreads();
#pragma unroll
        for (int t = 0; t < 2; ++t) {
            const int chunk = t * 256 + tid;
            const int row = chunk >> 2, koff = (chunk & 3) << 3;
            g2l16(A  + (size_t)(bm + row) * K + k0 + koff, (char*)As + chunk * 16);
            g2l16(Bt + (size_t)(bn + row) * K + k0 + koff, (char*)Bs + chunk * 16);
        }
        __syncthreads();

        bf16x8 af[4], bfr[4];
#pragma unroll
        for (int m = 0; m < 4; ++m)
            af[m] = *(const bf16x8*)(As + (wr * 64 + m * 16 + l16) * 32 + lq * 8);
#pragma unroll
        for (int n = 0; n < 4; ++n)
            bfr[n] = *(const bf16x8*)(Bs + (wc * 64 + n * 16 + l16) * 32 + lq * 8);
#pragma unroll
        for (int m = 0; m < 4; ++m)
#pragma unroll
            for (int n = 0; n < 4; ++n)
                acc[m][n] = __builtin_amdgcn_mfma_f32_16x16x32_bf16(af[m], bfr[n], acc[m][n], 0, 0, 0);
    }

#pragma unroll
    for (int m = 0; m < 4; ++m)
#pragma unroll
        for (int n = 0; n < 4; ++n)
#pragma unroll
            for (int reg = 0; reg < 4; ++reg) {
                const int row = bm + wr * 64 + m * 16 + lq * 4 + reg;
                const int col = bn + wc * 64 + n * 16 + l16;
                if (OUT_BF16) ((unsigned short*)Cv)[(size_t)row * N + col] = f2bf(acc[m][n][reg]);
                else          ((float*)Cv)[(size_t)row * N + col] = acc[m][n][reg];
            }
}

// ---------------------------------------------------------------------------
// RMSNorm: fp32 in -> bf16 compact out
// ---------------------------------------------------------------------------
__global__ __launch_bounds__(256) void rmsnorm_bf(
    const float* __restrict__ in, const float* __restrict__ w,
    unsigned short* __restrict__ out, int in_stride, int cols)
{
    const int row = blockIdx.x;
    const float* p = in + (size_t)row * in_stride;
    float ss = 0.f;
    for (int c = threadIdx.x; c < cols; c += 256) { float v = p[c]; ss += v * v; }
#pragma unroll
    for (int off = 32; off > 0; off >>= 1) ss += __shfl_down(ss, off, 64);
    __shared__ float wsum[4];
    __shared__ float s_scale;
    const int wave = threadIdx.x >> 6;
    if ((threadIdx.x & 63) == 0) wsum[wave] = ss;
    __syncthreads();
    if (threadIdx.x == 0) {
        float t = wsum[0] + wsum[1] + wsum[2] + wsum[3];
        s_scale = rsqrtf(t / (float)cols + EPSF);
    }
    __syncthreads();
    const float sc = s_scale;
    for (int c = threadIdx.x; c < cols; c += 256)
        out[(size_t)row * cols + c] = f2bf(p[c] * sc * w[c]);
}

// ---------------------------------------------------------------------------
// rope_k: kv640 fp32 cols 512..575 -> roped bf16 [tok][64]
// ---------------------------------------------------------------------------
__global__ __launch_bounds__(64) void rope_k(
    const float* __restrict__ kv, unsigned short* __restrict__ krope_bf)
{
    const int tok = blockIdx.x;
    const int s = tok & (SEQ - 1);
    const int j = threadIdx.x;
    const int jj = j & 31;
    float inv = exp2f(-ROPE_L2 * (float)jj);
    float f = (float)s * inv;
    float sn, cs;
    sincosf(f, &sn, &cs);
    const float* kb = kv + (size_t)tok * 640 + 512;
    float v = (j < 32) ? (kb[j] * cs - kb[j + 32] * sn)
                       : (kb[j] * cs + kb[j - 32] * sn);
    krope_bf[(size_t)tok * 64 + j] = f2bf(v);
}

// ---------------------------------------------------------------------------
// pack_q: qbuf bf16 (tok,3072) -> q_bf [b][h][s][192], RoPE'd + scaled
// ---------------------------------------------------------------------------
__global__ __launch_bounds__(256) void pack_q(
    const unsigned short* __restrict__ qbuf, unsigned short* __restrict__ q_bf)
{
    const int tok = blockIdx.x;
    const int b = tok >> 11, s = tok & (SEQ - 1);
    const unsigned short* src = qbuf + (size_t)tok * 3072;
    const float scale = 0.07216878364870323f;  // 1/sqrt(192)
#pragma unroll
    for (int t = 0; t < 12; ++t) {
        int i = threadIdx.x + t * 256;
        int h = i / 192, d = i - h * 192;
        float v = bf2f(src[i]);
        if (d >= 128) {
            int j = (d - 128) & 31;
            float inv = exp2f(-ROPE_L2 * (float)j);
            float f = (float)s * inv;
            float sn, cs;
            sincosf(f, &sn, &cs);
            if (d < 160) v = v * cs - bf2f(src[i + 32]) * sn;
            else         v = v * cs + bf2f(src[i - 32]) * sn;
        }
        q_bf[((size_t)(b * NHEADS + h) * SEQ + s) * 192 + d] = f2bf(v * scale);
    }
}

// ---------------------------------------------------------------------------
// pack_k: k_bf [b][h][s][192] = [ kvb nope(128) | krope_bf(64) ]
// ---------------------------------------------------------------------------
__global__ __launch_bounds__(256) void pack_k(
    const unsigned short* __restrict__ kvb, const unsigned short* __restrict__ krope_bf,
    unsigned short* __restrict__ k_bf)
{
    const int tok = blockIdx.x;
    const int b = tok >> 11, s = tok & (SEQ - 1);
#pragma unroll
    for (int t = 0; t < 12; ++t) {
        int i = threadIdx.x + t * 256;
        int h = i / 192, d = i - h * 192;
        unsigned short o;
        if (d < 128) o = kvb[(size_t)tok * 4096 + h * 256 + d];
        else         o = krope_bf[(size_t)tok * 64 + (d - 128)];
        k_bf[((size_t)(b * NHEADS + h) * SEQ + s) * 192 + d] = o;
    }
}

// ---------------------------------------------------------------------------
// pack_vt: vt_bf [b][h][d=128][s] = kvb_bf[tok][h*256+128+d] (transpose)
// ---------------------------------------------------------------------------
__global__ __launch_bounds__(256) void pack_vt(
    const unsigned short* __restrict__ kvb, unsigned short* __restrict__ vt_bf)
{
    __shared__ __align__(16) unsigned short T[64][136];
    const int st = blockIdx.x, h = blockIdx.y, b = blockIdx.z;
    const int tid = threadIdx.x;
#pragma unroll
    for (int t = 0; t < 4; ++t) {
        int i = tid + t * 256;
        int r = i >> 4, c8 = i & 15;
        bf16x8 v = *(const bf16x8*)(kvb + (size_t)(b * SEQ + st * 64 + r) * 4096 + h * 256 + 128 + c8 * 8);
        *(bf16x8*)&T[r][c8 * 8] = v;
    }
    __syncthreads();
    const int d = tid >> 1, sh = (tid & 1) * 32;
    unsigned short tmp[32];
#pragma unroll
    for (int k = 0; k < 32; ++k) tmp[k] = T[sh + k][d];
    unsigned short* dst = vt_bf + ((size_t)(b * NHEADS + h) * 128 + d) * SEQ + st * 64 + sh;
#pragma unroll
    for (int c = 0; c < 4; ++c) *(bf16x8*)(dst + c * 8) = *(bf16x8*)&tmp[c * 8];
}

// ---------------------------------------------------------------------------
// MFMA flash attention, causal, PAIRED q-tiles for load balance:
// block p handles qt=p (pass 0) and qt=31-p (pass 1) -> uniform 33 kt-iters.
// Grid (16, 16, 2) = 512 blocks = exactly 2 blocks/CU, all resident.
// ---------------------------------------------------------------------------
#define KPD 200
#define VPD 72
#define PPD 72

__global__ __launch_bounds__(256) void flash_mfma(
    const unsigned short* __restrict__ q_bf,
    const unsigned short* __restrict__ k_bf,
    const unsigned short* __restrict__ vt_bf,
    unsigned short* __restrict__ ctx)
{
    __shared__ __align__(16) unsigned short Ks[64][KPD];
    __shared__ __align__(16) unsigned short Vs[128][VPD];
    __shared__ __align__(16) unsigned short Ps[4][16][PPD];
    const int pair = blockIdx.x;
    const int h = blockIdx.y, b = blockIdx.z;
    const int tid = threadIdx.x;
    const int wid = tid >> 6, lane = tid & 63;
    const int l16 = lane & 15, lq = lane >> 4;

    const size_t headQ = (size_t)(b * NHEADS + h) * SEQ * 192;
    const size_t headV = (size_t)(b * NHEADS + h) * 128 * SEQ;

    // div-free staging coords
    const int krow = tid >> 2, kg = tid & 3;   // K: 4 threads/row, 6 chunks each
    const int vrow = tid >> 1, vg = tid & 1;   // V: 2 threads/row, 4 chunks each

#pragma unroll
    for (int pass = 0; pass < 2; ++pass) {
        const int qt = pass ? (31 - pair) : pair;

        bf16x8 qf[6];
        {
            const unsigned short* qp = q_bf + headQ + (size_t)(qt * 64 + wid * 16 + l16) * 192 + lq * 8;
#pragma unroll
            for (int kk = 0; kk < 6; ++kk) qf[kk] = *(const bf16x8*)(qp + kk * 32);
        }

        f32x4 o[8];
#pragma unroll
        for (int f = 0; f < 8; ++f) o[f] = (f32x4){0.f, 0.f, 0.f, 0.f};
        float m[4] = {-1e30f, -1e30f, -1e30f, -1e30f};
        float lsum[4] = {0.f, 0.f, 0.f, 0.f};

        const int nkt = qt + 1;
        for (int kt = 0; kt < nkt; ++kt) {
            __syncthreads();   // prev tile fully consumed (or pass start)
            {
                const unsigned short* ksrc = k_bf + headQ + (size_t)(kt * 64 + krow) * 192 + kg * 8;
#pragma unroll
                for (int j = 0; j < 6; ++j)
                    *(bf16x8*)&Ks[krow][(kg + j * 4) * 8] = *(const bf16x8*)(ksrc + j * 32);
                const unsigned short* vsrc = vt_bf + headV + (size_t)vrow * SEQ + kt * 64 + vg * 8;
#pragma unroll
                for (int j = 0; j < 4; ++j)
                    *(bf16x8*)&Vs[vrow][(vg + j * 2) * 8] = *(const bf16x8*)(vsrc + j * 16);
            }
            __syncthreads();

            // S = Q(16x192) @ K^T(192x64)
            f32x4 s[4];
#pragma unroll
            for (int f = 0; f < 4; ++f) s[f] = (f32x4){0.f, 0.f, 0.f, 0.f};
            __builtin_amdgcn_s_setprio(1);
#pragma unroll
            for (int f = 0; f < 4; ++f) {
#pragma unroll
                for (int kk = 0; kk < 6; ++kk) {
                    bf16x8 bfr = *(const bf16x8*)&Ks[f * 16 + l16][kk * 32 + lq * 8];
                    s[f] = __builtin_amdgcn_mfma_f32_16x16x32_bf16(qf[kk], bfr, s[f], 0, 0, 0);
                }
            }
            __builtin_amdgcn_s_setprio(0);

            const int qabs = qt * 64 + wid * 16 + lq * 4;
            const bool diag = (kt == qt);
#pragma unroll
            for (int reg = 0; reg < 4; ++reg) {
                float a0 = s[0][reg], a1 = s[1][reg], a2 = s[2][reg], a3 = s[3][reg];
                if (diag) {
                    int q = qabs + reg;
                    int k0 = kt * 64 + l16;
                    if (k0      > q) a0 = -1e30f;
                    if (k0 + 16 > q) a1 = -1e30f;
                    if (k0 + 32 > q) a2 = -1e30f;
                    if (k0 + 48 > q) a3 = -1e30f;
                }
                float rmax = fmaxf(fmaxf(a0, a1), fmaxf(a2, a3));
                rmax = fmaxf(rmax, __shfl_xor(rmax, 1, 64));
                rmax = fmaxf(rmax, __shfl_xor(rmax, 2, 64));
                rmax = fmaxf(rmax, __shfl_xor(rmax, 4, 64));
                rmax = fmaxf(rmax, __shfl_xor(rmax, 8, 64));
                float mnew = fmaxf(m[reg], rmax);
                float sc = __expf(m[reg] - mnew);
                m[reg] = mnew;
                float p0 = __expf(a0 - mnew), p1 = __expf(a1 - mnew);
                float p2 = __expf(a2 - mnew), p3 = __expf(a3 - mnew);
                float rs = p0 + p1 + p2 + p3;
                rs += __shfl_xor(rs, 1, 64);
                rs += __shfl_xor(rs, 2, 64);
                rs += __shfl_xor(rs, 4, 64);
                rs += __shfl_xor(rs, 8, 64);
                lsum[reg] = lsum[reg] * sc + rs;
#pragma unroll
                for (int f = 0; f < 8; ++f) o[f][reg] *= sc;
                Ps[wid][lq * 4 + reg][ 0 + l16] = f2bf(p0);
                Ps[wid][lq * 4 + reg][16 + l16] = f2bf(p1);
                Ps[wid][lq * 4 + reg][32 + l16] = f2bf(p2);
                Ps[wid][lq * 4 + reg][48 + l16] = f2bf(p3);
            }

            bf16x8 pa0 = *(const bf16x8*)&Ps[wid][l16][lq * 8];
            bf16x8 pa1 = *(const bf16x8*)&Ps[wid][l16][32 + lq * 8];
            __builtin_amdgcn_s_setprio(1);
#pragma unroll
            for (int f = 0; f < 8; ++f) {
                bf16x8 b0 = *(const bf16x8*)&Vs[f * 16 + l16][lq * 8];
                bf16x8 b1 = *(const bf16x8*)&Vs[f * 16 + l16][32 + lq * 8];
                o[f] = __builtin_amdgcn_mfma_f32_16x16x32_bf16(pa0, b0, o[f], 0, 0, 0);
                o[f] = __builtin_amdgcn_mfma_f32_16x16x32_bf16(pa1, b1, o[f], 0, 0, 0);
            }
            __builtin_amdgcn_s_setprio(0);
        }

#pragma unroll
        for (int reg = 0; reg < 4; ++reg) {
            float inv = 1.0f / lsum[reg];
            unsigned short* dst = ctx + (size_t)(b * SEQ + qt * 64 + wid * 16 + lq * 4 + reg) * 2048 + h * 128 + l16;
#pragma unroll
            for (int f = 0; f < 8; ++f) dst[f * 16] = f2bf(o[f][reg] * inv);
        }
    }
}

// ---------------------------------------------------------------------------
extern "C" void kernel_launch(void* const* d_in, const int* in_sizes, int n_in,
                              void* d_out, int out_size, void* d_ws, size_t ws_size,
                              hipStream_t stream) {
    const float* x          = (const float*)d_in[0];
    const float* q_a_w      = (const float*)d_in[1];
    const float* q_a_norm_w = (const float*)d_in[2];
    const float* q_b_w      = (const float*)d_in[3];
    const float* kv_a_w     = (const float*)d_in[4];
    const float* kv_norm_w  = (const float*)d_in[5];
    const float* kv_b_w     = (const float*)d_in[6];
    const float* o_w        = (const float*)d_in[7];
    float* out = (float*)d_out;

    char* ws = (char*)d_ws;
    float*          q_a      = (float*)(ws + 0);                   // 4096x1536 f32
    unsigned short* q_bf     = (unsigned short*)(ws + 0);          // overlay after q_a dead
    unsigned short* qbuf_bf  = (unsigned short*)(ws + 25165824);   // 4096x3072 bf16
    unsigned short* k_bf     = (unsigned short*)(ws + 25165824);   // overlay after qbuf dead
    unsigned short* vt_bf    = (unsigned short*)(ws + 50331648);   // 2x16x128x2048 bf16
    unsigned short* kvb_bf   = (unsigned short*)(ws + 67108864);   // 4096x4096 bf16
    unsigned short* ctx_bf   = (unsigned short*)(ws + 67108864);   // overlay after kvb dead
    float*          kv640    = (float*)(ws + 100663296);           // 4096x640 f32
    unsigned short* x_bf     = (unsigned short*)(ws + 111149056);  // 4096x2048 bf16
    unsigned short* q_a_bf   = (unsigned short*)(ws + 111149056);  // overlay after x_bf dead
    unsigned short* kv_c_bf  = (unsigned short*)(ws + 127926272);  // 4096x512 bf16
    unsigned short* krope_bf = (unsigned short*)(ws + 132120576);  // 4096x64 bf16
    unsigned short* wqa_t    = (unsigned short*)(ws + 132644864);  // 1536x2048
    unsigned short* wqb_t    = (unsigned short*)(ws + 138936320);  // 3072x1536
    unsigned short* wkva_t   = (unsigned short*)(ws + 148373504);  // 640x2048 (pad)
    unsigned short* wkvb_t   = (unsigned short*)(ws + 150994944);  // 4096x512
    unsigned short* wo_t     = (unsigned short*)(ws + 155189248);  // 2048x2048

    dim3 blk(256);

    // conversions
    cvt_bf16<<<4096, blk, 0, stream>>>(x, x_bf);
    transpose_cvt<<<dim3(48, 64),  blk, 0, stream>>>(q_a_w,  wqa_t,  1536, 2048);
    transpose_cvt<<<dim3(96, 48),  blk, 0, stream>>>(q_b_w,  wqb_t,  3072, 1536);
    transpose_cvt<<<dim3(20, 64),  blk, 0, stream>>>(kv_a_w, wkva_t, 576,  2048);
    transpose_cvt<<<dim3(128, 16), blk, 0, stream>>>(kv_b_w, wkvb_t, 4096, 512);
    transpose_cvt<<<dim3(64, 64),  blk, 0, stream>>>(o_w,    wo_t,   2048, 2048);

    // projections
    gemm_bt<0><<<dim3(12, 32), blk, 0, stream>>>(x_bf, wqa_t, q_a, 2048, 1536);
    gemm_bt<0><<<dim3(5, 32),  blk, 0, stream>>>(x_bf, wkva_t, kv640, 2048, 640);
    rmsnorm_bf<<<NTOK, blk, 0, stream>>>(q_a, q_a_norm_w, q_a_bf, 1536, 1536);
    rmsnorm_bf<<<NTOK, blk, 0, stream>>>(kv640, kv_norm_w, kv_c_bf, 640, 512);
    gemm_bt<1><<<dim3(24, 32), blk, 0, stream>>>(q_a_bf, wqb_t, qbuf_bf, 1536, 3072);
    gemm_bt<1><<<dim3(32, 32), blk, 0, stream>>>(kv_c_bf, wkvb_t, kvb_bf, 512, 4096);

    // attention prep
    rope_k<<<NTOK, dim3(64), 0, stream>>>(kv640, krope_bf);
    pack_q<<<NTOK, blk, 0, stream>>>(qbuf_bf, q_bf);
    pack_k<<<NTOK, blk, 0, stream>>>(kvb_bf, krope_bf, k_bf);
    pack_vt<<<dim3(SEQ / 64, NHEADS, BATCH), blk, 0, stream>>>(kvb_bf, vt_bf);

    // attention (paired q-tiles, 512 blocks = 2/CU, uniform work)
    flash_mfma<<<dim3(16, NHEADS, BATCH), blk, 0, stream>>>(q_bf, k_bf, vt_bf, ctx_bf);

    // output projection
    gemm_bt<0><<<dim3(16, 32), blk, 0, stream>>>(ctx_bf, wo_t, out, 2048, 2048);
}

// Round 7
// 415.265 us; speedup vs baseline: 14.4528x; 1.0819x over previous
//
#include <hip/hip_runtime.h>
#include <hip/hip_bf16.h>
#include <math.h>

#define NHEADS 16
#define SEQ 2048
#define BATCH 2
#define NTOK (BATCH * SEQ)
#define EPSF 1e-6f

typedef short bf16x8 __attribute__((ext_vector_type(8)));
typedef float f32x4 __attribute__((ext_vector_type(4)));

__device__ __forceinline__ unsigned short f2bf(float v) {
    __hip_bfloat16 h = __float2bfloat16(v);
    return *reinterpret_cast<unsigned short*>(&h);
}
__device__ __forceinline__ float bf2f(unsigned short u) {
    __hip_bfloat16 h = *reinterpret_cast<__hip_bfloat16*>(&u);
    return __bfloat162float(h);
}
__device__ __forceinline__ void g2l16(const void* g, void* l) {
    __builtin_amdgcn_global_load_lds(
        (const __attribute__((address_space(1))) void*)g,
        (__attribute__((address_space(3))) void*)l, 16, 0, 0);
}

// log2(10000) * 2 / 64
#define ROPE_L2 0.4152410118609203f

// ---------------------------------------------------------------------------
// x fp32 -> bf16 (8 elems/thread)
// ---------------------------------------------------------------------------
__global__ __launch_bounds__(256) void cvt_bf16(
    const float* __restrict__ in, unsigned short* __restrict__ out)
{
    const int i = blockIdx.x * 256 + threadIdx.x;
    float4 a = ((const float4*)in)[i * 2];
    float4 b = ((const float4*)in)[i * 2 + 1];
    unsigned short o[8] = {f2bf(a.x), f2bf(a.y), f2bf(a.z), f2bf(a.w),
                           f2bf(b.x), f2bf(b.y), f2bf(b.z), f2bf(b.w)};
    *(bf16x8*)(out + (size_t)i * 8) = *(bf16x8*)o;
}

// ---------------------------------------------------------------------------
// weight transpose+convert: w [K][Nw] fp32 -> wt [Npad][K] bf16
// ---------------------------------------------------------------------------
__global__ __launch_bounds__(256) void transpose_cvt(
    const float* __restrict__ w, unsigned short* __restrict__ wt,
    int Nw, int K)
{
    __shared__ float T[32][33];
    const int n0 = blockIdx.x * 32, k0 = blockIdx.y * 32;
    const int tid = threadIdx.x;
    const int r = tid >> 3, c4 = (tid & 7) * 4;
    const bool valid = (n0 < Nw);
    if (valid) {
        float4 v = *(const float4*)(w + (size_t)(k0 + r) * Nw + n0 + c4);
        T[r][c4 + 0] = v.x; T[r][c4 + 1] = v.y; T[r][c4 + 2] = v.z; T[r][c4 + 3] = v.w;
    }
    __syncthreads();
    unsigned short o[4];
#pragma unroll
    for (int j = 0; j < 4; ++j) o[j] = valid ? f2bf(T[c4 + j][r]) : (unsigned short)0;
    *(ulong1*)(wt + (size_t)(n0 + r) * K + k0 + c4) = *(ulong1*)o;
}

// ---------------------------------------------------------------------------
// bf16 MFMA GEMM: C[M,N] = A[M,K](bf16) @ Bt[N,K](bf16)^T. 128x128 tile, BK=32.
// ---------------------------------------------------------------------------
template <int OUT_BF16>
__global__ __launch_bounds__(256) void gemm_bt(
    const unsigned short* __restrict__ A,
    const unsigned short* __restrict__ Bt,
    void* __restrict__ Cv,
    int K, int N)
{
    __shared__ __align__(16) unsigned short As[128 * 32];
    __shared__ __align__(16) unsigned short Bs[128 * 32];
    const int tid = threadIdx.x;
    const int lane = tid & 63, wid = tid >> 6;
    const int l16 = lane & 15, lq = lane >> 4;
    const int wr = wid >> 1, wc = wid & 1;
    const int bm = blockIdx.y * 128, bn = blockIdx.x * 128;

    f32x4 acc[4][4];
#pragma unroll
    for (int m = 0; m < 4; ++m)
#pragma unroll
        for (int n = 0; n < 4; ++n) acc[m][n] = (f32x4){0.f, 0.f, 0.f, 0.f};

    for (int k0 = 0; k0 < K; k0 += 32) {
        __syncthreads();
#pragma unroll
        for (int t = 0; t < 2; ++t) {
            const int chunk = t * 256 + tid;
            const int row = chunk >> 2, koff = (chunk & 3) << 3;
            g2l16(A  + (size_t)(bm + row) * K + k0 + koff, (char*)As + chunk * 16);
            g2l16(Bt + (size_t)(bn + row) * K + k0 + koff, (char*)Bs + chunk * 16);
        }
        __syncthreads();

        bf16x8 af[4], bfr[4];
#pragma unroll
        for (int m = 0; m < 4; ++m)
            af[m] = *(const bf16x8*)(As + (wr * 64 + m * 16 + l16) * 32 + lq * 8);
#pragma unroll
        for (int n = 0; n < 4; ++n)
            bfr[n] = *(const bf16x8*)(Bs + (wc * 64 + n * 16 + l16) * 32 + lq * 8);
#pragma unroll
        for (int m = 0; m < 4; ++m)
#pragma unroll
            for (int n = 0; n < 4; ++n)
                acc[m][n] = __builtin_amdgcn_mfma_f32_16x16x32_bf16(af[m], bfr[n], acc[m][n], 0, 0, 0);
    }

#pragma unroll
    for (int m = 0; m < 4; ++m)
#pragma unroll
        for (int n = 0; n < 4; ++n)
#pragma unroll
            for (int reg = 0; reg < 4; ++reg) {
                const int row = bm + wr * 64 + m * 16 + lq * 4 + reg;
                const int col = bn + wc * 64 + n * 16 + l16;
                if (OUT_BF16) ((unsigned short*)Cv)[(size_t)row * N + col] = f2bf(acc[m][n][reg]);
                else          ((float*)Cv)[(size_t)row * N + col] = acc[m][n][reg];
            }
}

// ---------------------------------------------------------------------------
// RMSNorm: fp32 in -> bf16 compact out
// ---------------------------------------------------------------------------
__global__ __launch_bounds__(256) void rmsnorm_bf(
    const float* __restrict__ in, const float* __restrict__ w,
    unsigned short* __restrict__ out, int in_stride, int cols)
{
    const int row = blockIdx.x;
    const float* p = in + (size_t)row * in_stride;
    float ss = 0.f;
    for (int c = threadIdx.x; c < cols; c += 256) { float v = p[c]; ss += v * v; }
#pragma unroll
    for (int off = 32; off > 0; off >>= 1) ss += __shfl_down(ss, off, 64);
    __shared__ float wsum[4];
    __shared__ float s_scale;
    const int wave = threadIdx.x >> 6;
    if ((threadIdx.x & 63) == 0) wsum[wave] = ss;
    __syncthreads();
    if (threadIdx.x == 0) {
        float t = wsum[0] + wsum[1] + wsum[2] + wsum[3];
        s_scale = rsqrtf(t / (float)cols + EPSF);
    }
    __syncthreads();
    const float sc = s_scale;
    for (int c = threadIdx.x; c < cols; c += 256)
        out[(size_t)row * cols + c] = f2bf(p[c] * sc * w[c]);
}

// ---------------------------------------------------------------------------
// rope_k: kv640 fp32 cols 512..575 -> roped bf16 [tok][64]
// ---------------------------------------------------------------------------
__global__ __launch_bounds__(64) void rope_k(
    const float* __restrict__ kv, unsigned short* __restrict__ krope_bf)
{
    const int tok = blockIdx.x;
    const int s = tok & (SEQ - 1);
    const int j = threadIdx.x;
    const int jj = j & 31;
    float inv = exp2f(-ROPE_L2 * (float)jj);
    float f = (float)s * inv;
    float sn, cs;
    sincosf(f, &sn, &cs);
    const float* kb = kv + (size_t)tok * 640 + 512;
    float v = (j < 32) ? (kb[j] * cs - kb[j + 32] * sn)
                       : (kb[j] * cs + kb[j - 32] * sn);
    krope_bf[(size_t)tok * 64 + j] = f2bf(v);
}

// ---------------------------------------------------------------------------
// pack_vt: vt_bf [b][h][d=128][s] = kvb_bf[tok][h*256+128+d] (transpose)
// ---------------------------------------------------------------------------
__global__ __launch_bounds__(256) void pack_vt(
    const unsigned short* __restrict__ kvb, unsigned short* __restrict__ vt_bf)
{
    __shared__ __align__(16) unsigned short T[64][136];
    const int st = blockIdx.x, h = blockIdx.y, b = blockIdx.z;
    const int tid = threadIdx.x;
#pragma unroll
    for (int t = 0; t < 4; ++t) {
        int i = tid + t * 256;
        int r = i >> 4, c8 = i & 15;
        bf16x8 v = *(const bf16x8*)(kvb + (size_t)(b * SEQ + st * 64 + r) * 4096 + h * 256 + 128 + c8 * 8);
        *(bf16x8*)&T[r][c8 * 8] = v;
    }
    __syncthreads();
    const int d = tid >> 1, sh = (tid & 1) * 32;
    unsigned short tmp[32];
#pragma unroll
    for (int k = 0; k < 32; ++k) tmp[k] = T[sh + k][d];
    unsigned short* dst = vt_bf + ((size_t)(b * NHEADS + h) * 128 + d) * SEQ + st * 64 + sh;
#pragma unroll
    for (int c = 0; c < 4; ++c) *(bf16x8*)(dst + c * 8) = *(bf16x8*)&tmp[c * 8];
}

// ---------------------------------------------------------------------------
// MFMA flash attention, causal, paired q-tiles + XCD swizzle.
// Reads qbuf (RoPE folded into Q-load), kvb (K-nope), krope, vt. No pack_q/k.
// Grid: 512 1D blocks; xcd = id&7 keeps each (b,h)'s K/V on one XCD's L2.
// ---------------------------------------------------------------------------
#define KPD 200
#define VPD 72
#define PPD 72

__global__ __launch_bounds__(256) void flash_mfma(
    const unsigned short* __restrict__ qbuf,   // [tok][3072]
    const unsigned short* __restrict__ kvb,    // [tok][4096]
    const unsigned short* __restrict__ krope,  // [tok][64]
    const unsigned short* __restrict__ vt,     // [b][h][128][SEQ]
    unsigned short* __restrict__ ctx)          // [tok][2048]
{
    __shared__ __align__(16) unsigned short Ks[64][KPD];
    __shared__ __align__(16) unsigned short Vs[128][VPD];
    __shared__ __align__(16) unsigned short Ps[4][16][PPD];
    const int id = blockIdx.x;
    const int xcd = id & 7, sl = id >> 3;
    const int grp = sl >> 4, pair = sl & 15;
    const int hb = xcd + 8 * grp;          // 0..31
    const int h = hb & 15, b = hb >> 4;
    const int tid = threadIdx.x;
    const int wid = tid >> 6, lane = tid & 63;
    const int l16 = lane & 15, lq = lane >> 4;

    const size_t headV = (size_t)(b * NHEADS + h) * 128 * SEQ;
    const float scale = 0.07216878364870323f;  // 1/sqrt(192)

    // per-lane rope cos/sin for j = lq*8 + jj
    float cs8[8], sn8[8];

    const int vrow = tid >> 1, vg = tid & 1;

#pragma unroll
    for (int pass = 0; pass < 2; ++pass) {
        const int qt = pass ? (31 - pair) : pair;
        const int srow = qt * 64 + wid * 16 + l16;   // seq position of this lane's q-row

        // Q fragments with in-register RoPE + scale
        bf16x8 qf[6];
        {
            const unsigned short* qp = qbuf + (size_t)(b * SEQ + srow) * 3072 + h * 192 + lq * 8;
            bf16x8 raw[6];
#pragma unroll
            for (int kk = 0; kk < 6; ++kk) raw[kk] = *(const bf16x8*)(qp + kk * 32);
#pragma unroll
            for (int jj = 0; jj < 8; ++jj) {
                float inv = exp2f(-ROPE_L2 * (float)(lq * 8 + jj));
                sincosf((float)srow * inv, &sn8[jj], &cs8[jj]);
            }
#pragma unroll
            for (int kk = 0; kk < 4; ++kk) {
                unsigned short o[8];
#pragma unroll
                for (int e = 0; e < 8; ++e) o[e] = f2bf(bf2f(((unsigned short*)&raw[kk])[e]) * scale);
                qf[kk] = *(bf16x8*)o;
            }
            unsigned short o4[8], o5[8];
#pragma unroll
            for (int e = 0; e < 8; ++e) {
                float x1 = bf2f(((unsigned short*)&raw[4])[e]);
                float x2 = bf2f(((unsigned short*)&raw[5])[e]);
                o4[e] = f2bf((x1 * cs8[e] - x2 * sn8[e]) * scale);
                o5[e] = f2bf((x2 * cs8[e] + x1 * sn8[e]) * scale);
            }
            qf[4] = *(bf16x8*)o4;
            qf[5] = *(bf16x8*)o5;
        }

        f32x4 o[8];
#pragma unroll
        for (int f = 0; f < 8; ++f) o[f] = (f32x4){0.f, 0.f, 0.f, 0.f};
        float m[4] = {-1e30f, -1e30f, -1e30f, -1e30f};
        float lsum[4] = {0.f, 0.f, 0.f, 0.f};

        const int nkt = qt + 1;
        for (int kt = 0; kt < nkt; ++kt) {
            __syncthreads();   // prev tile fully consumed (or pass start)
            {
                const int tk0 = b * SEQ + kt * 64;
                // K nope: 64 rows x 128 elems from kvb
#pragma unroll
                for (int t = 0; t < 4; ++t) {
                    int i = tid + t * 256;
                    int r = i >> 4, c8 = i & 15;
                    *(bf16x8*)&Ks[r][c8 * 8] =
                        *(const bf16x8*)(kvb + (size_t)(tk0 + r) * 4096 + h * 256 + c8 * 8);
                }
                // K rope: 64 rows x 64 elems from krope
#pragma unroll
                for (int t = 0; t < 2; ++t) {
                    int i = tid + t * 256;
                    int r = i >> 3, c8 = i & 7;
                    *(bf16x8*)&Ks[r][128 + c8 * 8] =
                        *(const bf16x8*)(krope + (size_t)(tk0 + r) * 64 + c8 * 8);
                }
                // V^T tile
                const unsigned short* vsrc = vt + headV + (size_t)vrow * SEQ + kt * 64 + vg * 8;
#pragma unroll
                for (int j = 0; j < 4; ++j)
                    *(bf16x8*)&Vs[vrow][(vg + j * 2) * 8] = *(const bf16x8*)(vsrc + j * 16);
            }
            __syncthreads();

            // S = Q(16x192) @ K^T(192x64)
            f32x4 s[4];
#pragma unroll
            for (int f = 0; f < 4; ++f) s[f] = (f32x4){0.f, 0.f, 0.f, 0.f};
            __builtin_amdgcn_s_setprio(1);
#pragma unroll
            for (int f = 0; f < 4; ++f) {
#pragma unroll
                for (int kk = 0; kk < 6; ++kk) {
                    bf16x8 bfr = *(const bf16x8*)&Ks[f * 16 + l16][kk * 32 + lq * 8];
                    s[f] = __builtin_amdgcn_mfma_f32_16x16x32_bf16(qf[kk], bfr, s[f], 0, 0, 0);
                }
            }
            __builtin_amdgcn_s_setprio(0);

            const int qabs = qt * 64 + wid * 16 + lq * 4;
            const bool diag = (kt == qt);
#pragma unroll
            for (int reg = 0; reg < 4; ++reg) {
                float a0 = s[0][reg], a1 = s[1][reg], a2 = s[2][reg], a3 = s[3][reg];
                if (diag) {
                    int q = qabs + reg;
                    int k0 = kt * 64 + l16;
                    if (k0      > q) a0 = -1e30f;
                    if (k0 + 16 > q) a1 = -1e30f;
                    if (k0 + 32 > q) a2 = -1e30f;
                    if (k0 + 48 > q) a3 = -1e30f;
                }
                float rmax = fmaxf(fmaxf(a0, a1), fmaxf(a2, a3));
                rmax = fmaxf(rmax, __shfl_xor(rmax, 1, 64));
                rmax = fmaxf(rmax, __shfl_xor(rmax, 2, 64));
                rmax = fmaxf(rmax, __shfl_xor(rmax, 4, 64));
                rmax = fmaxf(rmax, __shfl_xor(rmax, 8, 64));
                float mnew = fmaxf(m[reg], rmax);
                float sc = __expf(m[reg] - mnew);
                m[reg] = mnew;
                float p0 = __expf(a0 - mnew), p1 = __expf(a1 - mnew);
                float p2 = __expf(a2 - mnew), p3 = __expf(a3 - mnew);
                float rs = p0 + p1 + p2 + p3;
                rs += __shfl_xor(rs, 1, 64);
                rs += __shfl_xor(rs, 2, 64);
                rs += __shfl_xor(rs, 4, 64);
                rs += __shfl_xor(rs, 8, 64);
                lsum[reg] = lsum[reg] * sc + rs;
#pragma unroll
                for (int f = 0; f < 8; ++f) o[f][reg] *= sc;
                Ps[wid][lq * 4 + reg][ 0 + l16] = f2bf(p0);
                Ps[wid][lq * 4 + reg][16 + l16] = f2bf(p1);
                Ps[wid][lq * 4 + reg][32 + l16] = f2bf(p2);
                Ps[wid][lq * 4 + reg][48 + l16] = f2bf(p3);
            }

            bf16x8 pa0 = *(const bf16x8*)&Ps[wid][l16][lq * 8];
            bf16x8 pa1 = *(const bf16x8*)&Ps[wid][l16][32 + lq * 8];
            __builtin_amdgcn_s_setprio(1);
#pragma unroll
            for (int f = 0; f < 8; ++f) {
                bf16x8 b0 = *(const bf16x8*)&Vs[f * 16 + l16][lq * 8];
                bf16x8 b1 = *(const bf16x8*)&Vs[f * 16 + l16][32 + lq * 8];
                o[f] = __builtin_amdgcn_mfma_f32_16x16x32_bf16(pa0, b0, o[f], 0, 0, 0);
                o[f] = __builtin_amdgcn_mfma_f32_16x16x32_bf16(pa1, b1, o[f], 0, 0, 0);
            }
            __builtin_amdgcn_s_setprio(0);
        }

#pragma unroll
        for (int reg = 0; reg < 4; ++reg) {
            float inv = 1.0f / lsum[reg];
            unsigned short* dst = ctx + (size_t)(b * SEQ + qt * 64 + wid * 16 + lq * 4 + reg) * 2048 + h * 128 + l16;
#pragma unroll
            for (int f = 0; f < 8; ++f) dst[f * 16] = f2bf(o[f][reg] * inv);
        }
    }
}

// ---------------------------------------------------------------------------
extern "C" void kernel_launch(void* const* d_in, const int* in_sizes, int n_in,
                              void* d_out, int out_size, void* d_ws, size_t ws_size,
                              hipStream_t stream) {
    const float* x          = (const float*)d_in[0];
    const float* q_a_w      = (const float*)d_in[1];
    const float* q_a_norm_w = (const float*)d_in[2];
    const float* q_b_w      = (const float*)d_in[3];
    const float* kv_a_w     = (const float*)d_in[4];
    const float* kv_norm_w  = (const float*)d_in[5];
    const float* kv_b_w     = (const float*)d_in[6];
    const float* o_w        = (const float*)d_in[7];
    float* out = (float*)d_out;

    char* ws = (char*)d_ws;
    float*          q_a      = (float*)(ws + 0);                   // 4096x1536 f32 (25.2MB)
    unsigned short* ctx_bf   = (unsigned short*)(ws + 0);          // overlay after q_a dead (16.8MB)
    unsigned short* qbuf_bf  = (unsigned short*)(ws + 25165824);   // 4096x3072 bf16 (25.2MB)
    unsigned short* vt_bf    = (unsigned short*)(ws + 50331648);   // 2x16x128x2048 bf16 (16.8MB)
    unsigned short* kvb_bf   = (unsigned short*)(ws + 67108864);   // 4096x4096 bf16 (33.6MB)
    float*          kv640    = (float*)(ws + 100663296);           // 4096x640 f32 (10.5MB)
    unsigned short* x_bf     = (unsigned short*)(ws + 111149056);  // 4096x2048 bf16 (16.8MB)
    unsigned short* q_a_bf   = (unsigned short*)(ws + 111149056);  // overlay after x_bf dead
    unsigned short* kv_c_bf  = (unsigned short*)(ws + 127926272);  // 4096x512 bf16
    unsigned short* krope_bf = (unsigned short*)(ws + 132120576);  // 4096x64 bf16
    unsigned short* wqa_t    = (unsigned short*)(ws + 132644864);  // 1536x2048
    unsigned short* wqb_t    = (unsigned short*)(ws + 138936320);  // 3072x1536
    unsigned short* wkva_t   = (unsigned short*)(ws + 148373504);  // 640x2048 (pad)
    unsigned short* wkvb_t   = (unsigned short*)(ws + 150994944);  // 4096x512
    unsigned short* wo_t     = (unsigned short*)(ws + 155189248);  // 2048x2048

    dim3 blk(256);

    // conversions
    cvt_bf16<<<4096, blk, 0, stream>>>(x, x_bf);
    transpose_cvt<<<dim3(48, 64),  blk, 0, stream>>>(q_a_w,  wqa_t,  1536, 2048);
    transpose_cvt<<<dim3(96, 48),  blk, 0, stream>>>(q_b_w,  wqb_t,  3072, 1536);
    transpose_cvt<<<dim3(20, 64),  blk, 0, stream>>>(kv_a_w, wkva_t, 576,  2048);
    transpose_cvt<<<dim3(128, 16), blk, 0, stream>>>(kv_b_w, wkvb_t, 4096, 512);
    transpose_cvt<<<dim3(64, 64),  blk, 0, stream>>>(o_w,    wo_t,   2048, 2048);

    // projections
    gemm_bt<0><<<dim3(12, 32), blk, 0, stream>>>(x_bf, wqa_t, q_a, 2048, 1536);
    gemm_bt<0><<<dim3(5, 32),  blk, 0, stream>>>(x_bf, wkva_t, kv640, 2048, 640);
    rmsnorm_bf<<<NTOK, blk, 0, stream>>>(q_a, q_a_norm_w, q_a_bf, 1536, 1536);
    rmsnorm_bf<<<NTOK, blk, 0, stream>>>(kv640, kv_norm_w, kv_c_bf, 640, 512);
    gemm_bt<1><<<dim3(24, 32), blk, 0, stream>>>(q_a_bf, wqb_t, qbuf_bf, 1536, 3072);
    gemm_bt<1><<<dim3(32, 32), blk, 0, stream>>>(kv_c_bf, wkvb_t, kvb_bf, 512, 4096);

    // attention prep
    rope_k<<<NTOK, dim3(64), 0, stream>>>(kv640, krope_bf);
    pack_vt<<<dim3(SEQ / 64, NHEADS, BATCH), blk, 0, stream>>>(kvb_bf, vt_bf);

    // attention (paired q-tiles, XCD-swizzled, RoPE fused into Q-load)
    flash_mfma<<<dim3(512), blk, 0, stream>>>(qbuf_bf, kvb_bf, krope_bf, vt_bf, ctx_bf);

    // output projection
    gemm_bt<0><<<dim3(16, 32), blk, 0, stream>>>(ctx_bf, wo_t, out, 2048, 2048);
}

// Round 8
// 386.541 us; speedup vs baseline: 15.5268x; 1.0743x over previous
//
#include <hip/hip_runtime.h>
#include <hip/hip_bf16.h>
#include <math.h>

#define NHEADS 16
#define SEQ 2048
#define BATCH 2
#define NTOK (BATCH * SEQ)
#define EPSF 1e-6f

typedef short bf16x8 __attribute__((ext_vector_type(8)));
typedef float f32x4 __attribute__((ext_vector_type(4)));

__device__ __forceinline__ unsigned short f2bf(float v) {
    __hip_bfloat16 h = __float2bfloat16(v);
    return *reinterpret_cast<unsigned short*>(&h);
}
__device__ __forceinline__ float bf2f(unsigned short u) {
    __hip_bfloat16 h = *reinterpret_cast<__hip_bfloat16*>(&u);
    return __bfloat162float(h);
}
__device__ __forceinline__ void g2l16(const void* g, void* l) {
    __builtin_amdgcn_global_load_lds(
        (const __attribute__((address_space(1))) void*)g,
        (__attribute__((address_space(3))) void*)l, 16, 0, 0);
}

// log2(10000) * 2 / 64
#define ROPE_L2 0.4152410118609203f

// ---------------------------------------------------------------------------
// x fp32 -> bf16 (8 elems/thread)
// ---------------------------------------------------------------------------
__global__ __launch_bounds__(256) void cvt_bf16(
    const float* __restrict__ in, unsigned short* __restrict__ out)
{
    const int i = blockIdx.x * 256 + threadIdx.x;
    float4 a = ((const float4*)in)[i * 2];
    float4 b = ((const float4*)in)[i * 2 + 1];
    unsigned short o[8] = {f2bf(a.x), f2bf(a.y), f2bf(a.z), f2bf(a.w),
                           f2bf(b.x), f2bf(b.y), f2bf(b.z), f2bf(b.w)};
    *(bf16x8*)(out + (size_t)i * 8) = *(bf16x8*)o;
}

// ---------------------------------------------------------------------------
// prep_weights: all 5 weight transposes (fp32 [K][Nw] -> bf16 [Npad][K]) in
// one launch. Segment chosen by block id against offset table.
// ---------------------------------------------------------------------------
struct WSeg { const float* src; unsigned short* dst; int Nw, K, nx, off; };
struct WSegs { WSeg s[5]; };

__global__ __launch_bounds__(256) void prep_weights(WSegs segs)
{
    __shared__ float T[32][33];
    const int bid = blockIdx.x;
    int si = 0;
#pragma unroll
    for (int i = 1; i < 5; ++i) si += (bid >= segs.s[i].off) ? 1 : 0;
    const WSeg sg = segs.s[si];
    const int local = bid - sg.off;
    const int bx = local % sg.nx, by = local / sg.nx;
    const int n0 = bx * 32, k0 = by * 32;
    const int tid = threadIdx.x;
    const int r = tid >> 3, c4 = (tid & 7) * 4;
    const bool valid = (n0 < sg.Nw);
    if (valid) {
        float4 v = *(const float4*)(sg.src + (size_t)(k0 + r) * sg.Nw + n0 + c4);
        T[r][c4 + 0] = v.x; T[r][c4 + 1] = v.y; T[r][c4 + 2] = v.z; T[r][c4 + 3] = v.w;
    }
    __syncthreads();
    unsigned short o[4];
#pragma unroll
    for (int j = 0; j < 4; ++j) o[j] = valid ? f2bf(T[c4 + j][r]) : (unsigned short)0;
    *(ulong1*)(sg.dst + (size_t)(n0 + r) * sg.K + k0 + c4) = *(ulong1*)o;
}

// ---------------------------------------------------------------------------
// bf16 MFMA GEMM: C[M,N] = A[M,K](bf16) @ Bt[N,K](bf16)^T. 128x128 tile, BK=32.
// ---------------------------------------------------------------------------
template <int OUT_BF16>
__global__ __launch_bounds__(256) void gemm_bt(
    const unsigned short* __restrict__ A,
    const unsigned short* __restrict__ Bt,
    void* __restrict__ Cv,
    int K, int N)
{
    __shared__ __align__(16) unsigned short As[128 * 32];
    __shared__ __align__(16) unsigned short Bs[128 * 32];
    const int tid = threadIdx.x;
    const int lane = tid & 63, wid = tid >> 6;
    const int l16 = lane & 15, lq = lane >> 4;
    const int wr = wid >> 1, wc = wid & 1;
    const int bm = blockIdx.y * 128, bn = blockIdx.x * 128;

    f32x4 acc[4][4];
#pragma unroll
    for (int m = 0; m < 4; ++m)
#pragma unroll
        for (int n = 0; n < 4; ++n) acc[m][n] = (f32x4){0.f, 0.f, 0.f, 0.f};

    for (int k0 = 0; k0 < K; k0 += 32) {
        __syncthreads();
#pragma unroll
        for (int t = 0; t < 2; ++t) {
            const int chunk = t * 256 + tid;
            const int row = chunk >> 2, koff = (chunk & 3) << 3;
            g2l16(A  + (size_t)(bm + row) * K + k0 + koff, (char*)As + chunk * 16);
            g2l16(Bt + (size_t)(bn + row) * K + k0 + koff, (char*)Bs + chunk * 16);
        }
        __syncthreads();

        bf16x8 af[4], bfr[4];
#pragma unroll
        for (int m = 0; m < 4; ++m)
            af[m] = *(const bf16x8*)(As + (wr * 64 + m * 16 + l16) * 32 + lq * 8);
#pragma unroll
        for (int n = 0; n < 4; ++n)
            bfr[n] = *(const bf16x8*)(Bs + (wc * 64 + n * 16 + l16) * 32 + lq * 8);
#pragma unroll
        for (int m = 0; m < 4; ++m)
#pragma unroll
            for (int n = 0; n < 4; ++n)
                acc[m][n] = __builtin_amdgcn_mfma_f32_16x16x32_bf16(af[m], bfr[n], acc[m][n], 0, 0, 0);
    }

#pragma unroll
    for (int m = 0; m < 4; ++m)
#pragma unroll
        for (int n = 0; n < 4; ++n)
#pragma unroll
            for (int reg = 0; reg < 4; ++reg) {
                const int row = bm + wr * 64 + m * 16 + lq * 4 + reg;
                const int col = bn + wc * 64 + n * 16 + l16;
                if (OUT_BF16) ((unsigned short*)Cv)[(size_t)row * N + col] = f2bf(acc[m][n][reg]);
                else          ((float*)Cv)[(size_t)row * N + col] = acc[m][n][reg];
            }
}

// ---------------------------------------------------------------------------
// RMSNorm: fp32 in (base pre-offset, row stride) -> bf16 compact out
// ---------------------------------------------------------------------------
__global__ __launch_bounds__(256) void rmsnorm_bf(
    const float* __restrict__ in, const float* __restrict__ w,
    unsigned short* __restrict__ out, int in_stride, int cols)
{
    const int row = blockIdx.x;
    const float* p = in + (size_t)row * in_stride;
    float ss = 0.f;
    for (int c = threadIdx.x; c < cols; c += 256) { float v = p[c]; ss += v * v; }
#pragma unroll
    for (int off = 32; off > 0; off >>= 1) ss += __shfl_down(ss, off, 64);
    __shared__ float wsum[4];
    __shared__ float s_scale;
    const int wave = threadIdx.x >> 6;
    if ((threadIdx.x & 63) == 0) wsum[wave] = ss;
    __syncthreads();
    if (threadIdx.x == 0) {
        float t = wsum[0] + wsum[1] + wsum[2] + wsum[3];
        s_scale = rsqrtf(t / (float)cols + EPSF);
    }
    __syncthreads();
    const float sc = s_scale;
    for (int c = threadIdx.x; c < cols; c += 256)
        out[(size_t)row * cols + c] = f2bf(p[c] * sc * w[c]);
}

// ---------------------------------------------------------------------------
// rmsnorm_kv_rope: in = qkv_cat + 1536 (stride 2176).
//   cols 0..511  -> RMSNorm -> kv_c_bf [row][512]
//   cols 512..575 -> RoPE   -> krope_bf [row][64]
// ---------------------------------------------------------------------------
__global__ __launch_bounds__(256) void rmsnorm_kv_rope(
    const float* __restrict__ in, const float* __restrict__ w,
    unsigned short* __restrict__ kv_out, unsigned short* __restrict__ krope_out)
{
    const int row = blockIdx.x;
    const float* p = in + (size_t)row * 2176;
    const int tid = threadIdx.x;
    float v0 = p[tid], v1 = p[tid + 256];
    float ss = v0 * v0 + v1 * v1;
#pragma unroll
    for (int off = 32; off > 0; off >>= 1) ss += __shfl_down(ss, off, 64);
    __shared__ float wsum[4];
    __shared__ float s_scale;
    const int wave = tid >> 6;
    if ((tid & 63) == 0) wsum[wave] = ss;
    __syncthreads();
    if (tid == 0) {
        float t = wsum[0] + wsum[1] + wsum[2] + wsum[3];
        s_scale = rsqrtf(t / 512.0f + EPSF);
    }
    __syncthreads();
    const float sc = s_scale;
    kv_out[(size_t)row * 512 + tid]       = f2bf(v0 * sc * w[tid]);
    kv_out[(size_t)row * 512 + tid + 256] = f2bf(v1 * sc * w[tid + 256]);
    if (tid < 64) {
        const int s = row & (SEQ - 1);
        const int j = tid, jj = j & 31;
        float inv = exp2f(-ROPE_L2 * (float)jj);
        float f = (float)s * inv;
        float sn, cs;
        sincosf(f, &sn, &cs);
        const float* kb = p + 512;
        float v = (j < 32) ? (kb[j] * cs - kb[j + 32] * sn)
                           : (kb[j] * cs + kb[j - 32] * sn);
        krope_out[(size_t)row * 64 + j] = f2bf(v);
    }
}

// ---------------------------------------------------------------------------
// pack_vt: vt_bf [b][h][d=128][s] = kvb_bf[tok][h*256+128+d] (transpose)
// ---------------------------------------------------------------------------
__global__ __launch_bounds__(256) void pack_vt(
    const unsigned short* __restrict__ kvb, unsigned short* __restrict__ vt_bf)
{
    __shared__ __align__(16) unsigned short T[64][136];
    const int st = blockIdx.x, h = blockIdx.y, b = blockIdx.z;
    const int tid = threadIdx.x;
#pragma unroll
    for (int t = 0; t < 4; ++t) {
        int i = tid + t * 256;
        int r = i >> 4, c8 = i & 15;
        bf16x8 v = *(const bf16x8*)(kvb + (size_t)(b * SEQ + st * 64 + r) * 4096 + h * 256 + 128 + c8 * 8);
        *(bf16x8*)&T[r][c8 * 8] = v;
    }
    __syncthreads();
    const int d = tid >> 1, sh = (tid & 1) * 32;
    unsigned short tmp[32];
#pragma unroll
    for (int k = 0; k < 32; ++k) tmp[k] = T[sh + k][d];
    unsigned short* dst = vt_bf + ((size_t)(b * NHEADS + h) * 128 + d) * SEQ + st * 64 + sh;
#pragma unroll
    for (int c = 0; c < 4; ++c) *(bf16x8*)(dst + c * 8) = *(bf16x8*)&tmp[c * 8];
}

// ---------------------------------------------------------------------------
// MFMA flash attention, causal, paired q-tiles + XCD swizzle + register
// double-buffered K/V staging (async-STAGE split: issue loads for kt+1 right
// after publishing kt to LDS; latency hides under QK/softmax/PV compute).
// ---------------------------------------------------------------------------
#define KPD 200
#define VPD 72
#define PPD 72

__global__ __launch_bounds__(256) void flash_mfma(
    const unsigned short* __restrict__ qbuf,   // [tok][3072]
    const unsigned short* __restrict__ kvb,    // [tok][4096]
    const unsigned short* __restrict__ krope,  // [tok][64]
    const unsigned short* __restrict__ vt,     // [b][h][128][SEQ]
    unsigned short* __restrict__ ctx)          // [tok][2048]
{
    __shared__ __align__(16) unsigned short Ks[64][KPD];
    __shared__ __align__(16) unsigned short Vs[128][VPD];
    __shared__ __align__(16) unsigned short Ps[4][16][PPD];
    const int id = blockIdx.x;
    const int xcd = id & 7, sl = id >> 3;
    const int grp = sl >> 4, pair = sl & 15;
    const int hb = xcd + 8 * grp;          // 0..31
    const int h = hb & 15, b = hb >> 4;
    const int tid = threadIdx.x;
    const int wid = tid >> 6, lane = tid & 63;
    const int l16 = lane & 15, lq = lane >> 4;

    const size_t headV = (size_t)(b * NHEADS + h) * 128 * SEQ;
    const float scale = 0.07216878364870323f;  // 1/sqrt(192)

    float cs8[8], sn8[8];
    const int vrow = tid >> 1, vg = tid & 1;

    // staging registers (double buffer in regs)
    bf16x8 kn[4], kr[2], vv[4];

#define FLASH_LOAD(KT)                                                          \
    {                                                                           \
        const int tk0_ = b * SEQ + (KT) * 64;                                   \
        _Pragma("unroll")                                                       \
        for (int t = 0; t < 4; ++t) {                                           \
            int i_ = tid + t * 256, r_ = i_ >> 4, c8_ = i_ & 15;                \
            kn[t] = *(const bf16x8*)(kvb + (size_t)(tk0_ + r_) * 4096 + h * 256 + c8_ * 8); \
        }                                                                       \
        _Pragma("unroll")                                                       \
        for (int t = 0; t < 2; ++t) {                                           \
            int i_ = tid + t * 256, r_ = i_ >> 3, c8_ = i_ & 7;                 \
            kr[t] = *(const bf16x8*)(krope + (size_t)(tk0_ + r_) * 64 + c8_ * 8); \
        }                                                                       \
        const unsigned short* vsrc_ = vt + headV + (size_t)vrow * SEQ + (KT) * 64 + vg * 8; \
        _Pragma("unroll")                                                       \
        for (int j = 0; j < 4; ++j) vv[j] = *(const bf16x8*)(vsrc_ + j * 16);   \
    }

#pragma unroll
    for (int pass = 0; pass < 2; ++pass) {
        const int qt = pass ? (31 - pair) : pair;
        const int srow = qt * 64 + wid * 16 + l16;

        // Q fragments with in-register RoPE + scale
        bf16x8 qf[6];
        {
            const unsigned short* qp = qbuf + (size_t)(b * SEQ + srow) * 3072 + h * 192 + lq * 8;
            bf16x8 raw[6];
#pragma unroll
            for (int kk = 0; kk < 6; ++kk) raw[kk] = *(const bf16x8*)(qp + kk * 32);
#pragma unroll
            for (int jj = 0; jj < 8; ++jj) {
                float inv = exp2f(-ROPE_L2 * (float)(lq * 8 + jj));
                sincosf((float)srow * inv, &sn8[jj], &cs8[jj]);
            }
#pragma unroll
            for (int kk = 0; kk < 4; ++kk) {
                unsigned short o[8];
#pragma unroll
                for (int e = 0; e < 8; ++e) o[e] = f2bf(bf2f(((unsigned short*)&raw[kk])[e]) * scale);
                qf[kk] = *(bf16x8*)o;
            }
            unsigned short o4[8], o5[8];
#pragma unroll
            for (int e = 0; e < 8; ++e) {
                float x1 = bf2f(((unsigned short*)&raw[4])[e]);
                float x2 = bf2f(((unsigned short*)&raw[5])[e]);
                o4[e] = f2bf((x1 * cs8[e] - x2 * sn8[e]) * scale);
                o5[e] = f2bf((x2 * cs8[e] + x1 * sn8[e]) * scale);
            }
            qf[4] = *(bf16x8*)o4;
            qf[5] = *(bf16x8*)o5;
        }

        f32x4 o[8];
#pragma unroll
        for (int f = 0; f < 8; ++f) o[f] = (f32x4){0.f, 0.f, 0.f, 0.f};
        float m[4] = {-1e30f, -1e30f, -1e30f, -1e30f};
        float lsum[4] = {0.f, 0.f, 0.f, 0.f};

        const int nkt = qt + 1;
        FLASH_LOAD(0);
        for (int kt = 0; kt < nkt; ++kt) {
            __syncthreads();   // prev tile's LDS fully consumed
            // publish regs -> LDS
#pragma unroll
            for (int t = 0; t < 4; ++t) {
                int i = tid + t * 256, r = i >> 4, c8 = i & 15;
                *(bf16x8*)&Ks[r][c8 * 8] = kn[t];
            }
#pragma unroll
            for (int t = 0; t < 2; ++t) {
                int i = tid + t * 256, r = i >> 3, c8 = i & 7;
                *(bf16x8*)&Ks[r][128 + c8 * 8] = kr[t];
            }
#pragma unroll
            for (int j = 0; j < 4; ++j)
                *(bf16x8*)&Vs[vrow][(vg + j * 2) * 8] = vv[j];
            __syncthreads();
            // issue next tile's loads; latency hides under compute below
            if (kt + 1 < nkt) FLASH_LOAD(kt + 1);

            // S = Q(16x192) @ K^T(192x64)
            f32x4 s[4];
#pragma unroll
            for (int f = 0; f < 4; ++f) s[f] = (f32x4){0.f, 0.f, 0.f, 0.f};
            __builtin_amdgcn_s_setprio(1);
#pragma unroll
            for (int f = 0; f < 4; ++f) {
#pragma unroll
                for (int kk = 0; kk < 6; ++kk) {
                    bf16x8 bfr = *(const bf16x8*)&Ks[f * 16 + l16][kk * 32 + lq * 8];
                    s[f] = __builtin_amdgcn_mfma_f32_16x16x32_bf16(qf[kk], bfr, s[f], 0, 0, 0);
                }
            }
            __builtin_amdgcn_s_setprio(0);

            const int qabs = qt * 64 + wid * 16 + lq * 4;
            const bool diag = (kt == qt);
#pragma unroll
            for (int reg = 0; reg < 4; ++reg) {
                float a0 = s[0][reg], a1 = s[1][reg], a2 = s[2][reg], a3 = s[3][reg];
                if (diag) {
                    int q = qabs + reg;
                    int k0 = kt * 64 + l16;
                    if (k0      > q) a0 = -1e30f;
                    if (k0 + 16 > q) a1 = -1e30f;
                    if (k0 + 32 > q) a2 = -1e30f;
                    if (k0 + 48 > q) a3 = -1e30f;
                }
                float rmax = fmaxf(fmaxf(a0, a1), fmaxf(a2, a3));
                rmax = fmaxf(rmax, __shfl_xor(rmax, 1, 64));
                rmax = fmaxf(rmax, __shfl_xor(rmax, 2, 64));
                rmax = fmaxf(rmax, __shfl_xor(rmax, 4, 64));
                rmax = fmaxf(rmax, __shfl_xor(rmax, 8, 64));
                float mnew = fmaxf(m[reg], rmax);
                float sc = __expf(m[reg] - mnew);
                m[reg] = mnew;
                float p0 = __expf(a0 - mnew), p1 = __expf(a1 - mnew);
                float p2 = __expf(a2 - mnew), p3 = __expf(a3 - mnew);
                float rs = p0 + p1 + p2 + p3;
                rs += __shfl_xor(rs, 1, 64);
                rs += __shfl_xor(rs, 2, 64);
                rs += __shfl_xor(rs, 4, 64);
                rs += __shfl_xor(rs, 8, 64);
                lsum[reg] = lsum[reg] * sc + rs;
#pragma unroll
                for (int f = 0; f < 8; ++f) o[f][reg] *= sc;
                Ps[wid][lq * 4 + reg][ 0 + l16] = f2bf(p0);
                Ps[wid][lq * 4 + reg][16 + l16] = f2bf(p1);
                Ps[wid][lq * 4 + reg][32 + l16] = f2bf(p2);
                Ps[wid][lq * 4 + reg][48 + l16] = f2bf(p3);
            }

            bf16x8 pa0 = *(const bf16x8*)&Ps[wid][l16][lq * 8];
            bf16x8 pa1 = *(const bf16x8*)&Ps[wid][l16][32 + lq * 8];
            __builtin_amdgcn_s_setprio(1);
#pragma unroll
            for (int f = 0; f < 8; ++f) {
                bf16x8 b0 = *(const bf16x8*)&Vs[f * 16 + l16][lq * 8];
                bf16x8 b1 = *(const bf16x8*)&Vs[f * 16 + l16][32 + lq * 8];
                o[f] = __builtin_amdgcn_mfma_f32_16x16x32_bf16(pa0, b0, o[f], 0, 0, 0);
                o[f] = __builtin_amdgcn_mfma_f32_16x16x32_bf16(pa1, b1, o[f], 0, 0, 0);
            }
            __builtin_amdgcn_s_setprio(0);
        }

#pragma unroll
        for (int reg = 0; reg < 4; ++reg) {
            float inv = 1.0f / lsum[reg];
            unsigned short* dst = ctx + (size_t)(b * SEQ + qt * 64 + wid * 16 + lq * 4 + reg) * 2048 + h * 128 + l16;
#pragma unroll
            for (int f = 0; f < 8; ++f) dst[f * 16] = f2bf(o[f][reg] * inv);
        }
    }
#undef FLASH_LOAD
}

// ---------------------------------------------------------------------------
extern "C" void kernel_launch(void* const* d_in, const int* in_sizes, int n_in,
                              void* d_out, int out_size, void* d_ws, size_t ws_size,
                              hipStream_t stream) {
    const float* x          = (const float*)d_in[0];
    const float* q_a_w      = (const float*)d_in[1];
    const float* q_a_norm_w = (const float*)d_in[2];
    const float* q_b_w      = (const float*)d_in[3];
    const float* kv_a_w     = (const float*)d_in[4];
    const float* kv_norm_w  = (const float*)d_in[5];
    const float* kv_b_w     = (const float*)d_in[6];
    const float* o_w        = (const float*)d_in[7];
    float* out = (float*)d_out;

    char* ws = (char*)d_ws;
    float*          qkv_cat  = (float*)(ws + 0);                   // 4096x2176 f32 (35.7MB)
    unsigned short* ctx_bf   = (unsigned short*)(ws + 0);          // overlay after qkv_cat dead
    unsigned short* qbuf_bf  = (unsigned short*)(ws + 35651584);   // 4096x3072 bf16 (25.2MB)
    unsigned short* vt_bf    = (unsigned short*)(ws + 60817408);   // 2x16x128x2048 bf16 (16.8MB)
    unsigned short* kvb_bf   = (unsigned short*)(ws + 77594624);   // 4096x4096 bf16 (33.6MB)
    unsigned short* x_bf     = (unsigned short*)(ws + 111149056);  // 4096x2048 bf16 (16.8MB)
    unsigned short* q_a_bf   = (unsigned short*)(ws + 111149056);  // overlay after x_bf dead
    unsigned short* kv_c_bf  = (unsigned short*)(ws + 127926272);  // 4096x512 bf16
    unsigned short* krope_bf = (unsigned short*)(ws + 132120576);  // 4096x64 bf16
    unsigned short* wcat     = (unsigned short*)(ws + 132644864);  // 2176x2048 (qa 1536 | kva 640)
    unsigned short* wkva_t   = wcat + (size_t)1536 * 2048;
    unsigned short* wqb_t    = (unsigned short*)(ws + 141557760);  // 3072x1536
    unsigned short* wkvb_t   = (unsigned short*)(ws + 150994944);  // 4096x512
    unsigned short* wo_t     = (unsigned short*)(ws + 155189248);  // 2048x2048

    dim3 blk(256);

    // input conversion + all weight transposes (one launch)
    cvt_bf16<<<4096, blk, 0, stream>>>(x, x_bf);
    WSegs segs;
    segs.s[0] = { q_a_w,  wcat,   1536, 2048,  48,     0 };
    segs.s[1] = { q_b_w,  wqb_t,  3072, 1536,  96,  3072 };
    segs.s[2] = { kv_a_w, wkva_t,  576, 2048,  20,  7680 };
    segs.s[3] = { kv_b_w, wkvb_t, 4096,  512, 128,  8960 };
    segs.s[4] = { o_w,    wo_t,   2048, 2048,  64, 11008 };
    prep_weights<<<15104, blk, 0, stream>>>(segs);

    // fused q_a + kv_a projection: [4096][2176] = x_bf @ wcat^T
    gemm_bt<0><<<dim3(17, 32), blk, 0, stream>>>(x_bf, wcat, qkv_cat, 2048, 2176);

    // norms (+ fused k-rope)
    rmsnorm_bf<<<NTOK, blk, 0, stream>>>(qkv_cat, q_a_norm_w, q_a_bf, 2176, 1536);
    rmsnorm_kv_rope<<<NTOK, blk, 0, stream>>>(qkv_cat + 1536, kv_norm_w, kv_c_bf, krope_bf);

    // second-stage projections
    gemm_bt<1><<<dim3(24, 32), blk, 0, stream>>>(q_a_bf, wqb_t, qbuf_bf, 1536, 3072);
    gemm_bt<1><<<dim3(32, 32), blk, 0, stream>>>(kv_c_bf, wkvb_t, kvb_bf, 512, 4096);

    // V transpose
    pack_vt<<<dim3(SEQ / 64, NHEADS, BATCH), blk, 0, stream>>>(kvb_bf, vt_bf);

    // attention (paired q-tiles, XCD-swizzled, RoPE-fused Q, reg-dbuf staging)
    flash_mfma<<<dim3(512), blk, 0, stream>>>(qbuf_bf, kvb_bf, krope_bf, vt_bf, ctx_bf);

    // output projection
    gemm_bt<0><<<dim3(16, 32), blk, 0, stream>>>(ctx_bf, wo_t, out, 2048, 2048);
}

// Round 10
// 367.631 us; speedup vs baseline: 16.3255x; 1.0514x over previous
//
#include <hip/hip_runtime.h>
#include <hip/hip_bf16.h>
#include <math.h>

#define NHEADS 16
#define SEQ 2048
#define BATCH 2
#define NTOK (BATCH * SEQ)
#define EPSF 1e-6f

typedef short bf16x8 __attribute__((ext_vector_type(8)));
typedef float f32x4 __attribute__((ext_vector_type(4)));

__device__ __forceinline__ unsigned short f2bf(float v) {
    __hip_bfloat16 h = __float2bfloat16(v);
    return *reinterpret_cast<unsigned short*>(&h);
}
__device__ __forceinline__ float bf2f(unsigned short u) {
    __hip_bfloat16 h = *reinterpret_cast<__hip_bfloat16*>(&u);
    return __bfloat162float(h);
}
__device__ __forceinline__ void g2l16(const void* g, void* l) {
    __builtin_amdgcn_global_load_lds(
        (const __attribute__((address_space(1))) void*)g,
        (__attribute__((address_space(3))) void*)l, 16, 0, 0);
}

// log2(10000) * 2 / 64
#define ROPE_L2 0.4152410118609203f

// ---------------------------------------------------------------------------
// x fp32 -> bf16 (8 elems/thread)
// ---------------------------------------------------------------------------
__global__ __launch_bounds__(256) void cvt_bf16(
    const float* __restrict__ in, unsigned short* __restrict__ out)
{
    const int i = blockIdx.x * 256 + threadIdx.x;
    float4 a = ((const float4*)in)[i * 2];
    float4 b = ((const float4*)in)[i * 2 + 1];
    unsigned short o[8] = {f2bf(a.x), f2bf(a.y), f2bf(a.z), f2bf(a.w),
                           f2bf(b.x), f2bf(b.y), f2bf(b.z), f2bf(b.w)};
    *(bf16x8*)(out + (size_t)i * 8) = *(bf16x8*)o;
}

// ---------------------------------------------------------------------------
// prep_weights: all 5 weight transposes (fp32 [K][Nw] -> bf16 [Npad][K]) in
// one launch. Segment chosen by block id against offset table.
// ---------------------------------------------------------------------------
struct WSeg { const float* src; unsigned short* dst; int Nw, K, nx, off; };
struct WSegs { WSeg s[5]; };

__global__ __launch_bounds__(256) void prep_weights(WSegs segs)
{
    __shared__ float T[32][33];
    const int bid = blockIdx.x;
    int si = 0;
#pragma unroll
    for (int i = 1; i < 5; ++i) si += (bid >= segs.s[i].off) ? 1 : 0;
    const WSeg sg = segs.s[si];
    const int local = bid - sg.off;
    const int bx = local % sg.nx, by = local / sg.nx;
    const int n0 = bx * 32, k0 = by * 32;
    const int tid = threadIdx.x;
    const int r = tid >> 3, c4 = (tid & 7) * 4;
    const bool valid = (n0 < sg.Nw);
    if (valid) {
        float4 v = *(const float4*)(sg.src + (size_t)(k0 + r) * sg.Nw + n0 + c4);
        T[r][c4 + 0] = v.x; T[r][c4 + 1] = v.y; T[r][c4 + 2] = v.z; T[r][c4 + 3] = v.w;
    }
    __syncthreads();
    unsigned short o[4];
#pragma unroll
    for (int j = 0; j < 4; ++j) o[j] = valid ? f2bf(T[c4 + j][r]) : (unsigned short)0;
    *(ulong1*)(sg.dst + (size_t)(n0 + r) * sg.K + k0 + c4) = *(ulong1*)o;
}

// ---------------------------------------------------------------------------
// bf16 MFMA GEMM: C[M,N] = A[M,K](bf16) @ Bt[N,K](bf16)^T. 128x128 tile, BK=32.
// ---------------------------------------------------------------------------
template <int OUT_BF16>
__global__ __launch_bounds__(256) void gemm_bt(
    const unsigned short* __restrict__ A,
    const unsigned short* __restrict__ Bt,
    void* __restrict__ Cv,
    int K, int N)
{
    __shared__ __align__(16) unsigned short As[128 * 32];
    __shared__ __align__(16) unsigned short Bs[128 * 32];
    const int tid = threadIdx.x;
    const int lane = tid & 63, wid = tid >> 6;
    const int l16 = lane & 15, lq = lane >> 4;
    const int wr = wid >> 1, wc = wid & 1;
    const int bm = blockIdx.y * 128, bn = blockIdx.x * 128;

    f32x4 acc[4][4];
#pragma unroll
    for (int m = 0; m < 4; ++m)
#pragma unroll
        for (int n = 0; n < 4; ++n) acc[m][n] = (f32x4){0.f, 0.f, 0.f, 0.f};

    for (int k0 = 0; k0 < K; k0 += 32) {
        __syncthreads();
#pragma unroll
        for (int t = 0; t < 2; ++t) {
            const int chunk = t * 256 + tid;
            const int row = chunk >> 2, koff = (chunk & 3) << 3;
            g2l16(A  + (size_t)(bm + row) * K + k0 + koff, (char*)As + chunk * 16);
            g2l16(Bt + (size_t)(bn + row) * K + k0 + koff, (char*)Bs + chunk * 16);
        }
        __syncthreads();

        bf16x8 af[4], bfr[4];
#pragma unroll
        for (int m = 0; m < 4; ++m)
            af[m] = *(const bf16x8*)(As + (wr * 64 + m * 16 + l16) * 32 + lq * 8);
#pragma unroll
        for (int n = 0; n < 4; ++n)
            bfr[n] = *(const bf16x8*)(Bs + (wc * 64 + n * 16 + l16) * 32 + lq * 8);
#pragma unroll
        for (int m = 0; m < 4; ++m)
#pragma unroll
            for (int n = 0; n < 4; ++n)
                acc[m][n] = __builtin_amdgcn_mfma_f32_16x16x32_bf16(af[m], bfr[n], acc[m][n], 0, 0, 0);
    }

#pragma unroll
    for (int m = 0; m < 4; ++m)
#pragma unroll
        for (int n = 0; n < 4; ++n)
#pragma unroll
            for (int reg = 0; reg < 4; ++reg) {
                const int row = bm + wr * 64 + m * 16 + lq * 4 + reg;
                const int col = bn + wc * 64 + n * 16 + l16;
                if (OUT_BF16) ((unsigned short*)Cv)[(size_t)row * N + col] = f2bf(acc[m][n][reg]);
                else          ((float*)Cv)[(size_t)row * N + col] = acc[m][n][reg];
            }
}

// ---------------------------------------------------------------------------
// RMSNorm: fp32 in (base pre-offset, row stride) -> bf16 compact out
// ---------------------------------------------------------------------------
__global__ __launch_bounds__(256) void rmsnorm_bf(
    const float* __restrict__ in, const float* __restrict__ w,
    unsigned short* __restrict__ out, int in_stride, int cols)
{
    const int row = blockIdx.x;
    const float* p = in + (size_t)row * in_stride;
    float ss = 0.f;
    for (int c = threadIdx.x; c < cols; c += 256) { float v = p[c]; ss += v * v; }
#pragma unroll
    for (int off = 32; off > 0; off >>= 1) ss += __shfl_down(ss, off, 64);
    __shared__ float wsum[4];
    __shared__ float s_scale;
    const int wave = threadIdx.x >> 6;
    if ((threadIdx.x & 63) == 0) wsum[wave] = ss;
    __syncthreads();
    if (threadIdx.x == 0) {
        float t = wsum[0] + wsum[1] + wsum[2] + wsum[3];
        s_scale = rsqrtf(t / (float)cols + EPSF);
    }
    __syncthreads();
    const float sc = s_scale;
    for (int c = threadIdx.x; c < cols; c += 256)
        out[(size_t)row * cols + c] = f2bf(p[c] * sc * w[c]);
}

// ---------------------------------------------------------------------------
// rmsnorm_kv_rope: in = qkv_cat + 1536 (stride 2176).
//   cols 0..511  -> RMSNorm -> kv_c_bf [row][512]
//   cols 512..575 -> RoPE   -> krope_bf [row][64]
// ---------------------------------------------------------------------------
__global__ __launch_bounds__(256) void rmsnorm_kv_rope(
    const float* __restrict__ in, const float* __restrict__ w,
    unsigned short* __restrict__ kv_out, unsigned short* __restrict__ krope_out)
{
    const int row = blockIdx.x;
    const float* p = in + (size_t)row * 2176;
    const int tid = threadIdx.x;
    float v0 = p[tid], v1 = p[tid + 256];
    float ss = v0 * v0 + v1 * v1;
#pragma unroll
    for (int off = 32; off > 0; off >>= 1) ss += __shfl_down(ss, off, 64);
    __shared__ float wsum[4];
    __shared__ float s_scale;
    const int wave = tid >> 6;
    if ((tid & 63) == 0) wsum[wave] = ss;
    __syncthreads();
    if (tid == 0) {
        float t = wsum[0] + wsum[1] + wsum[2] + wsum[3];
        s_scale = rsqrtf(t / 512.0f + EPSF);
    }
    __syncthreads();
    const float sc = s_scale;
    kv_out[(size_t)row * 512 + tid]       = f2bf(v0 * sc * w[tid]);
    kv_out[(size_t)row * 512 + tid + 256] = f2bf(v1 * sc * w[tid + 256]);
    if (tid < 64) {
        const int s = row & (SEQ - 1);
        const int j = tid, jj = j & 31;
        float inv = exp2f(-ROPE_L2 * (float)jj);
        float f = (float)s * inv;
        float sn, cs;
        sincosf(f, &sn, &cs);
        const float* kb = p + 512;
        float v = (j < 32) ? (kb[j] * cs - kb[j + 32] * sn)
                           : (kb[j] * cs + kb[j - 32] * sn);
        krope_out[(size_t)row * 64 + j] = f2bf(v);
    }
}

// ---------------------------------------------------------------------------
// pack_vt: vt_bf [b][h][d=128][s] = kvb_bf[tok][h*256+128+d] (transpose)
// ---------------------------------------------------------------------------
__global__ __launch_bounds__(256) void pack_vt(
    const unsigned short* __restrict__ kvb, unsigned short* __restrict__ vt_bf)
{
    __shared__ __align__(16) unsigned short T[64][136];
    const int st = blockIdx.x, h = blockIdx.y, b = blockIdx.z;
    const int tid = threadIdx.x;
#pragma unroll
    for (int t = 0; t < 4; ++t) {
        int i = tid + t * 256;
        int r = i >> 4, c8 = i & 15;
        bf16x8 v = *(const bf16x8*)(kvb + (size_t)(b * SEQ + st * 64 + r) * 4096 + h * 256 + 128 + c8 * 8);
        *(bf16x8*)&T[r][c8 * 8] = v;
    }
    __syncthreads();
    const int d = tid >> 1, sh = (tid & 1) * 32;
    unsigned short tmp[32];
#pragma unroll
    for (int k = 0; k < 32; ++k) tmp[k] = T[sh + k][d];
    unsigned short* dst = vt_bf + ((size_t)(b * NHEADS + h) * 128 + d) * SEQ + st * 64 + sh;
#pragma unroll
    for (int c = 0; c < 4; ++c) *(bf16x8*)(dst + c * 8) = *(bf16x8*)&tmp[c * 8];
}

// ---------------------------------------------------------------------------
// MFMA flash attention, causal, paired q-tiles + XCD swizzle.
// Softmax denominator via MFMA ones-row (Vs row 128 = 1.0); defer-max (THR=8).
// ---------------------------------------------------------------------------
#define KPD 200
#define VPD 72
#define PPD 72
#define RESCALE_THR 8.0f

__global__ __launch_bounds__(256) void flash_mfma(
    const unsigned short* __restrict__ qbuf,   // [tok][3072]
    const unsigned short* __restrict__ kvb,    // [tok][4096]
    const unsigned short* __restrict__ krope,  // [tok][64]
    const unsigned short* __restrict__ vt,     // [b][h][128][SEQ]
    unsigned short* __restrict__ ctx)          // [tok][2048]
{
    __shared__ __align__(16) unsigned short Ks[64][KPD];
    __shared__ __align__(16) unsigned short Vs[144][VPD];  // 128 V^T | ones | zeros
    __shared__ __align__(16) unsigned short Ps[4][16][PPD];
    const int id = blockIdx.x;
    const int xcd = id & 7, sl = id >> 3;
    const int grp = sl >> 4, pair = sl & 15;
    const int hb = xcd + 8 * grp;          // 0..31
    const int h = hb & 15, b = hb >> 4;
    const int tid = threadIdx.x;
    const int wid = tid >> 6, lane = tid & 63;
    const int l16 = lane & 15, lq = lane >> 4;

    const size_t headV = (size_t)(b * NHEADS + h) * 128 * SEQ;
    const float scale = 0.07216878364870323f;  // 1/sqrt(192)

    float cs8[8], sn8[8];
    const int vrow = tid >> 1, vg = tid & 1;

    // ones/zero rows 128..143 (once)
    {
        int r = 128 + (tid >> 4);
        int c = (tid & 15) * 4;
        unsigned short v = (tid >> 4) == 0 ? (unsigned short)0x3F80 : (unsigned short)0;
        Vs[r][c] = v; Vs[r][c + 1] = v; Vs[r][c + 2] = v; Vs[r][c + 3] = v;
    }

#pragma unroll
    for (int pass = 0; pass < 2; ++pass) {
        const int qt = pass ? (31 - pair) : pair;
        const int srow = qt * 64 + wid * 16 + l16;

        // Q fragments with in-register RoPE + scale
        bf16x8 qf[6];
        {
            const unsigned short* qp = qbuf + (size_t)(b * SEQ + srow) * 3072 + h * 192 + lq * 8;
            bf16x8 raw[6];
#pragma unroll
            for (int kk = 0; kk < 6; ++kk) raw[kk] = *(const bf16x8*)(qp + kk * 32);
#pragma unroll
            for (int jj = 0; jj < 8; ++jj) {
                float inv = exp2f(-ROPE_L2 * (float)(lq * 8 + jj));
                sincosf((float)srow * inv, &sn8[jj], &cs8[jj]);
            }
#pragma unroll
            for (int kk = 0; kk < 4; ++kk) {
                unsigned short o[8];
#pragma unroll
                for (int e = 0; e < 8; ++e) o[e] = f2bf(bf2f(((unsigned short*)&raw[kk])[e]) * scale);
                qf[kk] = *(bf16x8*)o;
            }
            unsigned short o4[8], o5[8];
#pragma unroll
            for (int e = 0; e < 8; ++e) {
                float x1 = bf2f(((unsigned short*)&raw[4])[e]);
                float x2 = bf2f(((unsigned short*)&raw[5])[e]);
                o4[e] = f2bf((x1 * cs8[e] - x2 * sn8[e]) * scale);
                o5[e] = f2bf((x2 * cs8[e] + x1 * sn8[e]) * scale);
            }
            qf[4] = *(bf16x8*)o4;
            qf[5] = *(bf16x8*)o5;
        }

        f32x4 o[8];
#pragma unroll
        for (int f = 0; f < 8; ++f) o[f] = (f32x4){0.f, 0.f, 0.f, 0.f};
        f32x4 oS = (f32x4){0.f, 0.f, 0.f, 0.f};   // softmax denominator via ones-row
        float m[4] = {-1e30f, -1e30f, -1e30f, -1e30f};

        const int nkt = qt + 1;
        for (int kt = 0; kt < nkt; ++kt) {
            __syncthreads();   // prev tile's LDS fully consumed
            {
                const int tk0 = b * SEQ + kt * 64;
#pragma unroll
                for (int t = 0; t < 4; ++t) {
                    int i = tid + t * 256;
                    int r = i >> 4, c8 = i & 15;
                    *(bf16x8*)&Ks[r][c8 * 8] =
                        *(const bf16x8*)(kvb + (size_t)(tk0 + r) * 4096 + h * 256 + c8 * 8);
                }
#pragma unroll
                for (int t = 0; t < 2; ++t) {
                    int i = tid + t * 256;
                    int r = i >> 3, c8 = i & 7;
                    *(bf16x8*)&Ks[r][128 + c8 * 8] =
                        *(const bf16x8*)(krope + (size_t)(tk0 + r) * 64 + c8 * 8);
                }
                const unsigned short* vsrc = vt + headV + (size_t)vrow * SEQ + kt * 64 + vg * 8;
#pragma unroll
                for (int j = 0; j < 4; ++j)
                    *(bf16x8*)&Vs[vrow][(vg + j * 2) * 8] = *(const bf16x8*)(vsrc + j * 16);
            }
            __syncthreads();

            // S = Q(16x192) @ K^T(192x64)
            f32x4 s[4];
#pragma unroll
            for (int f = 0; f < 4; ++f) s[f] = (f32x4){0.f, 0.f, 0.f, 0.f};
            __builtin_amdgcn_s_setprio(1);
#pragma unroll
            for (int f = 0; f < 4; ++f) {
#pragma unroll
                for (int kk = 0; kk < 6; ++kk) {
                    bf16x8 bfr = *(const bf16x8*)&Ks[f * 16 + l16][kk * 32 + lq * 8];
                    s[f] = __builtin_amdgcn_mfma_f32_16x16x32_bf16(qf[kk], bfr, s[f], 0, 0, 0);
                }
            }
            __builtin_amdgcn_s_setprio(0);

            const int qabs = qt * 64 + wid * 16 + lq * 4;
            const bool diag = (kt == qt);
            // mask + row-max
            float rmax4[4];
#pragma unroll
            for (int reg = 0; reg < 4; ++reg) {
                if (diag) {
                    int q = qabs + reg;
                    int k0 = kt * 64 + l16;
                    if (k0      > q) s[0][reg] = -1e30f;
                    if (k0 + 16 > q) s[1][reg] = -1e30f;
                    if (k0 + 32 > q) s[2][reg] = -1e30f;
                    if (k0 + 48 > q) s[3][reg] = -1e30f;
                }
                float rmax = fmaxf(fmaxf(s[0][reg], s[1][reg]), fmaxf(s[2][reg], s[3][reg]));
                rmax = fmaxf(rmax, __shfl_xor(rmax, 1, 64));
                rmax = fmaxf(rmax, __shfl_xor(rmax, 2, 64));
                rmax = fmaxf(rmax, __shfl_xor(rmax, 4, 64));
                rmax = fmaxf(rmax, __shfl_xor(rmax, 8, 64));
                rmax4[reg] = rmax;
            }
            // defer-max: rescale only when some row grew past threshold
            float dmx = fmaxf(fmaxf(rmax4[0] - m[0], rmax4[1] - m[1]),
                              fmaxf(rmax4[2] - m[2], rmax4[3] - m[3]));
            if (!__all(dmx <= RESCALE_THR)) {
#pragma unroll
                for (int reg = 0; reg < 4; ++reg) {
                    float mnew = fmaxf(m[reg], rmax4[reg]);
                    float al = __expf(m[reg] - mnew);
                    m[reg] = mnew;
#pragma unroll
                    for (int f = 0; f < 8; ++f) o[f][reg] *= al;
                    oS[reg] *= al;
                }
            }
            // P = exp(S - m), store bf16
#pragma unroll
            for (int reg = 0; reg < 4; ++reg) {
                Ps[wid][lq * 4 + reg][ 0 + l16] = f2bf(__expf(s[0][reg] - m[reg]));
                Ps[wid][lq * 4 + reg][16 + l16] = f2bf(__expf(s[1][reg] - m[reg]));
                Ps[wid][lq * 4 + reg][32 + l16] = f2bf(__expf(s[2][reg] - m[reg]));
                Ps[wid][lq * 4 + reg][48 + l16] = f2bf(__expf(s[3][reg] - m[reg]));
            }

            bf16x8 pa0 = *(const bf16x8*)&Ps[wid][l16][lq * 8];
            bf16x8 pa1 = *(const bf16x8*)&Ps[wid][l16][32 + lq * 8];
            __builtin_amdgcn_s_setprio(1);
#pragma unroll
            for (int f = 0; f < 8; ++f) {
                bf16x8 b0 = *(const bf16x8*)&Vs[f * 16 + l16][lq * 8];
                bf16x8 b1 = *(const bf16x8*)&Vs[f * 16 + l16][32 + lq * 8];
                o[f] = __builtin_amdgcn_mfma_f32_16x16x32_bf16(pa0, b0, o[f], 0, 0, 0);
                o[f] = __builtin_amdgcn_mfma_f32_16x16x32_bf16(pa1, b1, o[f], 0, 0, 0);
            }
            {   // denominator: oS += P @ ones-row (d=128 column)
                bf16x8 s0 = *(const bf16x8*)&Vs[128 + l16][lq * 8];
                bf16x8 s1 = *(const bf16x8*)&Vs[128 + l16][32 + lq * 8];
                oS = __builtin_amdgcn_mfma_f32_16x16x32_bf16(pa0, s0, oS, 0, 0, 0);
                oS = __builtin_amdgcn_mfma_f32_16x16x32_bf16(pa1, s1, oS, 0, 0, 0);
            }
            __builtin_amdgcn_s_setprio(0);
        }

        // epilogue: lsum lives in lanes l16==0 of each lq group; broadcast
#pragma unroll
        for (int reg = 0; reg < 4; ++reg) {
            float ls = __shfl(oS[reg], lane & 48, 64);
            float inv = 1.0f / ls;
            unsigned short* dst = ctx + (size_t)(b * SEQ + qt * 64 + wid * 16 + lq * 4 + reg) * 2048 + h * 128 + l16;
#pragma unroll
            for (int f = 0; f < 8; ++f) dst[f * 16] = f2bf(o[f][reg] * inv);
        }
    }
}

// ---------------------------------------------------------------------------
extern "C" void kernel_launch(void* const* d_in, const int* in_sizes, int n_in,
                              void* d_out, int out_size, void* d_ws, size_t ws_size,
                              hipStream_t stream) {
    const float* x          = (const float*)d_in[0];
    const float* q_a_w      = (const float*)d_in[1];
    const float* q_a_norm_w = (const float*)d_in[2];
    const float* q_b_w      = (const float*)d_in[3];
    const float* kv_a_w     = (const float*)d_in[4];
    const float* kv_norm_w  = (const float*)d_in[5];
    const float* kv_b_w     = (const float*)d_in[6];
    const float* o_w        = (const float*)d_in[7];
    float* out = (float*)d_out;

    char* ws = (char*)d_ws;
    float*          qkv_cat  = (float*)(ws + 0);                   // 4096x2176 f32 (35.7MB)
    unsigned short* ctx_bf   = (unsigned short*)(ws + 0);          // overlay after qkv_cat dead
    unsigned short* qbuf_bf  = (unsigned short*)(ws + 35651584);   // 4096x3072 bf16 (25.2MB)
    unsigned short* vt_bf    = (unsigned short*)(ws + 60817408);   // 2x16x128x2048 bf16 (16.8MB)
    unsigned short* kvb_bf   = (unsigned short*)(ws + 77594624);   // 4096x4096 bf16 (33.6MB)
    unsigned short* x_bf     = (unsigned short*)(ws + 111149056);  // 4096x2048 bf16 (16.8MB)
    unsigned short* q_a_bf   = (unsigned short*)(ws + 111149056);  // overlay after x_bf dead
    unsigned short* kv_c_bf  = (unsigned short*)(ws + 127926272);  // 4096x512 bf16
    unsigned short* krope_bf = (unsigned short*)(ws + 132120576);  // 4096x64 bf16
    unsigned short* wcat     = (unsigned short*)(ws + 132644864);  // 2176x2048 (qa 1536 | kva 640)
    unsigned short* wkva_t   = wcat + (size_t)1536 * 2048;
    unsigned short* wqb_t    = (unsigned short*)(ws + 141557760);  // 3072x1536
    unsigned short* wkvb_t   = (unsigned short*)(ws + 150994944);  // 4096x512
    unsigned short* wo_t     = (unsigned short*)(ws + 155189248);  // 2048x2048

    dim3 blk(256);

    // input conversion + all weight transposes (one launch)
    cvt_bf16<<<4096, blk, 0, stream>>>(x, x_bf);
    WSegs segs;
    segs.s[0] = { q_a_w,  wcat,   1536, 2048,  48,     0 };
    segs.s[1] = { q_b_w,  wqb_t,  3072, 1536,  96,  3072 };
    segs.s[2] = { kv_a_w, wkva_t,  576, 2048,  20,  7680 };
    segs.s[3] = { kv_b_w, wkvb_t, 4096,  512, 128,  8960 };
    segs.s[4] = { o_w,    wo_t,   2048, 2048,  64, 11008 };
    prep_weights<<<15104, blk, 0, stream>>>(segs);

    // fused q_a + kv_a projection: [4096][2176] = x_bf @ wcat^T
    gemm_bt<0><<<dim3(17, 32), blk, 0, stream>>>(x_bf, wcat, qkv_cat, 2048, 2176);

    // norms (+ fused k-rope)
    rmsnorm_bf<<<NTOK, blk, 0, stream>>>(qkv_cat, q_a_norm_w, q_a_bf, 2176, 1536);
    rmsnorm_kv_rope<<<NTOK, blk, 0, stream>>>(qkv_cat + 1536, kv_norm_w, kv_c_bf, krope_bf);

    // second-stage projections
    gemm_bt<1><<<dim3(24, 32), blk, 0, stream>>>(q_a_bf, wqb_t, qbuf_bf, 1536, 3072);
    gemm_bt<1><<<dim3(32, 32), blk, 0, stream>>>(kv_c_bf, wkvb_t, kvb_bf, 512, 4096);

    // V transpose
    pack_vt<<<dim3(SEQ / 64, NHEADS, BATCH), blk, 0, stream>>>(kvb_bf, vt_bf);

    // attention (paired q-tiles, XCD-swizzled, RoPE-fused Q, MFMA denominator)
    flash_mfma<<<dim3(512), blk, 0, stream>>>(qbuf_bf, kvb_bf, krope_bf, vt_bf, ctx_bf);

    // output projection
    gemm_bt<0><<<dim3(16, 32), blk, 0, stream>>>(ctx_bf, wo_t, out, 2048, 2048);
}

// Round 11
// 342.902 us; speedup vs baseline: 17.5028x; 1.0721x over previous
//
#include <hip/hip_runtime.h>
#include <hip/hip_bf16.h>
#include <math.h>

#define NHEADS 16
#define SEQ 2048
#define BATCH 2
#define NTOK (BATCH * SEQ)
#define EPSF 1e-6f

typedef short bf16x8 __attribute__((ext_vector_type(8)));
typedef float f32x4 __attribute__((ext_vector_type(4)));

__device__ __forceinline__ unsigned short f2bf(float v) {
    __hip_bfloat16 h = __float2bfloat16(v);
    return *reinterpret_cast<unsigned short*>(&h);
}
__device__ __forceinline__ float bf2f(unsigned short u) {
    __hip_bfloat16 h = *reinterpret_cast<__hip_bfloat16*>(&u);
    return __bfloat162float(h);
}
__device__ __forceinline__ void g2l16(const void* g, void* l) {
    __builtin_amdgcn_global_load_lds(
        (const __attribute__((address_space(1))) void*)g,
        (__attribute__((address_space(3))) void*)l, 16, 0, 0);
}

// log2(10000) * 2 / 64
#define ROPE_L2 0.4152410118609203f

// ---------------------------------------------------------------------------
// prep_weights: 5 weight transposes (fp32 [K][Nw] -> bf16 [Npad][K]) + x->bf16
// conversion, all in one launch. Blocks >= CVT_OFF do the x conversion.
// ---------------------------------------------------------------------------
struct WSeg { const float* src; unsigned short* dst; int Nw, K, nx, off; };
struct WSegs { WSeg s[5]; };
#define CVT_OFF 15104

__global__ __launch_bounds__(256) void prep_weights(
    WSegs segs, const float* __restrict__ x, unsigned short* __restrict__ x_bf)
{
    const int bid = blockIdx.x;
    const int tid = threadIdx.x;
    if (bid >= CVT_OFF) {
        const int i = (bid - CVT_OFF) * 256 + tid;
        float4 a = ((const float4*)x)[i * 2];
        float4 b = ((const float4*)x)[i * 2 + 1];
        unsigned short o[8] = {f2bf(a.x), f2bf(a.y), f2bf(a.z), f2bf(a.w),
                               f2bf(b.x), f2bf(b.y), f2bf(b.z), f2bf(b.w)};
        *(bf16x8*)(x_bf + (size_t)i * 8) = *(bf16x8*)o;
        return;
    }
    __shared__ float T[32][33];
    int si = 0;
#pragma unroll
    for (int i = 1; i < 5; ++i) si += (bid >= segs.s[i].off) ? 1 : 0;
    const WSeg sg = segs.s[si];
    const int local = bid - sg.off;
    const int bx = local % sg.nx, by = local / sg.nx;
    const int n0 = bx * 32, k0 = by * 32;
    const int r = tid >> 3, c4 = (tid & 7) * 4;
    const bool valid = (n0 < sg.Nw);
    if (valid) {
        float4 v = *(const float4*)(sg.src + (size_t)(k0 + r) * sg.Nw + n0 + c4);
        T[r][c4 + 0] = v.x; T[r][c4 + 1] = v.y; T[r][c4 + 2] = v.z; T[r][c4 + 3] = v.w;
    }
    __syncthreads();
    unsigned short o[4];
#pragma unroll
    for (int j = 0; j < 4; ++j) o[j] = valid ? f2bf(T[c4 + j][r]) : (unsigned short)0;
    *(ulong1*)(sg.dst + (size_t)(n0 + r) * sg.K + k0 + c4) = *(ulong1*)o;
}

// ---------------------------------------------------------------------------
// bf16 MFMA GEMM: C[M,N] = A[M,K](bf16) @ Bt[N,K](bf16)^T. 128x128 tile, BK=32.
// ---------------------------------------------------------------------------
template <int OUT_BF16>
__global__ __launch_bounds__(256) void gemm_bt(
    const unsigned short* __restrict__ A,
    const unsigned short* __restrict__ Bt,
    void* __restrict__ Cv,
    int K, int N)
{
    __shared__ __align__(16) unsigned short As[128 * 32];
    __shared__ __align__(16) unsigned short Bs[128 * 32];
    const int tid = threadIdx.x;
    const int lane = tid & 63, wid = tid >> 6;
    const int l16 = lane & 15, lq = lane >> 4;
    const int wr = wid >> 1, wc = wid & 1;
    const int bm = blockIdx.y * 128, bn = blockIdx.x * 128;

    f32x4 acc[4][4];
#pragma unroll
    for (int m = 0; m < 4; ++m)
#pragma unroll
        for (int n = 0; n < 4; ++n) acc[m][n] = (f32x4){0.f, 0.f, 0.f, 0.f};

    for (int k0 = 0; k0 < K; k0 += 32) {
        __syncthreads();
#pragma unroll
        for (int t = 0; t < 2; ++t) {
            const int chunk = t * 256 + tid;
            const int row = chunk >> 2, koff = (chunk & 3) << 3;
            g2l16(A  + (size_t)(bm + row) * K + k0 + koff, (char*)As + chunk * 16);
            g2l16(Bt + (size_t)(bn + row) * K + k0 + koff, (char*)Bs + chunk * 16);
        }
        __syncthreads();

        bf16x8 af[4], bfr[4];
#pragma unroll
        for (int m = 0; m < 4; ++m)
            af[m] = *(const bf16x8*)(As + (wr * 64 + m * 16 + l16) * 32 + lq * 8);
#pragma unroll
        for (int n = 0; n < 4; ++n)
            bfr[n] = *(const bf16x8*)(Bs + (wc * 64 + n * 16 + l16) * 32 + lq * 8);
#pragma unroll
        for (int m = 0; m < 4; ++m)
#pragma unroll
            for (int n = 0; n < 4; ++n)
                acc[m][n] = __builtin_amdgcn_mfma_f32_16x16x32_bf16(af[m], bfr[n], acc[m][n], 0, 0, 0);
    }

#pragma unroll
    for (int m = 0; m < 4; ++m)
#pragma unroll
        for (int n = 0; n < 4; ++n)
#pragma unroll
            for (int reg = 0; reg < 4; ++reg) {
                const int row = bm + wr * 64 + m * 16 + lq * 4 + reg;
                const int col = bn + wc * 64 + n * 16 + l16;
                if (OUT_BF16) ((unsigned short*)Cv)[(size_t)row * N + col] = f2bf(acc[m][n][reg]);
                else          ((float*)Cv)[(size_t)row * N + col] = acc[m][n][reg];
            }
}

// ---------------------------------------------------------------------------
// gemm_stage2: merged qb + kvb projections (segment by blockIdx).
//   bid < 768 : qbuf[4096][3072] = q_a_bf @ wqb^T   (K=1536)
//   bid >= 768: kvb [4096][4096] = kv_c_bf @ wkvb^T (K=512); V-half tiles
//               (bn%256==128) write transposed vt instead of kvb.
// ---------------------------------------------------------------------------
__global__ __launch_bounds__(256) void gemm_stage2(
    const unsigned short* __restrict__ qa,
    const unsigned short* __restrict__ wqb,
    unsigned short* __restrict__ qbuf,
    const unsigned short* __restrict__ kvc,
    const unsigned short* __restrict__ wkvb,
    unsigned short* __restrict__ kvb,
    unsigned short* __restrict__ vt)
{
    __shared__ __align__(16) unsigned short As[128 * 32];
    __shared__ __align__(16) unsigned short Bs[128 * 32];
    const int bid = blockIdx.x;
    const int tid = threadIdx.x;
    const int lane = tid & 63, wid = tid >> 6;
    const int l16 = lane & 15, lq = lane >> 4;
    const int wr = wid >> 1, wc = wid & 1;

    const bool is_q = bid < 768;
    const unsigned short* A;
    const unsigned short* Bt;
    int K, N, bm, bn;
    if (is_q) { A = qa;  Bt = wqb;  K = 1536; N = 3072; bn = (bid % 24) * 128;        bm = (bid / 24) * 128; }
    else      { A = kvc; Bt = wkvb; K = 512;  N = 4096; bn = ((bid - 768) % 32) * 128; bm = ((bid - 768) / 32) * 128; }

    f32x4 acc[4][4];
#pragma unroll
    for (int m = 0; m < 4; ++m)
#pragma unroll
        for (int n = 0; n < 4; ++n) acc[m][n] = (f32x4){0.f, 0.f, 0.f, 0.f};

    for (int k0 = 0; k0 < K; k0 += 32) {
        __syncthreads();
#pragma unroll
        for (int t = 0; t < 2; ++t) {
            const int chunk = t * 256 + tid;
            const int row = chunk >> 2, koff = (chunk & 3) << 3;
            g2l16(A  + (size_t)(bm + row) * K + k0 + koff, (char*)As + chunk * 16);
            g2l16(Bt + (size_t)(bn + row) * K + k0 + koff, (char*)Bs + chunk * 16);
        }
        __syncthreads();

        bf16x8 af[4], bfr[4];
#pragma unroll
        for (int m = 0; m < 4; ++m)
            af[m] = *(const bf16x8*)(As + (wr * 64 + m * 16 + l16) * 32 + lq * 8);
#pragma unroll
        for (int n = 0; n < 4; ++n)
            bfr[n] = *(const bf16x8*)(Bs + (wc * 64 + n * 16 + l16) * 32 + lq * 8);
#pragma unroll
        for (int m = 0; m < 4; ++m)
#pragma unroll
            for (int n = 0; n < 4; ++n)
                acc[m][n] = __builtin_amdgcn_mfma_f32_16x16x32_bf16(af[m], bfr[n], acc[m][n], 0, 0, 0);
    }

    const bool is_v = (!is_q) && ((bn & 255) == 128);
    if (!is_v) {
        unsigned short* C = is_q ? qbuf : kvb;
#pragma unroll
        for (int m = 0; m < 4; ++m)
#pragma unroll
            for (int n = 0; n < 4; ++n)
#pragma unroll
                for (int reg = 0; reg < 4; ++reg) {
                    const int row = bm + wr * 64 + m * 16 + lq * 4 + reg;
                    const int col = bn + wc * 64 + n * 16 + l16;
                    C[(size_t)row * N + col] = f2bf(acc[m][n][reg]);
                }
    } else {
        // V tile: write transposed into vt [b][h][d=128][s=2048]; skip kvb.
        const int h = bn >> 8;
#pragma unroll
        for (int m = 0; m < 4; ++m)
#pragma unroll
            for (int n = 0; n < 4; ++n) {
                const int d = wc * 64 + n * 16 + l16;
                const int tok0 = bm + wr * 64 + m * 16 + lq * 4;
                const int b_ = tok0 >> 11, s_ = tok0 & (SEQ - 1);
                unsigned short pk[4];
#pragma unroll
                for (int reg = 0; reg < 4; ++reg) pk[reg] = f2bf(acc[m][n][reg]);
                *(ulong1*)(vt + (((size_t)(b_ * NHEADS + h) * 128 + d) * SEQ + s_)) = *(ulong1*)pk;
            }
    }
}

// ---------------------------------------------------------------------------
// norms_fused: one launch, 8192 blocks.
//   bid < 4096 : RMSNorm q_a (cols 0..1535 of qkv_cat row) -> q_a_bf
//   bid >= 4096: RMSNorm kv (cols 1536..2047) -> kv_c_bf; RoPE cols 2048..2111
// ---------------------------------------------------------------------------
__global__ __launch_bounds__(256) void norms_fused(
    const float* __restrict__ qkv, const float* __restrict__ qw,
    const float* __restrict__ kvw,
    unsigned short* __restrict__ qa_out, unsigned short* __restrict__ kv_out,
    unsigned short* __restrict__ krope_out)
{
    const int bid = blockIdx.x;
    const int tid = threadIdx.x;
    __shared__ float wsum[4];
    __shared__ float s_scale;
    const int wave = tid >> 6;

    if (bid < 4096) {
        const int row = bid;
        const float* p = qkv + (size_t)row * 2176;
        float ss = 0.f;
#pragma unroll
        for (int t = 0; t < 6; ++t) { float v = p[tid + t * 256]; ss += v * v; }
#pragma unroll
        for (int off = 32; off > 0; off >>= 1) ss += __shfl_down(ss, off, 64);
        if ((tid & 63) == 0) wsum[wave] = ss;
        __syncthreads();
        if (tid == 0) {
            float t = wsum[0] + wsum[1] + wsum[2] + wsum[3];
            s_scale = rsqrtf(t / 1536.0f + EPSF);
        }
        __syncthreads();
        const float sc = s_scale;
#pragma unroll
        for (int t = 0; t < 6; ++t) {
            int c = tid + t * 256;
            qa_out[(size_t)row * 1536 + c] = f2bf(p[c] * sc * qw[c]);
        }
    } else {
        const int row = bid - 4096;
        const float* p = qkv + (size_t)row * 2176 + 1536;
        float v0 = p[tid], v1 = p[tid + 256];
        float ss = v0 * v0 + v1 * v1;
#pragma unroll
        for (int off = 32; off > 0; off >>= 1) ss += __shfl_down(ss, off, 64);
        if ((tid & 63) == 0) wsum[wave] = ss;
        __syncthreads();
        if (tid == 0) {
            float t = wsum[0] + wsum[1] + wsum[2] + wsum[3];
            s_scale = rsqrtf(t / 512.0f + EPSF);
        }
        __syncthreads();
        const float sc = s_scale;
        kv_out[(size_t)row * 512 + tid]       = f2bf(v0 * sc * kvw[tid]);
        kv_out[(size_t)row * 512 + tid + 256] = f2bf(v1 * sc * kvw[tid + 256]);
        if (tid < 64) {
            const int s = row & (SEQ - 1);
            const int j = tid, jj = j & 31;
            float inv = exp2f(-ROPE_L2 * (float)jj);
            float f = (float)s * inv;
            float sn, cs;
            sincosf(f, &sn, &cs);
            const float* kb = p + 512;
            float v = (j < 32) ? (kb[j] * cs - kb[j + 32] * sn)
                               : (kb[j] * cs + kb[j - 32] * sn);
            krope_out[(size_t)row * 64 + j] = f2bf(v);
        }
    }
}

// ---------------------------------------------------------------------------
// MFMA flash attention, causal, paired q-tiles + XCD swizzle.
// Softmax denominator via MFMA ones-row (Vs row 128 = 1.0); defer-max (THR=8).
// ---------------------------------------------------------------------------
#define KPD 200
#define VPD 72
#define PPD 72
#define RESCALE_THR 8.0f

__global__ __launch_bounds__(256) void flash_mfma(
    const unsigned short* __restrict__ qbuf,   // [tok][3072]
    const unsigned short* __restrict__ kvb,    // [tok][4096] (nope halves valid)
    const unsigned short* __restrict__ krope,  // [tok][64]
    const unsigned short* __restrict__ vt,     // [b][h][128][SEQ]
    unsigned short* __restrict__ ctx)          // [tok][2048]
{
    __shared__ __align__(16) unsigned short Ks[64][KPD];
    __shared__ __align__(16) unsigned short Vs[144][VPD];  // 128 V^T | ones | zeros
    __shared__ __align__(16) unsigned short Ps[4][16][PPD];
    const int id = blockIdx.x;
    const int xcd = id & 7, sl = id >> 3;
    const int grp = sl >> 4, pair = sl & 15;
    const int hb = xcd + 8 * grp;          // 0..31
    const int h = hb & 15, b = hb >> 4;
    const int tid = threadIdx.x;
    const int wid = tid >> 6, lane = tid & 63;
    const int l16 = lane & 15, lq = lane >> 4;

    const size_t headV = (size_t)(b * NHEADS + h) * 128 * SEQ;
    const float scale = 0.07216878364870323f;  // 1/sqrt(192)

    float cs8[8], sn8[8];
    const int vrow = tid >> 1, vg = tid & 1;

    // ones/zero rows 128..143 (once)
    {
        int r = 128 + (tid >> 4);
        int c = (tid & 15) * 4;
        unsigned short v = (tid >> 4) == 0 ? (unsigned short)0x3F80 : (unsigned short)0;
        Vs[r][c] = v; Vs[r][c + 1] = v; Vs[r][c + 2] = v; Vs[r][c + 3] = v;
    }

#pragma unroll
    for (int pass = 0; pass < 2; ++pass) {
        const int qt = pass ? (31 - pair) : pair;
        const int srow = qt * 64 + wid * 16 + l16;

        // Q fragments with in-register RoPE + scale (fast trig)
        bf16x8 qf[6];
        {
            const unsigned short* qp = qbuf + (size_t)(b * SEQ + srow) * 3072 + h * 192 + lq * 8;
            bf16x8 raw[6];
#pragma unroll
            for (int kk = 0; kk < 6; ++kk) raw[kk] = *(const bf16x8*)(qp + kk * 32);
#pragma unroll
            for (int jj = 0; jj < 8; ++jj) {
                float inv = exp2f(-ROPE_L2 * (float)(lq * 8 + jj));
                float fp = (float)srow * inv;
                sn8[jj] = __sinf(fp);
                cs8[jj] = __cosf(fp);
            }
#pragma unroll
            for (int kk = 0; kk < 4; ++kk) {
                unsigned short o[8];
#pragma unroll
                for (int e = 0; e < 8; ++e) o[e] = f2bf(bf2f(((unsigned short*)&raw[kk])[e]) * scale);
                qf[kk] = *(bf16x8*)o;
            }
            unsigned short o4[8], o5[8];
#pragma unroll
            for (int e = 0; e < 8; ++e) {
                float x1 = bf2f(((unsigned short*)&raw[4])[e]);
                float x2 = bf2f(((unsigned short*)&raw[5])[e]);
                o4[e] = f2bf((x1 * cs8[e] - x2 * sn8[e]) * scale);
                o5[e] = f2bf((x2 * cs8[e] + x1 * sn8[e]) * scale);
            }
            qf[4] = *(bf16x8*)o4;
            qf[5] = *(bf16x8*)o5;
        }

        f32x4 o[8];
#pragma unroll
        for (int f = 0; f < 8; ++f) o[f] = (f32x4){0.f, 0.f, 0.f, 0.f};
        f32x4 oS = (f32x4){0.f, 0.f, 0.f, 0.f};
        float m[4] = {-1e30f, -1e30f, -1e30f, -1e30f};

        const int nkt = qt + 1;
        for (int kt = 0; kt < nkt; ++kt) {
            __syncthreads();
            {
                const int tk0 = b * SEQ + kt * 64;
#pragma unroll
                for (int t = 0; t < 4; ++t) {
                    int i = tid + t * 256;
                    int r = i >> 4, c8 = i & 15;
                    *(bf16x8*)&Ks[r][c8 * 8] =
                        *(const bf16x8*)(kvb + (size_t)(tk0 + r) * 4096 + h * 256 + c8 * 8);
                }
#pragma unroll
                for (int t = 0; t < 2; ++t) {
                    int i = tid + t * 256;
                    int r = i >> 3, c8 = i & 7;
                    *(bf16x8*)&Ks[r][128 + c8 * 8] =
                        *(const bf16x8*)(krope + (size_t)(tk0 + r) * 64 + c8 * 8);
                }
                const unsigned short* vsrc = vt + headV + (size_t)vrow * SEQ + kt * 64 + vg * 8;
#pragma unroll
                for (int j = 0; j < 4; ++j)
                    *(bf16x8*)&Vs[vrow][(vg + j * 2) * 8] = *(const bf16x8*)(vsrc + j * 16);
            }
            __syncthreads();

            // S = Q(16x192) @ K^T(192x64)
            f32x4 s[4];
#pragma unroll
            for (int f = 0; f < 4; ++f) s[f] = (f32x4){0.f, 0.f, 0.f, 0.f};
            __builtin_amdgcn_s_setprio(1);
#pragma unroll
            for (int f = 0; f < 4; ++f) {
#pragma unroll
                for (int kk = 0; kk < 6; ++kk) {
                    bf16x8 bfr = *(const bf16x8*)&Ks[f * 16 + l16][kk * 32 + lq * 8];
                    s[f] = __builtin_amdgcn_mfma_f32_16x16x32_bf16(qf[kk], bfr, s[f], 0, 0, 0);
                }
            }
            __builtin_amdgcn_s_setprio(0);

            const int qabs = qt * 64 + wid * 16 + lq * 4;
            const bool diag = (kt == qt);
            float rmax4[4];
#pragma unroll
            for (int reg = 0; reg < 4; ++reg) {
                if (diag) {
                    int q = qabs + reg;
                    int k0 = kt * 64 + l16;
                    if (k0      > q) s[0][reg] = -1e30f;
                    if (k0 + 16 > q) s[1][reg] = -1e30f;
                    if (k0 + 32 > q) s[2][reg] = -1e30f;
                    if (k0 + 48 > q) s[3][reg] = -1e30f;
                }
                float rmax = fmaxf(fmaxf(s[0][reg], s[1][reg]), fmaxf(s[2][reg], s[3][reg]));
                rmax = fmaxf(rmax, __shfl_xor(rmax, 1, 64));
                rmax = fmaxf(rmax, __shfl_xor(rmax, 2, 64));
                rmax = fmaxf(rmax, __shfl_xor(rmax, 4, 64));
                rmax = fmaxf(rmax, __shfl_xor(rmax, 8, 64));
                rmax4[reg] = rmax;
            }
            float dmx = fmaxf(fmaxf(rmax4[0] - m[0], rmax4[1] - m[1]),
                              fmaxf(rmax4[2] - m[2], rmax4[3] - m[3]));
            if (!__all(dmx <= RESCALE_THR)) {
#pragma unroll
                for (int reg = 0; reg < 4; ++reg) {
                    float mnew = fmaxf(m[reg], rmax4[reg]);
                    float al = __expf(m[reg] - mnew);
                    m[reg] = mnew;
#pragma unroll
                    for (int f = 0; f < 8; ++f) o[f][reg] *= al;
                    oS[reg] *= al;
                }
            }
#pragma unroll
            for (int reg = 0; reg < 4; ++reg) {
                Ps[wid][lq * 4 + reg][ 0 + l16] = f2bf(__expf(s[0][reg] - m[reg]));
                Ps[wid][lq * 4 + reg][16 + l16] = f2bf(__expf(s[1][reg] - m[reg]));
                Ps[wid][lq * 4 + reg][32 + l16] = f2bf(__expf(s[2][reg] - m[reg]));
                Ps[wid][lq * 4 + reg][48 + l16] = f2bf(__expf(s[3][reg] - m[reg]));
            }

            bf16x8 pa0 = *(const bf16x8*)&Ps[wid][l16][lq * 8];
            bf16x8 pa1 = *(const bf16x8*)&Ps[wid][l16][32 + lq * 8];
            __builtin_amdgcn_s_setprio(1);
#pragma unroll
            for (int f = 0; f < 8; ++f) {
                bf16x8 b0 = *(const bf16x8*)&Vs[f * 16 + l16][lq * 8];
                bf16x8 b1 = *(const bf16x8*)&Vs[f * 16 + l16][32 + lq * 8];
                o[f] = __builtin_amdgcn_mfma_f32_16x16x32_bf16(pa0, b0, o[f], 0, 0, 0);
                o[f] = __builtin_amdgcn_mfma_f32_16x16x32_bf16(pa1, b1, o[f], 0, 0, 0);
            }
            {
                bf16x8 s0 = *(const bf16x8*)&Vs[128 + l16][lq * 8];
                bf16x8 s1 = *(const bf16x8*)&Vs[128 + l16][32 + lq * 8];
                oS = __builtin_amdgcn_mfma_f32_16x16x32_bf16(pa0, s0, oS, 0, 0, 0);
                oS = __builtin_amdgcn_mfma_f32_16x16x32_bf16(pa1, s1, oS, 0, 0, 0);
            }
            __builtin_amdgcn_s_setprio(0);
        }

#pragma unroll
        for (int reg = 0; reg < 4; ++reg) {
            float ls = __shfl(oS[reg], lane & 48, 64);
            float inv = 1.0f / ls;
            unsigned short* dst = ctx + (size_t)(b * SEQ + qt * 64 + wid * 16 + lq * 4 + reg) * 2048 + h * 128 + l16;
#pragma unroll
            for (int f = 0; f < 8; ++f) dst[f * 16] = f2bf(o[f][reg] * inv);
        }
    }
}

// ---------------------------------------------------------------------------
extern "C" void kernel_launch(void* const* d_in, const int* in_sizes, int n_in,
                              void* d_out, int out_size, void* d_ws, size_t ws_size,
                              hipStream_t stream) {
    const float* x          = (const float*)d_in[0];
    const float* q_a_w      = (const float*)d_in[1];
    const float* q_a_norm_w = (const float*)d_in[2];
    const float* q_b_w      = (const float*)d_in[3];
    const float* kv_a_w     = (const float*)d_in[4];
    const float* kv_norm_w  = (const float*)d_in[5];
    const float* kv_b_w     = (const float*)d_in[6];
    const float* o_w        = (const float*)d_in[7];
    float* out = (float*)d_out;

    char* ws = (char*)d_ws;
    float*          qkv_cat  = (float*)(ws + 0);                   // 4096x2176 f32 (35.7MB)
    unsigned short* ctx_bf   = (unsigned short*)(ws + 0);          // overlay after qkv_cat dead
    unsigned short* qbuf_bf  = (unsigned short*)(ws + 35651584);   // 4096x3072 bf16 (25.2MB)
    unsigned short* vt_bf    = (unsigned short*)(ws + 60817408);   // 2x16x128x2048 bf16 (16.8MB)
    unsigned short* kvb_bf   = (unsigned short*)(ws + 77594624);   // 4096x4096 bf16 (33.6MB)
    unsigned short* x_bf     = (unsigned short*)(ws + 111149056);  // 4096x2048 bf16 (16.8MB)
    unsigned short* q_a_bf   = (unsigned short*)(ws + 111149056);  // overlay after x_bf dead
    unsigned short* kv_c_bf  = (unsigned short*)(ws + 127926272);  // 4096x512 bf16
    unsigned short* krope_bf = (unsigned short*)(ws + 132120576);  // 4096x64 bf16
    unsigned short* wcat     = (unsigned short*)(ws + 132644864);  // 2176x2048 (qa 1536 | kva 640)
    unsigned short* wkva_t   = wcat + (size_t)1536 * 2048;
    unsigned short* wqb_t    = (unsigned short*)(ws + 141557760);  // 3072x1536
    unsigned short* wkvb_t   = (unsigned short*)(ws + 150994944);  // 4096x512
    unsigned short* wo_t     = (unsigned short*)(ws + 155189248);  // 2048x2048

    dim3 blk(256);

    // weight transposes + x conversion (one launch)
    WSegs segs;
    segs.s[0] = { q_a_w,  wcat,   1536, 2048,  48,     0 };
    segs.s[1] = { q_b_w,  wqb_t,  3072, 1536,  96,  3072 };
    segs.s[2] = { kv_a_w, wkva_t,  576, 2048,  20,  7680 };
    segs.s[3] = { kv_b_w, wkvb_t, 4096,  512, 128,  8960 };
    segs.s[4] = { o_w,    wo_t,   2048, 2048,  64, 11008 };
    prep_weights<<<CVT_OFF + 4096, blk, 0, stream>>>(segs, x, x_bf);

    // fused q_a + kv_a projection: [4096][2176] = x_bf @ wcat^T
    gemm_bt<0><<<dim3(17, 32), blk, 0, stream>>>(x_bf, wcat, qkv_cat, 2048, 2176);

    // both norms + k-rope (one launch)
    norms_fused<<<8192, blk, 0, stream>>>(qkv_cat, q_a_norm_w, kv_norm_w,
                                          q_a_bf, kv_c_bf, krope_bf);

    // merged second-stage projections (qb + kvb, V transposed in epilogue)
    gemm_stage2<<<1792, blk, 0, stream>>>(q_a_bf, wqb_t, qbuf_bf,
                                          kv_c_bf, wkvb_t, kvb_bf, vt_bf);

    // attention (paired q-tiles, XCD-swizzled, RoPE-fused Q, MFMA denominator)
    flash_mfma<<<dim3(512), blk, 0, stream>>>(qbuf_bf, kvb_bf, krope_bf, vt_bf, ctx_bf);

    // output projection
    gemm_bt<0><<<dim3(16, 32), blk, 0, stream>>>(ctx_bf, wo_t, out, 2048, 2048);
}

// Round 12
// 329.798 us; speedup vs baseline: 18.1983x; 1.0397x over previous
//
#include <hip/hip_runtime.h>
#include <hip/hip_bf16.h>
#include <math.h>

#define NHEADS 16
#define SEQ 2048
#define BATCH 2
#define NTOK (BATCH * SEQ)
#define EPSF 1e-6f

typedef short bf16x8 __attribute__((ext_vector_type(8)));
typedef float f32x4 __attribute__((ext_vector_type(4)));

__device__ __forceinline__ unsigned short f2bf(float v) {
    __hip_bfloat16 h = __float2bfloat16(v);
    return *reinterpret_cast<unsigned short*>(&h);
}
__device__ __forceinline__ float bf2f(unsigned short u) {
    __hip_bfloat16 h = *reinterpret_cast<__hip_bfloat16*>(&u);
    return __bfloat162float(h);
}
__device__ __forceinline__ void g2l16(const void* g, void* l) {
    __builtin_amdgcn_global_load_lds(
        (const __attribute__((address_space(1))) void*)g,
        (__attribute__((address_space(3))) void*)l, 16, 0, 0);
}

// log2(10000) * 2 / 64
#define ROPE_L2 0.4152410118609203f

// ---------------------------------------------------------------------------
// prep_weights: 5 weight transposes (fp32 [K][Nw] -> bf16 [Npad][K]) + x->bf16
// conversion, all in one launch. Blocks >= CVT_OFF do the x conversion.
// ---------------------------------------------------------------------------
struct WSeg { const float* src; unsigned short* dst; int Nw, K, nx, off; };
struct WSegs { WSeg s[5]; };
#define CVT_OFF 15104

__global__ __launch_bounds__(256) void prep_weights(
    WSegs segs, const float* __restrict__ x, unsigned short* __restrict__ x_bf)
{
    const int bid = blockIdx.x;
    const int tid = threadIdx.x;
    if (bid >= CVT_OFF) {
        const int i = (bid - CVT_OFF) * 256 + tid;
        float4 a = ((const float4*)x)[i * 2];
        float4 b = ((const float4*)x)[i * 2 + 1];
        unsigned short o[8] = {f2bf(a.x), f2bf(a.y), f2bf(a.z), f2bf(a.w),
                               f2bf(b.x), f2bf(b.y), f2bf(b.z), f2bf(b.w)};
        *(bf16x8*)(x_bf + (size_t)i * 8) = *(bf16x8*)o;
        return;
    }
    __shared__ float T[32][33];
    int si = 0;
#pragma unroll
    for (int i = 1; i < 5; ++i) si += (bid >= segs.s[i].off) ? 1 : 0;
    const WSeg sg = segs.s[si];
    const int local = bid - sg.off;
    const int bx = local % sg.nx, by = local / sg.nx;
    const int n0 = bx * 32, k0 = by * 32;
    const int r = tid >> 3, c4 = (tid & 7) * 4;
    const bool valid = (n0 < sg.Nw);
    if (valid) {
        float4 v = *(const float4*)(sg.src + (size_t)(k0 + r) * sg.Nw + n0 + c4);
        T[r][c4 + 0] = v.x; T[r][c4 + 1] = v.y; T[r][c4 + 2] = v.z; T[r][c4 + 3] = v.w;
    }
    __syncthreads();
    unsigned short o[4];
#pragma unroll
    for (int j = 0; j < 4; ++j) o[j] = valid ? f2bf(T[c4 + j][r]) : (unsigned short)0;
    *(ulong1*)(sg.dst + (size_t)(n0 + r) * sg.K + k0 + c4) = *(ulong1*)o;
}

// ---------------------------------------------------------------------------
// bf16 MFMA GEMM, double-buffered LDS (2-phase): stage tile t+1 before
// computing tile t; ONE barrier per K-step (its implicit vmcnt(0) drains the
// previous stage, which had the whole MFMA phase to land).
// ---------------------------------------------------------------------------
#define GSTAGE(AS, BS, BUF, T)                                                  \
    do {                                                                        \
        const int k0_ = (T) * 32;                                               \
        _Pragma("unroll")                                                       \
        for (int t_ = 0; t_ < 2; ++t_) {                                        \
            const int chunk_ = t_ * 256 + tid;                                  \
            const int row_ = chunk_ >> 2, koff_ = (chunk_ & 3) << 3;            \
            g2l16(A  + (size_t)(bm + row_) * K + k0_ + koff_, (char*)AS[BUF] + chunk_ * 16); \
            g2l16(Bt + (size_t)(bn + row_) * K + k0_ + koff_, (char*)BS[BUF] + chunk_ * 16); \
        }                                                                       \
    } while (0)

template <int OUT_BF16>
__global__ __launch_bounds__(256) void gemm_bt(
    const unsigned short* __restrict__ A,
    const unsigned short* __restrict__ Bt,
    void* __restrict__ Cv,
    int K, int N)
{
    __shared__ __align__(16) unsigned short As[2][128 * 32];
    __shared__ __align__(16) unsigned short Bs[2][128 * 32];
    const int tid = threadIdx.x;
    const int lane = tid & 63, wid = tid >> 6;
    const int l16 = lane & 15, lq = lane >> 4;
    const int wr = wid >> 1, wc = wid & 1;
    const int bm = blockIdx.y * 128, bn = blockIdx.x * 128;

    f32x4 acc[4][4];
#pragma unroll
    for (int m = 0; m < 4; ++m)
#pragma unroll
        for (int n = 0; n < 4; ++n) acc[m][n] = (f32x4){0.f, 0.f, 0.f, 0.f};

    const int nk = K >> 5;
    GSTAGE(As, Bs, 0, 0);
    int cur = 0;
    for (int t = 0; t < nk; ++t) {
        __syncthreads();                       // drains vmcnt -> buf[cur] ready
        if (t + 1 < nk) GSTAGE(As, Bs, cur ^ 1, t + 1);

        bf16x8 af[4], bfr[4];
#pragma unroll
        for (int m = 0; m < 4; ++m)
            af[m] = *(const bf16x8*)(As[cur] + (wr * 64 + m * 16 + l16) * 32 + lq * 8);
#pragma unroll
        for (int n = 0; n < 4; ++n)
            bfr[n] = *(const bf16x8*)(Bs[cur] + (wc * 64 + n * 16 + l16) * 32 + lq * 8);
#pragma unroll
        for (int m = 0; m < 4; ++m)
#pragma unroll
            for (int n = 0; n < 4; ++n)
                acc[m][n] = __builtin_amdgcn_mfma_f32_16x16x32_bf16(af[m], bfr[n], acc[m][n], 0, 0, 0);
        cur ^= 1;
    }

#pragma unroll
    for (int m = 0; m < 4; ++m)
#pragma unroll
        for (int n = 0; n < 4; ++n)
#pragma unroll
            for (int reg = 0; reg < 4; ++reg) {
                const int row = bm + wr * 64 + m * 16 + lq * 4 + reg;
                const int col = bn + wc * 64 + n * 16 + l16;
                if (OUT_BF16) ((unsigned short*)Cv)[(size_t)row * N + col] = f2bf(acc[m][n][reg]);
                else          ((float*)Cv)[(size_t)row * N + col] = acc[m][n][reg];
            }
}

// ---------------------------------------------------------------------------
// gemm_stage2: merged qb + kvb projections (segment by blockIdx), 2-phase.
//   bid < 768 : qbuf[4096][3072] = q_a_bf @ wqb^T   (K=1536)
//   bid >= 768: kvb [4096][4096] = kv_c_bf @ wkvb^T (K=512); V-half tiles
//               (bn%256==128) write transposed vt instead of kvb.
// ---------------------------------------------------------------------------
__global__ __launch_bounds__(256) void gemm_stage2(
    const unsigned short* __restrict__ qa,
    const unsigned short* __restrict__ wqb,
    unsigned short* __restrict__ qbuf,
    const unsigned short* __restrict__ kvc,
    const unsigned short* __restrict__ wkvb,
    unsigned short* __restrict__ kvb,
    unsigned short* __restrict__ vt)
{
    __shared__ __align__(16) unsigned short As[2][128 * 32];
    __shared__ __align__(16) unsigned short Bs[2][128 * 32];
    const int bid = blockIdx.x;
    const int tid = threadIdx.x;
    const int lane = tid & 63, wid = tid >> 6;
    const int l16 = lane & 15, lq = lane >> 4;
    const int wr = wid >> 1, wc = wid & 1;

    const bool is_q = bid < 768;
    const unsigned short* A;
    const unsigned short* Bt;
    int K, N, bm, bn;
    if (is_q) { A = qa;  Bt = wqb;  K = 1536; N = 3072; bn = (bid % 24) * 128;        bm = (bid / 24) * 128; }
    else      { A = kvc; Bt = wkvb; K = 512;  N = 4096; bn = ((bid - 768) % 32) * 128; bm = ((bid - 768) / 32) * 128; }

    f32x4 acc[4][4];
#pragma unroll
    for (int m = 0; m < 4; ++m)
#pragma unroll
        for (int n = 0; n < 4; ++n) acc[m][n] = (f32x4){0.f, 0.f, 0.f, 0.f};

    const int nk = K >> 5;
    GSTAGE(As, Bs, 0, 0);
    int cur = 0;
    for (int t = 0; t < nk; ++t) {
        __syncthreads();
        if (t + 1 < nk) GSTAGE(As, Bs, cur ^ 1, t + 1);

        bf16x8 af[4], bfr[4];
#pragma unroll
        for (int m = 0; m < 4; ++m)
            af[m] = *(const bf16x8*)(As[cur] + (wr * 64 + m * 16 + l16) * 32 + lq * 8);
#pragma unroll
        for (int n = 0; n < 4; ++n)
            bfr[n] = *(const bf16x8*)(Bs[cur] + (wc * 64 + n * 16 + l16) * 32 + lq * 8);
#pragma unroll
        for (int m = 0; m < 4; ++m)
#pragma unroll
            for (int n = 0; n < 4; ++n)
                acc[m][n] = __builtin_amdgcn_mfma_f32_16x16x32_bf16(af[m], bfr[n], acc[m][n], 0, 0, 0);
        cur ^= 1;
    }

    const bool is_v = (!is_q) && ((bn & 255) == 128);
    if (!is_v) {
        unsigned short* C = is_q ? qbuf : kvb;
#pragma unroll
        for (int m = 0; m < 4; ++m)
#pragma unroll
            for (int n = 0; n < 4; ++n)
#pragma unroll
                for (int reg = 0; reg < 4; ++reg) {
                    const int row = bm + wr * 64 + m * 16 + lq * 4 + reg;
                    const int col = bn + wc * 64 + n * 16 + l16;
                    C[(size_t)row * N + col] = f2bf(acc[m][n][reg]);
                }
    } else {
        // V tile: write transposed into vt [b][h][d=128][s=2048]; skip kvb.
        const int h = bn >> 8;
#pragma unroll
        for (int m = 0; m < 4; ++m)
#pragma unroll
            for (int n = 0; n < 4; ++n) {
                const int d = wc * 64 + n * 16 + l16;
                const int tok0 = bm + wr * 64 + m * 16 + lq * 4;
                const int b_ = tok0 >> 11, s_ = tok0 & (SEQ - 1);
                unsigned short pk[4];
#pragma unroll
                for (int reg = 0; reg < 4; ++reg) pk[reg] = f2bf(acc[m][n][reg]);
                *(ulong1*)(vt + (((size_t)(b_ * NHEADS + h) * 128 + d) * SEQ + s_)) = *(ulong1*)pk;
            }
    }
}

// ---------------------------------------------------------------------------
// norms_fused: one launch, 8192 blocks.
// ---------------------------------------------------------------------------
__global__ __launch_bounds__(256) void norms_fused(
    const float* __restrict__ qkv, const float* __restrict__ qw,
    const float* __restrict__ kvw,
    unsigned short* __restrict__ qa_out, unsigned short* __restrict__ kv_out,
    unsigned short* __restrict__ krope_out)
{
    const int bid = blockIdx.x;
    const int tid = threadIdx.x;
    __shared__ float wsum[4];
    __shared__ float s_scale;
    const int wave = tid >> 6;

    if (bid < 4096) {
        const int row = bid;
        const float* p = qkv + (size_t)row * 2176;
        float ss = 0.f;
#pragma unroll
        for (int t = 0; t < 6; ++t) { float v = p[tid + t * 256]; ss += v * v; }
#pragma unroll
        for (int off = 32; off > 0; off >>= 1) ss += __shfl_down(ss, off, 64);
        if ((tid & 63) == 0) wsum[wave] = ss;
        __syncthreads();
        if (tid == 0) {
            float t = wsum[0] + wsum[1] + wsum[2] + wsum[3];
            s_scale = rsqrtf(t / 1536.0f + EPSF);
        }
        __syncthreads();
        const float sc = s_scale;
#pragma unroll
        for (int t = 0; t < 6; ++t) {
            int c = tid + t * 256;
            qa_out[(size_t)row * 1536 + c] = f2bf(p[c] * sc * qw[c]);
        }
    } else {
        const int row = bid - 4096;
        const float* p = qkv + (size_t)row * 2176 + 1536;
        float v0 = p[tid], v1 = p[tid + 256];
        float ss = v0 * v0 + v1 * v1;
#pragma unroll
        for (int off = 32; off > 0; off >>= 1) ss += __shfl_down(ss, off, 64);
        if ((tid & 63) == 0) wsum[wave] = ss;
        __syncthreads();
        if (tid == 0) {
            float t = wsum[0] + wsum[1] + wsum[2] + wsum[3];
            s_scale = rsqrtf(t / 512.0f + EPSF);
        }
        __syncthreads();
        const float sc = s_scale;
        kv_out[(size_t)row * 512 + tid]       = f2bf(v0 * sc * kvw[tid]);
        kv_out[(size_t)row * 512 + tid + 256] = f2bf(v1 * sc * kvw[tid + 256]);
        if (tid < 64) {
            const int s = row & (SEQ - 1);
            const int j = tid, jj = j & 31;
            float inv = exp2f(-ROPE_L2 * (float)jj);
            float f = (float)s * inv;
            float sn, cs;
            sincosf(f, &sn, &cs);
            const float* kb = p + 512;
            float v = (j < 32) ? (kb[j] * cs - kb[j + 32] * sn)
                               : (kb[j] * cs + kb[j - 32] * sn);
            krope_out[(size_t)row * 64 + j] = f2bf(v);
        }
    }
}

// ---------------------------------------------------------------------------
// MFMA flash attention, causal, paired q-tiles + XCD swizzle.
// Softmax denominator via MFMA ones-row; defer-max (THR=8).
// VPD/PPD = 76 (stride 38 dwords, 6r%32 bank starts): 16-row reads
// conflict-free, 32-row V staging write 2-way (free).
// ---------------------------------------------------------------------------
#define KPD 200
#define VPD 76
#define PPD 76
#define RESCALE_THR 8.0f

__global__ __launch_bounds__(256) void flash_mfma(
    const unsigned short* __restrict__ qbuf,   // [tok][3072]
    const unsigned short* __restrict__ kvb,    // [tok][4096] (nope halves valid)
    const unsigned short* __restrict__ krope,  // [tok][64]
    const unsigned short* __restrict__ vt,     // [b][h][128][SEQ]
    unsigned short* __restrict__ ctx)          // [tok][2048]
{
    __shared__ __align__(16) unsigned short Ks[64][KPD];
    __shared__ __align__(16) unsigned short Vs[144][VPD];  // 128 V^T | ones | zeros
    __shared__ __align__(16) unsigned short Ps[4][16][PPD];
    const int id = blockIdx.x;
    const int xcd = id & 7, sl = id >> 3;
    const int grp = sl >> 4, pair = sl & 15;
    const int hb = xcd + 8 * grp;          // 0..31
    const int h = hb & 15, b = hb >> 4;
    const int tid = threadIdx.x;
    const int wid = tid >> 6, lane = tid & 63;
    const int l16 = lane & 15, lq = lane >> 4;

    const size_t headV = (size_t)(b * NHEADS + h) * 128 * SEQ;
    const float scale = 0.07216878364870323f;  // 1/sqrt(192)

    float cs8[8], sn8[8];
    const int vrow = tid >> 1, vg = tid & 1;

    // ones/zero rows 128..143 (once)
    {
        int r = 128 + (tid >> 4);
        int c = (tid & 15) * 4;
        unsigned short v = (tid >> 4) == 0 ? (unsigned short)0x3F80 : (unsigned short)0;
        Vs[r][c] = v; Vs[r][c + 1] = v; Vs[r][c + 2] = v; Vs[r][c + 3] = v;
    }

#pragma unroll
    for (int pass = 0; pass < 2; ++pass) {
        const int qt = pass ? (31 - pair) : pair;
        const int srow = qt * 64 + wid * 16 + l16;

        // Q fragments with in-register RoPE + scale (fast trig)
        bf16x8 qf[6];
        {
            const unsigned short* qp = qbuf + (size_t)(b * SEQ + srow) * 3072 + h * 192 + lq * 8;
            bf16x8 raw[6];
#pragma unroll
            for (int kk = 0; kk < 6; ++kk) raw[kk] = *(const bf16x8*)(qp + kk * 32);
#pragma unroll
            for (int jj = 0; jj < 8; ++jj) {
                float inv = exp2f(-ROPE_L2 * (float)(lq * 8 + jj));
                float fp = (float)srow * inv;
                sn8[jj] = __sinf(fp);
                cs8[jj] = __cosf(fp);
            }
#pragma unroll
            for (int kk = 0; kk < 4; ++kk) {
                unsigned short o[8];
#pragma unroll
                for (int e = 0; e < 8; ++e) o[e] = f2bf(bf2f(((unsigned short*)&raw[kk])[e]) * scale);
                qf[kk] = *(bf16x8*)o;
            }
            unsigned short o4[8], o5[8];
#pragma unroll
            for (int e = 0; e < 8; ++e) {
                float x1 = bf2f(((unsigned short*)&raw[4])[e]);
                float x2 = bf2f(((unsigned short*)&raw[5])[e]);
                o4[e] = f2bf((x1 * cs8[e] - x2 * sn8[e]) * scale);
                o5[e] = f2bf((x2 * cs8[e] + x1 * sn8[e]) * scale);
            }
            qf[4] = *(bf16x8*)o4;
            qf[5] = *(bf16x8*)o5;
        }

        f32x4 o[8];
#pragma unroll
        for (int f = 0; f < 8; ++f) o[f] = (f32x4){0.f, 0.f, 0.f, 0.f};
        f32x4 oS = (f32x4){0.f, 0.f, 0.f, 0.f};
        float m[4] = {-1e30f, -1e30f, -1e30f, -1e30f};

        const int nkt = qt + 1;
        for (int kt = 0; kt < nkt; ++kt) {
            __syncthreads();
            {
                const int tk0 = b * SEQ + kt * 64;
#pragma unroll
                for (int t = 0; t < 4; ++t) {
                    int i = tid + t * 256;
                    int r = i >> 4, c8 = i & 15;
                    *(bf16x8*)&Ks[r][c8 * 8] =
                        *(const bf16x8*)(kvb + (size_t)(tk0 + r) * 4096 + h * 256 + c8 * 8);
                }
#pragma unroll
                for (int t = 0; t < 2; ++t) {
                    int i = tid + t * 256;
                    int r = i >> 3, c8 = i & 7;
                    *(bf16x8*)&Ks[r][128 + c8 * 8] =
                        *(const bf16x8*)(krope + (size_t)(tk0 + r) * 64 + c8 * 8);
                }
                const unsigned short* vsrc = vt + headV + (size_t)vrow * SEQ + kt * 64 + vg * 8;
#pragma unroll
                for (int j = 0; j < 4; ++j)
                    *(bf16x8*)&Vs[vrow][(vg + j * 2) * 8] = *(const bf16x8*)(vsrc + j * 16);
            }
            __syncthreads();

            // S = Q(16x192) @ K^T(192x64)
            f32x4 s[4];
#pragma unroll
            for (int f = 0; f < 4; ++f) s[f] = (f32x4){0.f, 0.f, 0.f, 0.f};
            __builtin_amdgcn_s_setprio(1);
#pragma unroll
            for (int f = 0; f < 4; ++f) {
#pragma unroll
                for (int kk = 0; kk < 6; ++kk) {
                    bf16x8 bfr = *(const bf16x8*)&Ks[f * 16 + l16][kk * 32 + lq * 8];
                    s[f] = __builtin_amdgcn_mfma_f32_16x16x32_bf16(qf[kk], bfr, s[f], 0, 0, 0);
                }
            }
            __builtin_amdgcn_s_setprio(0);

            const int qabs = qt * 64 + wid * 16 + lq * 4;
            const bool diag = (kt == qt);
            float rmax4[4];
#pragma unroll
            for (int reg = 0; reg < 4; ++reg) {
                if (diag) {
                    int q = qabs + reg;
                    int k0 = kt * 64 + l16;
                    if (k0      > q) s[0][reg] = -1e30f;
                    if (k0 + 16 > q) s[1][reg] = -1e30f;
                    if (k0 + 32 > q) s[2][reg] = -1e30f;
                    if (k0 + 48 > q) s[3][reg] = -1e30f;
                }
                float rmax = fmaxf(fmaxf(s[0][reg], s[1][reg]), fmaxf(s[2][reg], s[3][reg]));
                rmax = fmaxf(rmax, __shfl_xor(rmax, 1, 64));
                rmax = fmaxf(rmax, __shfl_xor(rmax, 2, 64));
                rmax = fmaxf(rmax, __shfl_xor(rmax, 4, 64));
                rmax = fmaxf(rmax, __shfl_xor(rmax, 8, 64));
                rmax4[reg] = rmax;
            }
            float dmx = fmaxf(fmaxf(rmax4[0] - m[0], rmax4[1] - m[1]),
                              fmaxf(rmax4[2] - m[2], rmax4[3] - m[3]));
            if (!__all(dmx <= RESCALE_THR)) {
#pragma unroll
                for (int reg = 0; reg < 4; ++reg) {
                    float mnew = fmaxf(m[reg], rmax4[reg]);
                    float al = __expf(m[reg] - mnew);
                    m[reg] = mnew;
#pragma unroll
                    for (int f = 0; f < 8; ++f) o[f][reg] *= al;
                    oS[reg] *= al;
                }
            }
#pragma unroll
            for (int reg = 0; reg < 4; ++reg) {
                Ps[wid][lq * 4 + reg][ 0 + l16] = f2bf(__expf(s[0][reg] - m[reg]));
                Ps[wid][lq * 4 + reg][16 + l16] = f2bf(__expf(s[1][reg] - m[reg]));
                Ps[wid][lq * 4 + reg][32 + l16] = f2bf(__expf(s[2][reg] - m[reg]));
                Ps[wid][lq * 4 + reg][48 + l16] = f2bf(__expf(s[3][reg] - m[reg]));
            }

            bf16x8 pa0 = *(const bf16x8*)&Ps[wid][l16][lq * 8];
            bf16x8 pa1 = *(const bf16x8*)&Ps[wid][l16][32 + lq * 8];
            __builtin_amdgcn_s_setprio(1);
#pragma unroll
            for (int f = 0; f < 8; ++f) {
                bf16x8 b0 = *(const bf16x8*)&Vs[f * 16 + l16][lq * 8];
                bf16x8 b1 = *(const bf16x8*)&Vs[f * 16 + l16][32 + lq * 8];
                o[f] = __builtin_amdgcn_mfma_f32_16x16x32_bf16(pa0, b0, o[f], 0, 0, 0);
                o[f] = __builtin_amdgcn_mfma_f32_16x16x32_bf16(pa1, b1, o[f], 0, 0, 0);
            }
            {
                bf16x8 s0 = *(const bf16x8*)&Vs[128 + l16][lq * 8];
                bf16x8 s1 = *(const bf16x8*)&Vs[128 + l16][32 + lq * 8];
                oS = __builtin_amdgcn_mfma_f32_16x16x32_bf16(pa0, s0, oS, 0, 0, 0);
                oS = __builtin_amdgcn_mfma_f32_16x16x32_bf16(pa1, s1, oS, 0, 0, 0);
            }
            __builtin_amdgcn_s_setprio(0);
        }

#pragma unroll
        for (int reg = 0; reg < 4; ++reg) {
            float ls = __shfl(oS[reg], lane & 48, 64);
            float inv = 1.0f / ls;
            unsigned short* dst = ctx + (size_t)(b * SEQ + qt * 64 + wid * 16 + lq * 4 + reg) * 2048 + h * 128 + l16;
#pragma unroll
            for (int f = 0; f < 8; ++f) dst[f * 16] = f2bf(o[f][reg] * inv);
        }
    }
}

// ---------------------------------------------------------------------------
extern "C" void kernel_launch(void* const* d_in, const int* in_sizes, int n_in,
                              void* d_out, int out_size, void* d_ws, size_t ws_size,
                              hipStream_t stream) {
    const float* x          = (const float*)d_in[0];
    const float* q_a_w      = (const float*)d_in[1];
    const float* q_a_norm_w = (const float*)d_in[2];
    const float* q_b_w      = (const float*)d_in[3];
    const float* kv_a_w     = (const float*)d_in[4];
    const float* kv_norm_w  = (const float*)d_in[5];
    const float* kv_b_w     = (const float*)d_in[6];
    const float* o_w        = (const float*)d_in[7];
    float* out = (float*)d_out;

    char* ws = (char*)d_ws;
    float*          qkv_cat  = (float*)(ws + 0);                   // 4096x2176 f32 (35.7MB)
    unsigned short* ctx_bf   = (unsigned short*)(ws + 0);          // overlay after qkv_cat dead
    unsigned short* qbuf_bf  = (unsigned short*)(ws + 35651584);   // 4096x3072 bf16 (25.2MB)
    unsigned short* vt_bf    = (unsigned short*)(ws + 60817408);   // 2x16x128x2048 bf16 (16.8MB)
    unsigned short* kvb_bf   = (unsigned short*)(ws + 77594624);   // 4096x4096 bf16 (33.6MB)
    unsigned short* x_bf     = (unsigned short*)(ws + 111149056);  // 4096x2048 bf16 (16.8MB)
    unsigned short* q_a_bf   = (unsigned short*)(ws + 111149056);  // overlay after x_bf dead
    unsigned short* kv_c_bf  = (unsigned short*)(ws + 127926272);  // 4096x512 bf16
    unsigned short* krope_bf = (unsigned short*)(ws + 132120576);  // 4096x64 bf16
    unsigned short* wcat     = (unsigned short*)(ws + 132644864);  // 2176x2048 (qa 1536 | kva 640)
    unsigned short* wkva_t   = wcat + (size_t)1536 * 2048;
    unsigned short* wqb_t    = (unsigned short*)(ws + 141557760);  // 3072x1536
    unsigned short* wkvb_t   = (unsigned short*)(ws + 150994944);  // 4096x512
    unsigned short* wo_t     = (unsigned short*)(ws + 155189248);  // 2048x2048

    dim3 blk(256);

    // weight transposes + x conversion (one launch)
    WSegs segs;
    segs.s[0] = { q_a_w,  wcat,   1536, 2048,  48,     0 };
    segs.s[1] = { q_b_w,  wqb_t,  3072, 1536,  96,  3072 };
    segs.s[2] = { kv_a_w, wkva_t,  576, 2048,  20,  7680 };
    segs.s[3] = { kv_b_w, wkvb_t, 4096,  512, 128,  8960 };
    segs.s[4] = { o_w,    wo_t,   2048, 2048,  64, 11008 };
    prep_weights<<<CVT_OFF + 4096, blk, 0, stream>>>(segs, x, x_bf);

    // fused q_a + kv_a projection: [4096][2176] = x_bf @ wcat^T
    gemm_bt<0><<<dim3(17, 32), blk, 0, stream>>>(x_bf, wcat, qkv_cat, 2048, 2176);

    // both norms + k-rope (one launch)
    norms_fused<<<8192, blk, 0, stream>>>(qkv_cat, q_a_norm_w, kv_norm_w,
                                          q_a_bf, kv_c_bf, krope_bf);

    // merged second-stage projections (qb + kvb, V transposed in epilogue)
    gemm_stage2<<<1792, blk, 0, stream>>>(q_a_bf, wqb_t, qbuf_bf,
                                          kv_c_bf, wkvb_t, kvb_bf, vt_bf);

    // attention (paired q-tiles, XCD-swizzled, RoPE-fused Q, MFMA denominator)
    flash_mfma<<<dim3(512), blk, 0, stream>>>(qbuf_bf, kvb_bf, krope_bf, vt_bf, ctx_bf);

    // output projection
    gemm_bt<0><<<dim3(16, 32), blk, 0, stream>>>(ctx_bf, wo_t, out, 2048, 2048);
}

// Round 13
// 328.695 us; speedup vs baseline: 18.2593x; 1.0034x over previous
//
#include <hip/hip_runtime.h>
#include <hip/hip_bf16.h>
#include <math.h>

#define NHEADS 16
#define SEQ 2048
#define BATCH 2
#define NTOK (BATCH * SEQ)
#define EPSF 1e-6f

typedef short bf16x8 __attribute__((ext_vector_type(8)));
typedef float f32x4 __attribute__((ext_vector_type(4)));

__device__ __forceinline__ unsigned short f2bf(float v) {
    __hip_bfloat16 h = __float2bfloat16(v);
    return *reinterpret_cast<unsigned short*>(&h);
}
__device__ __forceinline__ float bf2f(unsigned short u) {
    __hip_bfloat16 h = *reinterpret_cast<__hip_bfloat16*>(&u);
    return __bfloat162float(h);
}
__device__ __forceinline__ void g2l16(const void* g, void* l) {
    __builtin_amdgcn_global_load_lds(
        (const __attribute__((address_space(1))) void*)g,
        (__attribute__((address_space(3))) void*)l, 16, 0, 0);
}
__device__ __forceinline__ unsigned cvt_pk_bf16(float lo, float hi) {
    unsigned r;
    asm volatile("v_cvt_pk_bf16_f32 %0, %1, %2" : "=v"(r) : "v"(lo), "v"(hi));
    return r;
}

// log2(10000) * 2 / 64
#define ROPE_L2 0.4152410118609203f

// ---------------------------------------------------------------------------
// prep_weights: 5 weight transposes (fp32 [K][Nw] -> bf16 [Npad][K]) + x->bf16
// conversion, all in one launch. Blocks >= CVT_OFF do the x conversion.
// ---------------------------------------------------------------------------
struct WSeg { const float* src; unsigned short* dst; int Nw, K, nx, off; };
struct WSegs { WSeg s[5]; };
#define CVT_OFF 15104

__global__ __launch_bounds__(256) void prep_weights(
    WSegs segs, const float* __restrict__ x, unsigned short* __restrict__ x_bf)
{
    const int bid = blockIdx.x;
    const int tid = threadIdx.x;
    if (bid >= CVT_OFF) {
        const int i = (bid - CVT_OFF) * 256 + tid;
        float4 a = ((const float4*)x)[i * 2];
        float4 b = ((const float4*)x)[i * 2 + 1];
        unsigned short o[8] = {f2bf(a.x), f2bf(a.y), f2bf(a.z), f2bf(a.w),
                               f2bf(b.x), f2bf(b.y), f2bf(b.z), f2bf(b.w)};
        *(bf16x8*)(x_bf + (size_t)i * 8) = *(bf16x8*)o;
        return;
    }
    __shared__ float T[32][33];
    int si = 0;
#pragma unroll
    for (int i = 1; i < 5; ++i) si += (bid >= segs.s[i].off) ? 1 : 0;
    const WSeg sg = segs.s[si];
    const int local = bid - sg.off;
    const int bx = local % sg.nx, by = local / sg.nx;
    const int n0 = bx * 32, k0 = by * 32;
    const int r = tid >> 3, c4 = (tid & 7) * 4;
    const bool valid = (n0 < sg.Nw);
    if (valid) {
        float4 v = *(const float4*)(sg.src + (size_t)(k0 + r) * sg.Nw + n0 + c4);
        T[r][c4 + 0] = v.x; T[r][c4 + 1] = v.y; T[r][c4 + 2] = v.z; T[r][c4 + 3] = v.w;
    }
    __syncthreads();
    unsigned short o[4];
#pragma unroll
    for (int j = 0; j < 4; ++j) o[j] = valid ? f2bf(T[c4 + j][r]) : (unsigned short)0;
    *(ulong1*)(sg.dst + (size_t)(n0 + r) * sg.K + k0 + c4) = *(ulong1*)o;
}

// ---------------------------------------------------------------------------
// bf16 MFMA GEMM, double-buffered LDS (2-phase).
// ---------------------------------------------------------------------------
#define GSTAGE(AS, BS, BUF, T)                                                  \
    do {                                                                        \
        const int k0_ = (T) * 32;                                               \
        _Pragma("unroll")                                                       \
        for (int t_ = 0; t_ < 2; ++t_) {                                        \
            const int chunk_ = t_ * 256 + tid;                                  \
            const int row_ = chunk_ >> 2, koff_ = (chunk_ & 3) << 3;            \
            g2l16(A  + (size_t)(bm + row_) * K + k0_ + koff_, (char*)AS[BUF] + chunk_ * 16); \
            g2l16(Bt + (size_t)(bn + row_) * K + k0_ + koff_, (char*)BS[BUF] + chunk_ * 16); \
        }                                                                       \
    } while (0)

template <int OUT_BF16>
__global__ __launch_bounds__(256) void gemm_bt(
    const unsigned short* __restrict__ A,
    const unsigned short* __restrict__ Bt,
    void* __restrict__ Cv,
    int K, int N)
{
    __shared__ __align__(16) unsigned short As[2][128 * 32];
    __shared__ __align__(16) unsigned short Bs[2][128 * 32];
    const int tid = threadIdx.x;
    const int lane = tid & 63, wid = tid >> 6;
    const int l16 = lane & 15, lq = lane >> 4;
    const int wr = wid >> 1, wc = wid & 1;
    const int bm = blockIdx.y * 128, bn = blockIdx.x * 128;

    f32x4 acc[4][4];
#pragma unroll
    for (int m = 0; m < 4; ++m)
#pragma unroll
        for (int n = 0; n < 4; ++n) acc[m][n] = (f32x4){0.f, 0.f, 0.f, 0.f};

    const int nk = K >> 5;
    GSTAGE(As, Bs, 0, 0);
    int cur = 0;
    for (int t = 0; t < nk; ++t) {
        __syncthreads();
        if (t + 1 < nk) GSTAGE(As, Bs, cur ^ 1, t + 1);

        bf16x8 af[4], bfr[4];
#pragma unroll
        for (int m = 0; m < 4; ++m)
            af[m] = *(const bf16x8*)(As[cur] + (wr * 64 + m * 16 + l16) * 32 + lq * 8);
#pragma unroll
        for (int n = 0; n < 4; ++n)
            bfr[n] = *(const bf16x8*)(Bs[cur] + (wc * 64 + n * 16 + l16) * 32 + lq * 8);
#pragma unroll
        for (int m = 0; m < 4; ++m)
#pragma unroll
            for (int n = 0; n < 4; ++n)
                acc[m][n] = __builtin_amdgcn_mfma_f32_16x16x32_bf16(af[m], bfr[n], acc[m][n], 0, 0, 0);
        cur ^= 1;
    }

#pragma unroll
    for (int m = 0; m < 4; ++m)
#pragma unroll
        for (int n = 0; n < 4; ++n)
#pragma unroll
            for (int reg = 0; reg < 4; ++reg) {
                const int row = bm + wr * 64 + m * 16 + lq * 4 + reg;
                const int col = bn + wc * 64 + n * 16 + l16;
                if (OUT_BF16) ((unsigned short*)Cv)[(size_t)row * N + col] = f2bf(acc[m][n][reg]);
                else          ((float*)Cv)[(size_t)row * N + col] = acc[m][n][reg];
            }
}

// ---------------------------------------------------------------------------
// gemm_stage2: merged qb + kvb projections, 2-phase; V tiles write vt.
// ---------------------------------------------------------------------------
__global__ __launch_bounds__(256) void gemm_stage2(
    const unsigned short* __restrict__ qa,
    const unsigned short* __restrict__ wqb,
    unsigned short* __restrict__ qbuf,
    const unsigned short* __restrict__ kvc,
    const unsigned short* __restrict__ wkvb,
    unsigned short* __restrict__ kvb,
    unsigned short* __restrict__ vt)
{
    __shared__ __align__(16) unsigned short As[2][128 * 32];
    __shared__ __align__(16) unsigned short Bs[2][128 * 32];
    const int bid = blockIdx.x;
    const int tid = threadIdx.x;
    const int lane = tid & 63, wid = tid >> 6;
    const int l16 = lane & 15, lq = lane >> 4;
    const int wr = wid >> 1, wc = wid & 1;

    const bool is_q = bid < 768;
    const unsigned short* A;
    const unsigned short* Bt;
    int K, N, bm, bn;
    if (is_q) { A = qa;  Bt = wqb;  K = 1536; N = 3072; bn = (bid % 24) * 128;        bm = (bid / 24) * 128; }
    else      { A = kvc; Bt = wkvb; K = 512;  N = 4096; bn = ((bid - 768) % 32) * 128; bm = ((bid - 768) / 32) * 128; }

    f32x4 acc[4][4];
#pragma unroll
    for (int m = 0; m < 4; ++m)
#pragma unroll
        for (int n = 0; n < 4; ++n) acc[m][n] = (f32x4){0.f, 0.f, 0.f, 0.f};

    const int nk = K >> 5;
    GSTAGE(As, Bs, 0, 0);
    int cur = 0;
    for (int t = 0; t < nk; ++t) {
        __syncthreads();
        if (t + 1 < nk) GSTAGE(As, Bs, cur ^ 1, t + 1);

        bf16x8 af[4], bfr[4];
#pragma unroll
        for (int m = 0; m < 4; ++m)
            af[m] = *(const bf16x8*)(As[cur] + (wr * 64 + m * 16 + l16) * 32 + lq * 8);
#pragma unroll
        for (int n = 0; n < 4; ++n)
            bfr[n] = *(const bf16x8*)(Bs[cur] + (wc * 64 + n * 16 + l16) * 32 + lq * 8);
#pragma unroll
        for (int m = 0; m < 4; ++m)
#pragma unroll
            for (int n = 0; n < 4; ++n)
                acc[m][n] = __builtin_amdgcn_mfma_f32_16x16x32_bf16(af[m], bfr[n], acc[m][n], 0, 0, 0);
        cur ^= 1;
    }

    const bool is_v = (!is_q) && ((bn & 255) == 128);
    if (!is_v) {
        unsigned short* C = is_q ? qbuf : kvb;
#pragma unroll
        for (int m = 0; m < 4; ++m)
#pragma unroll
            for (int n = 0; n < 4; ++n)
#pragma unroll
                for (int reg = 0; reg < 4; ++reg) {
                    const int row = bm + wr * 64 + m * 16 + lq * 4 + reg;
                    const int col = bn + wc * 64 + n * 16 + l16;
                    C[(size_t)row * N + col] = f2bf(acc[m][n][reg]);
                }
    } else {
        const int h = bn >> 8;
#pragma unroll
        for (int m = 0; m < 4; ++m)
#pragma unroll
            for (int n = 0; n < 4; ++n) {
                const int d = wc * 64 + n * 16 + l16;
                const int tok0 = bm + wr * 64 + m * 16 + lq * 4;
                const int b_ = tok0 >> 11, s_ = tok0 & (SEQ - 1);
                unsigned short pk[4];
#pragma unroll
                for (int reg = 0; reg < 4; ++reg) pk[reg] = f2bf(acc[m][n][reg]);
                *(ulong1*)(vt + (((size_t)(b_ * NHEADS + h) * 128 + d) * SEQ + s_)) = *(ulong1*)pk;
            }
    }
}

// ---------------------------------------------------------------------------
// norms_fused: one launch, 8192 blocks.
// ---------------------------------------------------------------------------
__global__ __launch_bounds__(256) void norms_fused(
    const float* __restrict__ qkv, const float* __restrict__ qw,
    const float* __restrict__ kvw,
    unsigned short* __restrict__ qa_out, unsigned short* __restrict__ kv_out,
    unsigned short* __restrict__ krope_out)
{
    const int bid = blockIdx.x;
    const int tid = threadIdx.x;
    __shared__ float wsum[4];
    __shared__ float s_scale;
    const int wave = tid >> 6;

    if (bid < 4096) {
        const int row = bid;
        const float* p = qkv + (size_t)row * 2176;
        float ss = 0.f;
#pragma unroll
        for (int t = 0; t < 6; ++t) { float v = p[tid + t * 256]; ss += v * v; }
#pragma unroll
        for (int off = 32; off > 0; off >>= 1) ss += __shfl_down(ss, off, 64);
        if ((tid & 63) == 0) wsum[wave] = ss;
        __syncthreads();
        if (tid == 0) {
            float t = wsum[0] + wsum[1] + wsum[2] + wsum[3];
            s_scale = rsqrtf(t / 1536.0f + EPSF);
        }
        __syncthreads();
        const float sc = s_scale;
#pragma unroll
        for (int t = 0; t < 6; ++t) {
            int c = tid + t * 256;
            qa_out[(size_t)row * 1536 + c] = f2bf(p[c] * sc * qw[c]);
        }
    } else {
        const int row = bid - 4096;
        const float* p = qkv + (size_t)row * 2176 + 1536;
        float v0 = p[tid], v1 = p[tid + 256];
        float ss = v0 * v0 + v1 * v1;
#pragma unroll
        for (int off = 32; off > 0; off >>= 1) ss += __shfl_down(ss, off, 64);
        if ((tid & 63) == 0) wsum[wave] = ss;
        __syncthreads();
        if (tid == 0) {
            float t = wsum[0] + wsum[1] + wsum[2] + wsum[3];
            s_scale = rsqrtf(t / 512.0f + EPSF);
        }
        __syncthreads();
        const float sc = s_scale;
        kv_out[(size_t)row * 512 + tid]       = f2bf(v0 * sc * kvw[tid]);
        kv_out[(size_t)row * 512 + tid + 256] = f2bf(v1 * sc * kvw[tid + 256]);
        if (tid < 64) {
            const int s = row & (SEQ - 1);
            const int j = tid, jj = j & 31;
            float inv = exp2f(-ROPE_L2 * (float)jj);
            float f = (float)s * inv;
            float sn, cs;
            sincosf(f, &sn, &cs);
            const float* kb = p + 512;
            float v = (j < 32) ? (kb[j] * cs - kb[j + 32] * sn)
                               : (kb[j] * cs + kb[j - 32] * sn);
            krope_out[(size_t)row * 64 + j] = f2bf(v);
        }
    }
}

// ---------------------------------------------------------------------------
// MFMA flash attention: swapped QK^T (S^T = K @ Q^T) -> each lane owns one
// q-row's scores -> in-register softmax (no Ps LDS, no shfl-heavy reduce).
// V LDS columns stored k-permuted (pi: slot-chunk 2g->g, 2g+1->g+4 per half)
// so each lane's own P chunks land in its PV A-slots with zero exchange.
// ---------------------------------------------------------------------------
#define KPD 200
#define VPD 76
#define RESCALE_THR 8.0f

__global__ __launch_bounds__(256) void flash_mfma(
    const unsigned short* __restrict__ qbuf,   // [tok][3072]
    const unsigned short* __restrict__ kvb,    // [tok][4096] (nope halves valid)
    const unsigned short* __restrict__ krope,  // [tok][64]
    const unsigned short* __restrict__ vt,     // [b][h][128][SEQ]
    unsigned short* __restrict__ ctx)          // [tok][2048]
{
    __shared__ __align__(16) unsigned short Ks[64][KPD];
    __shared__ __align__(16) unsigned short Vs[128][VPD];
    const int id = blockIdx.x;
    const int xcd = id & 7, sl = id >> 3;
    const int grp = sl >> 4, pair = sl & 15;
    const int hb = xcd + 8 * grp;          // 0..31
    const int h = hb & 15, b = hb >> 4;
    const int tid = threadIdx.x;
    const int wid = tid >> 6, lane = tid & 63;
    const int l16 = lane & 15, lq = lane >> 4;

    const size_t headV = (size_t)(b * NHEADS + h) * 128 * SEQ;
    const float scale = 0.07216878364870323f;  // 1/sqrt(192)

    float cs8[8], sn8[8];
    const int vrow = tid >> 1, vg = tid & 1;

#pragma unroll
    for (int pass = 0; pass < 2; ++pass) {
        const int qt = pass ? (31 - pair) : pair;
        const int srow = qt * 64 + wid * 16 + l16;   // this lane's q-row

        // Q fragments with in-register RoPE + scale
        bf16x8 qf[6];
        {
            const unsigned short* qp = qbuf + (size_t)(b * SEQ + srow) * 3072 + h * 192 + lq * 8;
            bf16x8 raw[6];
#pragma unroll
            for (int kk = 0; kk < 6; ++kk) raw[kk] = *(const bf16x8*)(qp + kk * 32);
#pragma unroll
            for (int jj = 0; jj < 8; ++jj) {
                float inv = exp2f(-ROPE_L2 * (float)(lq * 8 + jj));
                float fp = (float)srow * inv;
                sn8[jj] = __sinf(fp);
                cs8[jj] = __cosf(fp);
            }
#pragma unroll
            for (int kk = 0; kk < 4; ++kk) {
                unsigned short o[8];
#pragma unroll
                for (int e = 0; e < 8; ++e) o[e] = f2bf(bf2f(((unsigned short*)&raw[kk])[e]) * scale);
                qf[kk] = *(bf16x8*)o;
            }
            unsigned short o4[8], o5[8];
#pragma unroll
            for (int e = 0; e < 8; ++e) {
                float x1 = bf2f(((unsigned short*)&raw[4])[e]);
                float x2 = bf2f(((unsigned short*)&raw[5])[e]);
                o4[e] = f2bf((x1 * cs8[e] - x2 * sn8[e]) * scale);
                o5[e] = f2bf((x2 * cs8[e] + x1 * sn8[e]) * scale);
            }
            qf[4] = *(bf16x8*)o4;
            qf[5] = *(bf16x8*)o5;
        }

        f32x4 o[8];
#pragma unroll
        for (int f = 0; f < 8; ++f) o[f] = (f32x4){0.f, 0.f, 0.f, 0.f};
        float m = -1e30f;     // running max for q = l16 (shared across lq group)
        float lsum = 0.f;     // partial denominator (this lane's k-chunks)

        const int nkt = qt + 1;
        for (int kt = 0; kt < nkt; ++kt) {
            __syncthreads();
            {
                const int tk0 = b * SEQ + kt * 64;
#pragma unroll
                for (int t = 0; t < 4; ++t) {
                    int i = tid + t * 256;
                    int r = i >> 4, c8 = i & 15;
                    *(bf16x8*)&Ks[r][c8 * 8] =
                        *(const bf16x8*)(kvb + (size_t)(tk0 + r) * 4096 + h * 256 + c8 * 8);
                }
#pragma unroll
                for (int t = 0; t < 2; ++t) {
                    int i = tid + t * 256;
                    int r = i >> 3, c8 = i & 7;
                    *(bf16x8*)&Ks[r][128 + c8 * 8] =
                        *(const bf16x8*)(krope + (size_t)(tk0 + r) * 64 + c8 * 8);
                }
                // V staged with permuted columns: col-group g holds global
                // k-chunks {kA, kA+16}, kA = (g&3)*4 + (g>>2)*32.
                const unsigned short* vbase = vt + headV + (size_t)vrow * SEQ + kt * 64;
#pragma unroll
                for (int j = 0; j < 4; ++j) {
                    int g = vg + 2 * j;
                    int kA = (g & 3) * 4 + (g >> 2) * 32;
                    unsigned long long pk[2];
                    pk[0] = *(const unsigned long long*)(vbase + kA);
                    pk[1] = *(const unsigned long long*)(vbase + kA + 16);
                    *(bf16x8*)&Vs[vrow][g * 8] = *(const bf16x8*)pk;
                }
            }
            __syncthreads();

            // S^T = K(64x192) @ Q^T: s[f][reg] = S[q=l16][k = f*16+lq*4+reg]
            f32x4 s[4];
#pragma unroll
            for (int f = 0; f < 4; ++f) s[f] = (f32x4){0.f, 0.f, 0.f, 0.f};
            __builtin_amdgcn_s_setprio(1);
#pragma unroll
            for (int f = 0; f < 4; ++f) {
#pragma unroll
                for (int kk = 0; kk < 6; ++kk) {
                    bf16x8 kfr = *(const bf16x8*)&Ks[f * 16 + l16][kk * 32 + lq * 8];
                    s[f] = __builtin_amdgcn_mfma_f32_16x16x32_bf16(kfr, qf[kk], s[f], 0, 0, 0);
                }
            }
            __builtin_amdgcn_s_setprio(0);

            // causal mask (diag tile only)
            if (kt == qt) {
                const int kb0 = kt * 64 + lq * 4;
#pragma unroll
                for (int f = 0; f < 4; ++f)
#pragma unroll
                    for (int reg = 0; reg < 4; ++reg)
                        if (kb0 + f * 16 + reg > srow) s[f][reg] = -1e30f;
            }

            // row max: 15 in-reg + 2 shfl (combine lq-group partials)
            float rmax = fmaxf(fmaxf(s[0][0], s[0][1]), fmaxf(s[0][2], s[0][3]));
            rmax = fmaxf(rmax, fmaxf(fmaxf(s[1][0], s[1][1]), fmaxf(s[1][2], s[1][3])));
            rmax = fmaxf(rmax, fmaxf(fmaxf(s[2][0], s[2][1]), fmaxf(s[2][2], s[2][3])));
            rmax = fmaxf(rmax, fmaxf(fmaxf(s[3][0], s[3][1]), fmaxf(s[3][2], s[3][3])));
            rmax = fmaxf(rmax, __shfl_xor(rmax, 16, 64));
            rmax = fmaxf(rmax, __shfl_xor(rmax, 32, 64));

            // defer-max rescale (rare)
            if (!__all(rmax - m <= RESCALE_THR)) {
                float mnew = fmaxf(m, rmax);
                float al = __expf(m - mnew);
                m = mnew;
                lsum *= al;
#pragma unroll
                for (int reg = 0; reg < 4; ++reg) {
                    float ar = __shfl(al, (lane & 48) | (lq * 4 + reg), 64);
#pragma unroll
                    for (int f = 0; f < 8; ++f) o[f][reg] *= ar;
                }
            }

            // P = exp(S - m) in-register; pack to bf16 A-fragments (no LDS)
            unsigned d0[2], d1[2], d2[2], d3[2];
            float psum = 0.f;
            {
                float p0, p1, p2, p3;
                p0 = __expf(s[0][0] - m); p1 = __expf(s[0][1] - m);
                p2 = __expf(s[0][2] - m); p3 = __expf(s[0][3] - m);
                psum += (p0 + p1) + (p2 + p3);
                d0[0] = cvt_pk_bf16(p0, p1); d0[1] = cvt_pk_bf16(p2, p3);
                p0 = __expf(s[1][0] - m); p1 = __expf(s[1][1] - m);
                p2 = __expf(s[1][2] - m); p3 = __expf(s[1][3] - m);
                psum += (p0 + p1) + (p2 + p3);
                d1[0] = cvt_pk_bf16(p0, p1); d1[1] = cvt_pk_bf16(p2, p3);
                p0 = __expf(s[2][0] - m); p1 = __expf(s[2][1] - m);
                p2 = __expf(s[2][2] - m); p3 = __expf(s[2][3] - m);
                psum += (p0 + p1) + (p2 + p3);
                d2[0] = cvt_pk_bf16(p0, p1); d2[1] = cvt_pk_bf16(p2, p3);
                p0 = __expf(s[3][0] - m); p1 = __expf(s[3][1] - m);
                p2 = __expf(s[3][2] - m); p3 = __expf(s[3][3] - m);
                psum += (p0 + p1) + (p2 + p3);
                d3[0] = cvt_pk_bf16(p0, p1); d3[1] = cvt_pk_bf16(p2, p3);
            }
            lsum += psum;
            unsigned pk0[4] = {d0[0], d0[1], d1[0], d1[1]};  // k-chunks {lq, 4+lq}
            unsigned pk1[4] = {d2[0], d2[1], d3[0], d3[1]};  // k-chunks {8+lq, 12+lq}
            bf16x8 pa0 = *(const bf16x8*)pk0;
            bf16x8 pa1 = *(const bf16x8*)pk1;

            // O += P @ V (V columns pre-permuted to match lane chunk layout)
            __builtin_amdgcn_s_setprio(1);
#pragma unroll
            for (int f = 0; f < 8; ++f) {
                bf16x8 b0 = *(const bf16x8*)&Vs[f * 16 + l16][lq * 8];
                bf16x8 b1 = *(const bf16x8*)&Vs[f * 16 + l16][32 + lq * 8];
                o[f] = __builtin_amdgcn_mfma_f32_16x16x32_bf16(pa0, b0, o[f], 0, 0, 0);
                o[f] = __builtin_amdgcn_mfma_f32_16x16x32_bf16(pa1, b1, o[f], 0, 0, 0);
            }
            __builtin_amdgcn_s_setprio(0);
        }

        // epilogue: full denominator = sum of lq-group partials
        float Lf = lsum;
        Lf += __shfl_xor(Lf, 16, 64);
        Lf += __shfl_xor(Lf, 32, 64);
#pragma unroll
        for (int reg = 0; reg < 4; ++reg) {
            float ls = __shfl(Lf, (lane & 48) | (lq * 4 + reg), 64);
            float inv = 1.0f / ls;
            unsigned short* dst = ctx + (size_t)(b * SEQ + qt * 64 + wid * 16 + lq * 4 + reg) * 2048 + h * 128 + l16;
#pragma unroll
            for (int f = 0; f < 8; ++f) dst[f * 16] = f2bf(o[f][reg] * inv);
        }
    }
}

// ---------------------------------------------------------------------------
extern "C" void kernel_launch(void* const* d_in, const int* in_sizes, int n_in,
                              void* d_out, int out_size, void* d_ws, size_t ws_size,
                              hipStream_t stream) {
    const float* x          = (const float*)d_in[0];
    const float* q_a_w      = (const float*)d_in[1];
    const float* q_a_norm_w = (const float*)d_in[2];
    const float* q_b_w      = (const float*)d_in[3];
    const float* kv_a_w     = (const float*)d_in[4];
    const float* kv_norm_w  = (const float*)d_in[5];
    const float* kv_b_w     = (const float*)d_in[6];
    const float* o_w        = (const float*)d_in[7];
    float* out = (float*)d_out;

    char* ws = (char*)d_ws;
    float*          qkv_cat  = (float*)(ws + 0);                   // 4096x2176 f32 (35.7MB)
    unsigned short* ctx_bf   = (unsigned short*)(ws + 0);          // overlay after qkv_cat dead
    unsigned short* qbuf_bf  = (unsigned short*)(ws + 35651584);   // 4096x3072 bf16 (25.2MB)
    unsigned short* vt_bf    = (unsigned short*)(ws + 60817408);   // 2x16x128x2048 bf16 (16.8MB)
    unsigned short* kvb_bf   = (unsigned short*)(ws + 77594624);   // 4096x4096 bf16 (33.6MB)
    unsigned short* x_bf     = (unsigned short*)(ws + 111149056);  // 4096x2048 bf16 (16.8MB)
    unsigned short* q_a_bf   = (unsigned short*)(ws + 111149056);  // overlay after x_bf dead
    unsigned short* kv_c_bf  = (unsigned short*)(ws + 127926272);  // 4096x512 bf16
    unsigned short* krope_bf = (unsigned short*)(ws + 132120576);  // 4096x64 bf16
    unsigned short* wcat     = (unsigned short*)(ws + 132644864);  // 2176x2048 (qa 1536 | kva 640)
    unsigned short* wkva_t   = wcat + (size_t)1536 * 2048;
    unsigned short* wqb_t    = (unsigned short*)(ws + 141557760);  // 3072x1536
    unsigned short* wkvb_t   = (unsigned short*)(ws + 150994944);  // 4096x512
    unsigned short* wo_t     = (unsigned short*)(ws + 155189248);  // 2048x2048

    dim3 blk(256);

    // weight transposes + x conversion (one launch)
    WSegs segs;
    segs.s[0] = { q_a_w,  wcat,   1536, 2048,  48,     0 };
    segs.s[1] = { q_b_w,  wqb_t,  3072, 1536,  96,  3072 };
    segs.s[2] = { kv_a_w, wkva_t,  576, 2048,  20,  7680 };
    segs.s[3] = { kv_b_w, wkvb_t, 4096,  512, 128,  8960 };
    segs.s[4] = { o_w,    wo_t,   2048, 2048,  64, 11008 };
    prep_weights<<<CVT_OFF + 4096, blk, 0, stream>>>(segs, x, x_bf);

    // fused q_a + kv_a projection: [4096][2176] = x_bf @ wcat^T
    gemm_bt<0><<<dim3(17, 32), blk, 0, stream>>>(x_bf, wcat, qkv_cat, 2048, 2176);

    // both norms + k-rope (one launch)
    norms_fused<<<8192, blk, 0, stream>>>(qkv_cat, q_a_norm_w, kv_norm_w,
                                          q_a_bf, kv_c_bf, krope_bf);

    // merged second-stage projections (qb + kvb, V transposed in epilogue)
    gemm_stage2<<<1792, blk, 0, stream>>>(q_a_bf, wqb_t, qbuf_bf,
                                          kv_c_bf, wkvb_t, kvb_bf, vt_bf);

    // attention (swapped-QK in-register softmax, paired q-tiles, XCD swizzle)
    flash_mfma<<<dim3(512), blk, 0, stream>>>(qbuf_bf, kvb_bf, krope_bf, vt_bf, ctx_bf);

    // output projection
    gemm_bt<0><<<dim3(16, 32), blk, 0, stream>>>(ctx_bf, wo_t, out, 2048, 2048);
}